// Round 11
// baseline (337.049 us; speedup 1.0000x reference)
//
#include <hip/hip_runtime.h>

typedef short bf8 __attribute__((ext_vector_type(8)));
typedef float f32x4 __attribute__((ext_vector_type(4)));

static __device__ __forceinline__ unsigned short f2bf(float f) {
  unsigned u = __float_as_uint(f);
  unsigned r = u + 0x7FFFu + ((u >> 16) & 1u);
  return (unsigned short)(r >> 16);
}
static __device__ __forceinline__ float bf2f(unsigned short h) {
  return __uint_as_float(((unsigned)h) << 16);
}
// order-preserving float<->u32 key (for LDS atomicMax only)
static __device__ __forceinline__ unsigned fkey(float f) {
  unsigned u = __float_as_uint(f);
  return (u & 0x80000000u) ? ~u : (u | 0x80000000u);
}
static __device__ __forceinline__ float kdec(unsigned k) {
  unsigned u = (k & 0x80000000u) ? (k & 0x7FFFFFFFu) : ~k;
  return __uint_as_float(u);
}

// async global->LDS, 16B per lane. lds dest: wave-uniform base + lane*16.
static __device__ __forceinline__ void gload_lds16(const unsigned short* g, unsigned short* l) {
  __builtin_amdgcn_global_load_lds((const __attribute__((address_space(1))) void*)g,
                                   (__attribute__((address_space(3))) void*)l, 16, 0, 0);
}

// unfold(k=3,pad=1,stride=1) value: row d = (cc*3+ki)*3+kj, col m = i*S+j, src [C][S][S]
static __device__ __forceinline__ float uf3(const float* __restrict__ src, int lgS, int d, int m) {
  const int S = 1 << lgS;
  int cc = d / 9;
  int r9 = d - cc * 9;
  int ki = r9 / 3;
  int kj = r9 - ki * 3;
  int i = (m >> lgS) + ki - 1;
  int j = (m & (S - 1)) + kj - 1;
  if ((unsigned)i >= (unsigned)S || (unsigned)j >= (unsigned)S) return 0.f;
  return src[((size_t)cc << (2 * lgS)) + ((size_t)i << lgS) + j];
}

// ---------------- prep kernels (fused) ----------------

__global__ __launch_bounds__(256) void k_colnorm2(const float* __restrict__ lrsr3, const float* __restrict__ rsr3,
                                                  const float* __restrict__ b1, const float* __restrict__ b2,
                                                  float* __restrict__ sclr, float* __restrict__ scu3,
                                                  float* __restrict__ bl2, float* __restrict__ bl1) {
  const bool lr = blockIdx.x < 1024;
  const int m = blockIdx.x & 1023;
  const float* src = lr ? lrsr3 : rsr3;
  float s = 0.f, d1 = 0.f, d2 = 0.f;
  for (int d = threadIdx.x; d < 2304; d += 256) {
    float v = uf3(src, 5, d, m);
    s += v * v; d1 += b1[d] * v; d2 += b2[d] * v;
  }
  __shared__ float r0[256], r1[256], r2[256];
  r0[threadIdx.x] = s; r1[threadIdx.x] = d1; r2[threadIdx.x] = d2;
  __syncthreads();
  for (int o = 128; o > 0; o >>= 1) {
    if (threadIdx.x < o) {
      r0[threadIdx.x] += r0[threadIdx.x + o];
      r1[threadIdx.x] += r1[threadIdx.x + o];
      r2[threadIdx.x] += r2[threadIdx.x + o];
    }
    __syncthreads();
  }
  if (threadIdx.x == 0) {
    float sc = 1.f / fmaxf(sqrtf(r0[0]), 1e-12f);
    if (lr) { sclr[m] = sc; bl2[m] = r1[0] * sc; bl1[m] = r2[0] * sc; }
    else    { scu3[m] = sc; }
  }
}

// normalized unfold, bf16, layout [m][d]
__global__ __launch_bounds__(256) void k_pass2_md_bf(const float* __restrict__ src, const float* __restrict__ scale, unsigned short* __restrict__ out) {
  int id = blockIdx.x * 256 + threadIdx.x;
  int m = id / 2304, d = id - m * 2304;
  out[id] = f2bf(uf3(src, 5, d, m) * scale[m]);
}

// fused unfolds: blocks [0,18432): rsr2 -> U2b [4096][1152]; rest: rsr1 -> U1b [16384][640] (cols 576+ zero)
__global__ __launch_bounds__(256) void k_unfold2(const float* __restrict__ rsr2, const float* __restrict__ rsr1,
                                                 unsigned short* __restrict__ U2b, unsigned short* __restrict__ U1b) {
  int bid = blockIdx.x;
  if (bid < 18432) {
    int id = bid * 256 + threadIdx.x;
    int n = id / 1152, c = id - n * 1152;
    U2b[id] = f2bf(uf3(rsr2, 6, c, n));
  } else {
    int id = (bid - 18432) * 256 + threadIdx.x;
    int n = id / 640, c = id - n * 640;
    float v = (c < 576) ? uf3(rsr1, 7, c, n) : 0.f;
    U1b[id] = f2bf(v);
  }
}

// fused W transposes, LDS-tiled 64x64: blocks x<18 -> W1 (Cw=1152), else W2 (Cw=576)
__global__ __launch_bounds__(256) void k_wtrans2(const float* __restrict__ W1, const float* __restrict__ W2,
                                                 unsigned short* __restrict__ W1t, unsigned short* __restrict__ W2t) {
  __shared__ unsigned short Ls[64][65];
  const float* W; unsigned short* Wt; int Cw, c0;
  if (blockIdx.x < 18) { W = W1; Wt = W1t; Cw = 1152; c0 = blockIdx.x * 64; }
  else                 { W = W2; Wt = W2t; Cw = 576;  c0 = (blockIdx.x - 18) * 64; }
  const int d0 = blockIdx.y * 64;
#pragma unroll
  for (int i = 0; i < 16; ++i) {
    int idx = threadIdx.x + i * 256;
    int r = idx >> 6, c = idx & 63;
    Ls[r][c] = f2bf(W[(size_t)(d0 + r) * Cw + c0 + c]);
  }
  __syncthreads();
#pragma unroll
  for (int i = 0; i < 16; ++i) {
    int idx = threadIdx.x + i * 256;
    int cc = idx >> 6, rr = idx & 63;
    Wt[(size_t)(c0 + cc) * 2304 + d0 + rr] = Ls[rr][cc];
  }
}

// fused bw dots + bb: grid (8,10). y<9: x<5 -> bw2 chunk, x in [5,8) -> bw1 chunk. y==9: x==0 -> bb[0], x==1 -> bb[1].
__global__ __launch_bounds__(256) void k_bwbb(const float* __restrict__ W1, const float* __restrict__ W2,
                                              const float* __restrict__ b1, const float* __restrict__ b2,
                                              float* __restrict__ bw2, float* __restrict__ bw1,
                                              float* __restrict__ bb) {
  if (blockIdx.y == 9) {
    if (blockIdx.x >= 2) return;
    const float* b = blockIdx.x ? b2 : b1;
    float s = 0.f;
    for (int d = threadIdx.x; d < 2304; d += 256) s += b[d] * b[d];
    __shared__ float red[256];
    red[threadIdx.x] = s; __syncthreads();
    for (int o = 128; o > 0; o >>= 1) { if (threadIdx.x < o) red[threadIdx.x] += red[threadIdx.x + o]; __syncthreads(); }
    if (threadIdx.x == 0) bb[blockIdx.x] = red[0];
    return;
  }
  const bool two = blockIdx.x < 5;
  const float* W = two ? W1 : W2;
  const float* b = two ? b1 : b2;
  float* bw = two ? bw2 : bw1;
  const int Cw = two ? 1152 : 576;
  int c = (two ? blockIdx.x : blockIdx.x - 5) * 256 + threadIdx.x;
  if (c >= Cw) return;
  int d0 = blockIdx.y * 256;
  float s = 0.f;
  for (int d = d0; d < d0 + 256; ++d) s += b[d] * W[(size_t)d * Cw + c];
  atomicAdd(&bw[c], s);
}

// ---------------- ninv finalize ----------------
__global__ __launch_bounds__(256) void k_ninv(const float* __restrict__ pnsq2, const float* __restrict__ pbwd2,
                                              const float* __restrict__ pnsq1, const float* __restrict__ pbwd1,
                                              const float* __restrict__ bb,
                                              float* __restrict__ ninv2, float* __restrict__ ninv1) {
  int bid = blockIdx.x;
  if (bid < 16) {
    int i = bid * 256 + threadIdx.x;   // < 4096
    float nsq = 0.f, bwd = 0.f;
#pragma unroll
    for (int p = 0; p < 18; ++p) { nsq += pnsq2[p * 4096 + i]; bwd += pbwd2[p * 4096 + i]; }
    float tq = nsq + 2.f * bwd + bb[0];
    ninv2[i] = 1.f / fmaxf(sqrtf(fmaxf(tq, 0.f)), 1e-12f);
  } else {
    int i = (bid - 16) * 256 + threadIdx.x;  // < 16384
    float nsq = 0.f, bwd = 0.f;
#pragma unroll
    for (int p = 0; p < 10; ++p) { nsq += pnsq1[p * 16384 + i]; bwd += pbwd1[p * 16384 + i]; }
    float tq = nsq + 2.f * bwd + bb[1];
    ninv1[i] = 1.f / fmaxf(sqrtf(fmaxf(tq, 0.f)), 1e-12f);
  }
}

// ---------------- bf16 MFMA GEMM body: 128x128 tile, BK=32, NBUF=3 (depth-2 prefetch, 3 blocks/CU) ----------------
// LDS layout per 128x32 tile: linear row-major, stripe = 128B = 2 rows; 16B slot p within stripe s holds
// global slot q = p ^ (s&7) (pre-swizzled global source; read with the same involution). ds_read 2-way max.
// TN: C[i][j] = sum_k A[i][k]*Bt[j][k].  Two jobs per dispatch (logical id < nb0 -> j0).
// EPI 0: store bf16 C.  EPI 1: per-(colblock,wave-half) partials (unique writer slot = bx*2+wc).
// EPI 2: cmax[by][j] = max_{i in blk} (C[i][j]+bl[j])*ninv[i]  (ninv precomputed).
struct Job {
  const unsigned short* Alo;
  const unsigned short* Ahi;
  const unsigned short* Bt;
  unsigned short* Clo;
  unsigned short* Chi;
  const float* bl;
  const float* bw;
  const float* ninv;
  float* pnsq;
  float* pbwd;
  float* cmax;
  int Msplit, N, K, nbx, Mtot;
};

template <int EPI>
static __device__ __forceinline__ void gemm_body(const Job& j0, const Job& j1, int nb0) {
  constexpr int NBUF = 3;
  __shared__ __align__(16) unsigned short As[NBUF][128 * 32];
  __shared__ __align__(16) unsigned short Bs[NBUF][128 * 32];
  __shared__ unsigned colkey[128];

  // bijective XCD-chunked swizzle (m204)
  const int nwg = (int)gridDim.x;
  const int h = (int)blockIdx.x;
  const int qq = nwg >> 3, rm = nwg & 7;
  const int xcd = h & 7, wth = h >> 3;
  const int bid = (xcd < rm ? xcd * (qq + 1) : rm * (qq + 1) + (xcd - rm) * qq) + wth;

  const bool first = (bid < nb0);
  const Job j = first ? j0 : j1;
  const int local = bid - (first ? 0 : nb0);
  const int by = local / j.nbx;
  const int bx = local - by * j.nbx;
  const int m0 = by * 128, n0 = bx * 128;
  const int K = j.K, N = j.N;

  const unsigned short* Abase = (m0 < j.Msplit)
      ? j.Alo + (size_t)m0 * K
      : j.Ahi + (size_t)(m0 - j.Msplit) * K;
  const unsigned short* Bbase = j.Bt + (size_t)n0 * K;

  const int tid = threadIdx.x;
  const int l = tid & 63;
  const int w = tid >> 6;
  const int wr = w >> 1, wc = w & 1;
  if (EPI == 2 && tid < 128) colkey[tid] = 0u;

  f32x4 acc[4][4] = {};

  // staging: wave w covers rows [w*32, w*32+32) as 2 chunks x 16 rows (1KB each).
  // lane l -> stripe sg, slot p = l&7; pre-swizzled global slot q = p ^ (sg&7);
  // global row = 2*sg + (q>>2), col octet = q&3.
  const int sg0 = w * 16 + (l >> 3);
  const int q0 = (l & 7) ^ (sg0 & 7);
  const int grow0 = 2 * sg0 + (q0 >> 2);
  const int gcol0 = (q0 & 3) * 8;
  const int sg1 = sg0 + 8;
  const int q1 = (l & 7) ^ (sg1 & 7);
  const int grow1 = 2 * sg1 + (q1 >> 2);
  const int gcol1 = (q1 & 3) * 8;
  const int lb0 = (w * 32) * 32;        // ushort index of chunk0 LDS base
  const int lb1 = (w * 32 + 16) * 32;   // chunk1

  const int mr = l & 15;
  const int kg = l >> 4;                // k-octet 0..3 (BK=32)

  const int nt = K >> 5;
  const int snap_t = (n0 >> 5) + wc * 2;   // EPI1: first of two tiles covering this wave's 64-col window
  unsigned short snap[4][4][4];

  auto stage = [&](int buf, int kb) {
    gload_lds16(Abase + (size_t)grow0 * K + kb + gcol0, &As[buf][lb0]);
    gload_lds16(Abase + (size_t)grow1 * K + kb + gcol1, &As[buf][lb1]);
    gload_lds16(Bbase + (size_t)grow0 * K + kb + gcol0, &Bs[buf][lb0]);
    gload_lds16(Bbase + (size_t)grow1 * K + kb + gcol1, &Bs[buf][lb1]);
  };
  auto waitv = [&](int Wt) {           // allow Wt tiles (4 ops each) outstanding
    if (Wt >= 2)      asm volatile("s_waitcnt vmcnt(8)\ns_barrier" ::: "memory");
    else if (Wt == 1) asm volatile("s_waitcnt vmcnt(4)\ns_barrier" ::: "memory");
    else              asm volatile("s_waitcnt vmcnt(0)\ns_barrier" ::: "memory");
  };

  // prologue: NBUF tiles in flight; ensure tile 0 landed
#pragma unroll
  for (int p = 0; p < NBUF; ++p) if (p < nt) stage(p, p << 5);
  { int inflight = (NBUF < nt ? NBUF : nt); waitv(inflight - 1); }

  int cur = 0;
  for (int t = 0; t < nt; ++t) {
    {
      bf8 af[4], bv[4];
#pragma unroll
      for (int mi = 0; mi < 4; ++mi) {
        const int R = wr * 64 + mi * 16 + mr;
        af[mi] = *(const bf8*)&As[cur][(R >> 1) * 64 + ((((R & 1) << 2) | kg) ^ ((R >> 1) & 7)) * 8];
      }
#pragma unroll
      for (int ni = 0; ni < 4; ++ni) {
        const int R = wc * 64 + ni * 16 + mr;
        bv[ni] = *(const bf8*)&Bs[cur][(R >> 1) * 64 + ((((R & 1) << 2) | kg) ^ ((R >> 1) & 7)) * 8];
      }
#pragma unroll
      for (int mi = 0; mi < 4; ++mi)
#pragma unroll
        for (int ni = 0; ni < 4; ++ni)
          acc[mi][ni] = __builtin_amdgcn_mfma_f32_16x16x32_bf16(af[mi], bv[ni], acc[mi][ni], 0, 0, 0);
    }
    if (EPI == 1) {
      // snapshot A values for the quadratic form; wave's 64-col window spans tiles snap_t, snap_t+1.
      // Static indexing per branch (runtime-indexed arrays spill to scratch).
      if (t == snap_t) {
#pragma unroll
        for (int mi = 0; mi < 4; ++mi)
#pragma unroll
          for (int e = 0; e < 4; ++e) {
            const int R = wr * 64 + mi * 16 + kg * 4 + e;
            const int s = R >> 1;
#pragma unroll
            for (int nih = 0; nih < 2; ++nih) {
              const int lc = nih * 16 + mr;
              const int p = (((R & 1) << 2) | (lc >> 3)) ^ (s & 7);
              snap[mi][nih][e] = As[cur][s * 64 + p * 8 + (lc & 7)];
            }
          }
      } else if (t == snap_t + 1) {
#pragma unroll
        for (int mi = 0; mi < 4; ++mi)
#pragma unroll
          for (int e = 0; e < 4; ++e) {
            const int R = wr * 64 + mi * 16 + kg * 4 + e;
            const int s = R >> 1;
#pragma unroll
            for (int nih = 0; nih < 2; ++nih) {
              const int lc = nih * 16 + mr;
              const int p = (((R & 1) << 2) | (lc >> 3)) ^ (s & 7);
              snap[mi][2 + nih][e] = As[cur][s * 64 + p * 8 + (lc & 7)];
            }
          }
      }
    }
    if (t + 1 < nt) {
      asm volatile("s_waitcnt lgkmcnt(0)\ns_barrier" ::: "memory");   // buf[cur] free everywhere
      if (t + NBUF < nt) stage(cur, (t + NBUF) << 5);                 // refill freed buffer
      const int im = (nt - 1 < t + NBUF) ? (nt - 1) : (t + NBUF);     // newest tile issued
      waitv(im - (t + 1));                                            // tile t+1 landed
      cur = (cur + 1 == NBUF) ? 0 : cur + 1;
    }
  }

  // C/D frag layout: col = mr, row = kg*4 + e (within 16x16)
  const int lr0 = wr * 64;
  const int lc0 = wc * 64;
  if (EPI == 0) {
    unsigned short* Cbase = (m0 < j.Msplit)
        ? j.Clo + (size_t)m0 * N
        : j.Chi + (size_t)(m0 - j.Msplit) * N;
#pragma unroll
    for (int mi = 0; mi < 4; ++mi)
#pragma unroll
      for (int ni = 0; ni < 4; ++ni)
#pragma unroll
        for (int e = 0; e < 4; ++e)
          Cbase[(size_t)(lr0 + mi * 16 + kg * 4 + e) * (size_t)N + (n0 + lc0 + ni * 16 + mr)] = f2bf(acc[mi][ni][e]);
  } else if (EPI == 1) {
    float rp[4][4] = {};
    float bp[4][4] = {};
#pragma unroll
    for (int ni = 0; ni < 4; ++ni) {
      const float bwv = j.bw[n0 + lc0 + ni * 16 + mr];
#pragma unroll
      for (int mi = 0; mi < 4; ++mi)
#pragma unroll
        for (int e = 0; e < 4; ++e) {
          const float av = bf2f(snap[mi][ni][e]);
          rp[mi][e] += acc[mi][ni][e] * av;
          bp[mi][e] += bwv * av;
        }
    }
#pragma unroll
    for (int off = 1; off < 16; off <<= 1)
#pragma unroll
      for (int mi = 0; mi < 4; ++mi)
#pragma unroll
        for (int e = 0; e < 4; ++e) {
          rp[mi][e] += __shfl_xor(rp[mi][e], off);
          bp[mi][e] += __shfl_xor(bp[mi][e], off);
        }
    if (mr == 0) {
      // UNIQUE writer per (column-half slot = bx*2+wc, row)
      const size_t slotbase = (size_t)(bx * 2 + wc) * j.Mtot;
#pragma unroll
      for (int mi = 0; mi < 4; ++mi)
#pragma unroll
        for (int e = 0; e < 4; ++e) {
          const int r = m0 + lr0 + mi * 16 + kg * 4 + e;
          j.pnsq[slotbase + r] = rp[mi][e];
          j.pbwd[slotbase + r] = bp[mi][e];
        }
    }
  } else {
    float nv[4][4];
#pragma unroll
    for (int mi = 0; mi < 4; ++mi)
#pragma unroll
      for (int e = 0; e < 4; ++e)
        nv[mi][e] = j.ninv[m0 + lr0 + mi * 16 + kg * 4 + e];
#pragma unroll
    for (int ni = 0; ni < 4; ++ni) {
      float blv = j.bl[n0 + lc0 + ni * 16 + mr];
      float mx = -3.0e38f;
#pragma unroll
      for (int mi = 0; mi < 4; ++mi)
#pragma unroll
        for (int e = 0; e < 4; ++e) mx = fmaxf(mx, (acc[mi][ni][e] + blv) * nv[mi][e]);
      atomicMax(&colkey[lc0 + ni * 16 + mr], fkey(mx));   // LDS atomic only
    }
    __syncthreads();
    if (tid < 128) j.cmax[(size_t)by * 1024 + n0 + tid] = kdec(colkey[tid]);  // unique writer
  }
}

__global__ __launch_bounds__(256) void k_gP (Job a, Job b, int nb0) { gemm_body<0>(a, b, nb0); }
__global__ __launch_bounds__(256) void k_gE1(Job a, Job b, int nb0) { gemm_body<1>(a, b, nb0); }
__global__ __launch_bounds__(256) void k_gE2(Job a, Job b, int nb0) { gemm_body<2>(a, b, nb0); }

// ---------------- fp32 pixel Gram: G2[m][n] = sum_c L[c][m]*R[c][n], 1024x1024, K=256 ----------------
__global__ __launch_bounds__(256) void k_pixgram(const float* __restrict__ L, const float* __restrict__ R,
                                                 float* __restrict__ G2) {
  __shared__ float As[16][32];
  __shared__ float Bs[16][32];
  const int tid = threadIdx.x;
  const int tx = tid & 15, ty = tid >> 4;
  const int m0 = blockIdx.y * 32, n0 = blockIdx.x * 32;
  float acc[2][2] = {};
  for (int kb = 0; kb < 256; kb += 16) {
    __syncthreads();
    {
      int kk = tid >> 5, mm = tid & 31;
      As[kk][mm] = L[(size_t)(kb + kk) * 1024 + m0 + mm];
      Bs[kk][mm] = R[(size_t)(kb + kk) * 1024 + n0 + mm];
      int e2 = tid + 256; int kk2 = e2 >> 5, mm2 = e2 & 31;
      As[kk2][mm2] = L[(size_t)(kb + kk2) * 1024 + m0 + mm2];
      Bs[kk2][mm2] = R[(size_t)(kb + kk2) * 1024 + n0 + mm2];
    }
    __syncthreads();
#pragma unroll
    for (int kk = 0; kk < 16; ++kk) {
      float a0 = As[kk][ty * 2], a1 = As[kk][ty * 2 + 1];
      float b0 = Bs[kk][tx * 2], b1 = Bs[kk][tx * 2 + 1];
      acc[0][0] = fmaf(a0, b0, acc[0][0]); acc[0][1] = fmaf(a0, b1, acc[0][1]);
      acc[1][0] = fmaf(a1, b0, acc[1][0]); acc[1][1] = fmaf(a1, b1, acc[1][1]);
    }
  }
#pragma unroll
  for (int i = 0; i < 2; ++i)
#pragma unroll
    for (int j = 0; j < 2; ++j)
      G2[(size_t)(m0 + ty * 2 + i) * 1024 + (n0 + tx * 2 + j)] = acc[i][j];
}

// ---------------- R3 max/argmax from pixel Gram via masked 9-point diagonal-shift sum ----------------
__global__ __launch_bounds__(256) void k_r3max(const float* __restrict__ G2, const float* __restrict__ scu3,
                                               const float* __restrict__ sclr,
                                               float* __restrict__ s3, int* __restrict__ arg) {
  const int m = blockIdx.x;
  const int mi = m >> 5, mj = m & 31;
  float best = -3.0e38f; int bi = 0;
  for (int n = threadIdx.x; n < 1024; n += 256) {
    const int ni = n >> 5, nj = n & 31;
    float raw = 0.f;
#pragma unroll
    for (int dy = -1; dy <= 1; ++dy) {
#pragma unroll
      for (int dx = -1; dx <= 1; ++dx) {
        bool vm = ((unsigned)(mi + dy) < 32u) && ((unsigned)(mj + dx) < 32u);
        bool vn = ((unsigned)(ni + dy) < 32u) && ((unsigned)(nj + dx) < 32u);
        if (vm && vn) {
          int off = dy * 32 + dx;
          raw += G2[(size_t)(m + off) * 1024 + (n + off)];
        }
      }
    }
    float v = raw * scu3[n];
    if (v > best) { best = v; bi = n; }
  }
  __shared__ float bv[256]; __shared__ int bidx[256];
  bv[threadIdx.x] = best; bidx[threadIdx.x] = bi;
  __syncthreads();
  for (int o = 128; o > 0; o >>= 1) {
    if (threadIdx.x < o) {
      float ov = bv[threadIdx.x + o]; int oi = bidx[threadIdx.x + o];
      if (ov > bv[threadIdx.x] || (ov == bv[threadIdx.x] && oi < bidx[threadIdx.x])) {
        bv[threadIdx.x] = ov; bidx[threadIdx.x] = oi;
      }
    }
    __syncthreads();
  }
  if (threadIdx.x == 0) { s3[m] = bv[0] * sclr[m]; arg[m] = bidx[0]; }
}

// ---------------- fused gather+fold (vectorized) + S1/S2 finalize ----------------
// blocks [0,256): T3 (1 ch/block, plane+arg in LDS); [256,1280): T2 float2; [1280,2304): T1 float4;
// [2304,2312): S1/S2 reduce from cmax
__global__ __launch_bounds__(256) void k_tfold(const float* __restrict__ ref3, const float* __restrict__ ref2,
                                               const float* __restrict__ ref1, const int* __restrict__ arg,
                                               const float* __restrict__ cmax1, const float* __restrict__ cmax2,
                                               float* __restrict__ out) {
  const int bid = blockIdx.x;
  const int tid = threadIdx.x;
  if (bid < 256) {
    __shared__ float plane[1024];
    __shared__ int argL[1024];
    const int c = bid;
#pragma unroll
    for (int k = 0; k < 4; ++k) {
      plane[k * 256 + tid] = ref3[(size_t)c * 1024 + k * 256 + tid];
      argL[k * 256 + tid] = arg[k * 256 + tid];
    }
    __syncthreads();
#pragma unroll
    for (int k = 0; k < 4; ++k) {
      int px = k * 256 + tid;
      int y = px >> 5, x = px & 31;
      float s = 0.f;
#pragma unroll
      for (int di = -1; di <= 1; ++di) {
        int i = y + di;
        if ((unsigned)i >= 32u) continue;
#pragma unroll
        for (int dj = -1; dj <= 1; ++dj) {
          int jw = x + dj;
          if ((unsigned)jw >= 32u) continue;
          int n2 = argL[i * 32 + jw];
          int rr = (n2 >> 5) + y - i, cc = (n2 & 31) + x - jw;
          if ((unsigned)rr < 32u && (unsigned)cc < 32u) s += plane[rr * 32 + cc];
        }
      }
      out[3072 + (size_t)c * 1024 + px] = s * (1.f / 9.f);
    }
  } else if (bid < 1280) {
    __shared__ int argL[1024];
#pragma unroll
    for (int k = 0; k < 4; ++k) argL[k * 256 + tid] = arg[k * 256 + tid];
    __syncthreads();
    int id2 = (bid - 256) * 256 + tid;
    int q = id2 & 31, y = (id2 >> 5) & 63, c = id2 >> 11;
    int iy = y >> 1;
    float s0 = 0.f, s1 = 0.f;
#pragma unroll
    for (int di = -1; di <= 1; ++di) {
      int i = iy + di;
      if ((unsigned)i >= 32u) continue;
      int ry = y - 2 * i;
#pragma unroll
      for (int dj = -1; dj <= 1; ++dj) {
        int jw = q + dj;
        if ((unsigned)jw >= 32u) continue;
        int n2 = argL[i * 32 + jw];
        int rr = (n2 >> 5) * 2 + ry;
        int cb = (n2 & 31) * 2 + 2 * (q - jw);
        if ((unsigned)rr < 64u && (unsigned)cb < 63u) {
          const float* p = ref2 + (size_t)c * 4096 + rr * 64 + cb;
          s0 += p[0]; s1 += p[1];
        }
      }
    }
    float2 o; o.x = s0 * (1.f / 9.f); o.y = s1 * (1.f / 9.f);
    *(float2*)(out + 265216 + (size_t)c * 4096 + y * 64 + 2 * q) = o;
  } else if (bid < 2304) {
    __shared__ int argL[1024];
#pragma unroll
    for (int k = 0; k < 4; ++k) argL[k * 256 + tid] = arg[k * 256 + tid];
    __syncthreads();
    int id1 = (bid - 1280) * 256 + tid;
    int q = id1 & 31, y = (id1 >> 5) & 127, c = id1 >> 12;
    int iy = y >> 2;
    f32x4 s = {0.f, 0.f, 0.f, 0.f};
#pragma unroll
    for (int di = -1; di <= 1; ++di) {
      int i = iy + di;
      if ((unsigned)i >= 32u) continue;
      int ry = y - 4 * i;
#pragma unroll
      for (int dj = -1; dj <= 1; ++dj) {
        int jw = q + dj;
        if ((unsigned)jw >= 32u) continue;
        int n2 = argL[i * 32 + jw];
        int rr = (n2 >> 5) * 4 + ry;
        int cb = (n2 & 31) * 4 + 4 * (q - jw);
        if ((unsigned)rr < 128u && (unsigned)cb < 125u) {
          f32x4 v = *(const f32x4*)(ref1 + (size_t)c * 16384 + rr * 128 + cb);
          s += v;
        }
      }
    }
    s *= (1.f / 9.f);
    *(f32x4*)(out + 789504 + (size_t)c * 16384 + y * 128 + 4 * q) = s;
  } else {
    int t = (bid - 2304) * 256 + tid;  // 0..2047
    if (t < 1024) {
      float mx = -3.0e38f;
      for (int rb = 0; rb < 128; ++rb) mx = fmaxf(mx, cmax1[rb * 1024 + t]);
      out[t] = mx;            // S_1
    } else {
      int tt = t - 1024;
      float mx = -3.0e38f;
      for (int rb = 0; rb < 32; ++rb) mx = fmaxf(mx, cmax2[rb * 1024 + tt]);
      out[1024 + tt] = mx;    // S_2
    }
  }
}

// ---------------- workspace layout (bytes) ----------------
static constexpr size_t OFF_BW2     = 0;                        // 1152 f32
static constexpr size_t OFF_BW1     = 4608;                     // 640 f32
static constexpr size_t ZERO_BYTES  = 7168;
static constexpr size_t OFF_BB      = 7168;                     // 2 f32 (pad to 256)
static constexpr size_t OFF_BL2     = 7424;                     // 1024 f32
static constexpr size_t OFF_BL1     = 11520;                    // 1024 f32
static constexpr size_t OFF_SCLR    = 15616;                    // 1024 f32
static constexpr size_t OFF_SCU3    = 19712;                    // 1024 f32
static constexpr size_t OFF_R3ARG   = 23808;                    // 1024 int
static constexpr size_t OFF_PNSQ2   = 27904;                    // f32 [18][4096]
static constexpr size_t OFF_PBWD2   = OFF_PNSQ2 + 294912;       // f32 [18][4096]
static constexpr size_t OFF_PNSQ1   = OFF_PBWD2 + 294912;       // f32 [10][16384]
static constexpr size_t OFF_PBWD1   = OFF_PNSQ1 + 655360;       // f32 [10][16384]
static constexpr size_t OFF_CMAX2   = OFF_PBWD1 + 655360;       // f32 [32][1024]
static constexpr size_t OFF_CMAX1   = OFF_CMAX2 + 131072;       // f32 [128][1024]
static constexpr size_t OFF_NINV2   = OFF_CMAX1 + 524288;       // f32 [4096]
static constexpr size_t OFF_NINV1   = OFF_NINV2 + 16384;        // f32 [16384]
static constexpr size_t OFF_LR3NBT  = OFF_NINV1 + 65536;        // bf16 [1024][2304]
static constexpr size_t OFF_U2B     = OFF_LR3NBT + 4718592;     // bf16 [4096][1152]
static constexpr size_t OFF_U1B     = OFF_U2B    + 9437184;     // bf16 [16384][640]
static constexpr size_t OFF_W1T     = OFF_U1B    + 20971520;    // bf16 [1152][2304]
static constexpr size_t OFF_W2T     = OFF_W1T    + 5308416;     // bf16 [640][2304] (rows 576+ zero)
static constexpr size_t OFF_A2      = OFF_W2T    + 2949120;     // bf16 [1152][1152]
static constexpr size_t OFF_A1      = OFF_A2     + 2654208;     // bf16 [640][640]
static constexpr size_t OFF_M2T     = OFF_A1     + 819200;      // bf16 [1024][1152]
static constexpr size_t OFF_M1T     = OFF_M2T    + 2359296;     // bf16 [1024][640]
static constexpr size_t OFF_G2      = OFF_M1T    + 1310720;     // f32 [1024][1024]

extern "C" void kernel_launch(void* const* d_in, const int* in_sizes, int n_in,
                              void* d_out, int out_size, void* d_ws, size_t ws_size,
                              hipStream_t stream) {
  (void)in_sizes; (void)n_in; (void)out_size; (void)ws_size;
  const float* lrsr3  = (const float*)d_in[0];
  const float* rsr1   = (const float*)d_in[1];
  const float* rsr2   = (const float*)d_in[2];
  const float* rsr3   = (const float*)d_in[3];
  const float* ref1   = (const float*)d_in[4];
  const float* ref2   = (const float*)d_in[5];
  const float* ref3   = (const float*)d_in[6];
  const float* W1     = (const float*)d_in[7];
  const float* b1     = (const float*)d_in[8];
  const float* W2     = (const float*)d_in[9];
  const float* b2     = (const float*)d_in[10];
  float* out = (float*)d_out;
  char* ws = (char*)d_ws;

  float*          bw2     = (float*)(ws + OFF_BW2);
  float*          bw1     = (float*)(ws + OFF_BW1);
  float*          bb      = (float*)(ws + OFF_BB);
  float*          bl2     = (float*)(ws + OFF_BL2);
  float*          bl1     = (float*)(ws + OFF_BL1);
  float*          sclr    = (float*)(ws + OFF_SCLR);
  float*          scu3    = (float*)(ws + OFF_SCU3);
  int*            R3arg   = (int*)(ws + OFF_R3ARG);
  float*          pnsq2   = (float*)(ws + OFF_PNSQ2);
  float*          pbwd2   = (float*)(ws + OFF_PBWD2);
  float*          pnsq1   = (float*)(ws + OFF_PNSQ1);
  float*          pbwd1   = (float*)(ws + OFF_PBWD1);
  float*          cmax2   = (float*)(ws + OFF_CMAX2);
  float*          cmax1   = (float*)(ws + OFF_CMAX1);
  float*          ninv2   = (float*)(ws + OFF_NINV2);
  float*          ninv1   = (float*)(ws + OFF_NINV1);
  unsigned short* lr3nbT  = (unsigned short*)(ws + OFF_LR3NBT);
  unsigned short* U2b     = (unsigned short*)(ws + OFF_U2B);
  unsigned short* U1b     = (unsigned short*)(ws + OFF_U1B);
  unsigned short* W1t     = (unsigned short*)(ws + OFF_W1T);
  unsigned short* W2t     = (unsigned short*)(ws + OFF_W2T);
  unsigned short* A2b     = (unsigned short*)(ws + OFF_A2);
  unsigned short* A1b     = (unsigned short*)(ws + OFF_A1);
  unsigned short* M2tb    = (unsigned short*)(ws + OFF_M2T);
  unsigned short* M1tb    = (unsigned short*)(ws + OFF_M1T);
  float*          G2      = (float*)(ws + OFF_G2);

  hipMemsetAsync(d_ws, 0, ZERO_BYTES, stream);
  // zero pad rows 576..639 of W2t
  hipMemsetAsync(ws + OFF_W2T + (size_t)576 * 2304 * 2, 0, (size_t)64 * 2304 * 2, stream);

  // norms + bias dots + pixel Gram (R3 path, all fp32)
  k_colnorm2<<<2048, 256, 0, stream>>>(lrsr3, rsr3, b1, b2, sclr, scu3, bl2, bl1);
  k_pixgram<<<dim3(32, 32), 256, 0, stream>>>(lrsr3, rsr3, G2);
  k_r3max<<<1024, 256, 0, stream>>>(G2, scu3, sclr, out + 2048, R3arg);

  // unfolds / transposes for the bf16 score paths
  k_pass2_md_bf<<<9216, 256, 0, stream>>>(lrsr3, sclr, lr3nbT);
  k_unfold2<<<59392, 256, 0, stream>>>(rsr2, rsr1, U2b, U1b);
  k_wtrans2<<<dim3(27, 36), 256, 0, stream>>>(W1, W2, W1t, W2t);
  k_bwbb<<<dim3(8, 10), 256, 0, stream>>>(W1, W2, b1, b2, bw2, bw1, bb);

  Job jz = {};

  // P: Gram matrices + M^T, fused across row-concat [Wt ; lr3nbT]
  {
    Job a = jz, b = jz;
    a.Alo = W1t; a.Ahi = lr3nbT; a.Msplit = 1152; a.Bt = W1t;
    a.Clo = A2b; a.Chi = M2tb; a.N = 1152; a.K = 2304; a.nbx = 9;
    b.Alo = W2t; b.Ahi = lr3nbT; b.Msplit = 640; b.Bt = W2t;
    b.Clo = A1b; b.Chi = M1tb; b.N = 640; b.K = 2304; b.nbx = 5;
    k_gP<<<153 + 65, 256, 0, stream>>>(a, b, 153);
  }
  // E1: per-(colblock,half) norm/bw partials via Gram quadratic form (no atomics, unique writers)
  {
    Job a = jz, b = jz;
    a.Alo = U2b; a.Ahi = U2b; a.Msplit = 4096; a.Bt = A2b;
    a.bw = bw2; a.pnsq = pnsq2; a.pbwd = pbwd2; a.Mtot = 4096;
    a.N = 1152; a.K = 1152; a.nbx = 9;
    b.Alo = U1b; b.Ahi = U1b; b.Msplit = 16384; b.Bt = A1b;
    b.bw = bw1; b.pnsq = pnsq1; b.pbwd = pbwd1; b.Mtot = 16384;
    b.N = 640; b.K = 640; b.nbx = 5;
    k_gE1<<<288 + 640, 256, 0, stream>>>(a, b, 288);
  }
  // ninv finalize: one pass over the partials
  k_ninv<<<80, 256, 0, stream>>>(pnsq2, pbwd2, pnsq1, pbwd1, bb, ninv2, ninv1);
  // E2: score max, per-rowblock col-max stores
  {
    Job a = jz, b = jz;
    a.Alo = U2b; a.Ahi = U2b; a.Msplit = 4096; a.Bt = M2tb;
    a.bl = bl2; a.ninv = ninv2; a.cmax = cmax2; a.Mtot = 4096;
    a.N = 1024; a.K = 1152; a.nbx = 8;
    b.Alo = U1b; b.Ahi = U1b; b.Msplit = 16384; b.Bt = M1tb;
    b.bl = bl1; b.ninv = ninv1; b.cmax = cmax1; b.Mtot = 16384;
    b.N = 1024; b.K = 640; b.nbx = 8;
    k_gE2<<<256 + 1024, 256, 0, stream>>>(a, b, 256);
  }

  // transfer + S1/S2 finalize (fused, vectorized gathers)
  k_tfold<<<2312, 256, 0, stream>>>(ref3, ref2, ref1, R3arg, cmax1, cmax2, out);
}

// Round 12
// 294.682 us; speedup vs baseline: 1.1438x; 1.1438x over previous
//
#include <hip/hip_runtime.h>

typedef short bf8 __attribute__((ext_vector_type(8)));
typedef float f32x4 __attribute__((ext_vector_type(4)));

static __device__ __forceinline__ unsigned short f2bf(float f) {
  unsigned u = __float_as_uint(f);
  unsigned r = u + 0x7FFFu + ((u >> 16) & 1u);
  return (unsigned short)(r >> 16);
}
static __device__ __forceinline__ float bf2f(unsigned short h) {
  return __uint_as_float(((unsigned)h) << 16);
}
// order-preserving float<->u32 key (for LDS atomicMax only)
static __device__ __forceinline__ unsigned fkey(float f) {
  unsigned u = __float_as_uint(f);
  return (u & 0x80000000u) ? ~u : (u | 0x80000000u);
}
static __device__ __forceinline__ float kdec(unsigned k) {
  unsigned u = (k & 0x80000000u) ? (k & 0x7FFFFFFFu) : ~k;
  return __uint_as_float(u);
}

// async global->LDS, 16B per lane. lds dest: wave-uniform base + lane*16.
static __device__ __forceinline__ void gload_lds16(const unsigned short* g, unsigned short* l) {
  __builtin_amdgcn_global_load_lds((const __attribute__((address_space(1))) void*)g,
                                   (__attribute__((address_space(3))) void*)l, 16, 0, 0);
}

// unfold(k=3,pad=1,stride=1) value: row d = (cc*3+ki)*3+kj, col m = i*S+j, src [C][S][S]
static __device__ __forceinline__ float uf3(const float* __restrict__ src, int lgS, int d, int m) {
  const int S = 1 << lgS;
  int cc = d / 9;
  int r9 = d - cc * 9;
  int ki = r9 / 3;
  int kj = r9 - ki * 3;
  int i = (m >> lgS) + ki - 1;
  int j = (m & (S - 1)) + kj - 1;
  if ((unsigned)i >= (unsigned)S || (unsigned)j >= (unsigned)S) return 0.f;
  return src[((size_t)cc << (2 * lgS)) + ((size_t)i << lgS) + j];
}

// ---------------- prep kernels (fused) ----------------

__global__ __launch_bounds__(256) void k_colnorm2(const float* __restrict__ lrsr3, const float* __restrict__ rsr3,
                                                  const float* __restrict__ b1, const float* __restrict__ b2,
                                                  float* __restrict__ sclr, float* __restrict__ scu3,
                                                  float* __restrict__ bl2, float* __restrict__ bl1) {
  const bool lr = blockIdx.x < 1024;
  const int m = blockIdx.x & 1023;
  const float* src = lr ? lrsr3 : rsr3;
  float s = 0.f, d1 = 0.f, d2 = 0.f;
  for (int d = threadIdx.x; d < 2304; d += 256) {
    float v = uf3(src, 5, d, m);
    s += v * v; d1 += b1[d] * v; d2 += b2[d] * v;
  }
  __shared__ float r0[256], r1[256], r2[256];
  r0[threadIdx.x] = s; r1[threadIdx.x] = d1; r2[threadIdx.x] = d2;
  __syncthreads();
  for (int o = 128; o > 0; o >>= 1) {
    if (threadIdx.x < o) {
      r0[threadIdx.x] += r0[threadIdx.x + o];
      r1[threadIdx.x] += r1[threadIdx.x + o];
      r2[threadIdx.x] += r2[threadIdx.x + o];
    }
    __syncthreads();
  }
  if (threadIdx.x == 0) {
    float sc = 1.f / fmaxf(sqrtf(r0[0]), 1e-12f);
    if (lr) { sclr[m] = sc; bl2[m] = r1[0] * sc; bl1[m] = r2[0] * sc; }
    else    { scu3[m] = sc; }
  }
}

// normalized unfold, bf16, layout [m][d], 8 elems/thread (vectorized store)
__global__ __launch_bounds__(256) void k_pass2_md_bf(const float* __restrict__ src, const float* __restrict__ scale, unsigned short* __restrict__ out) {
  int id8 = blockIdx.x * 256 + threadIdx.x;         // < 1024*288
  int m = id8 / 288, c0 = (id8 - m * 288) * 8;
  float sc = scale[m];
  bf8 v;
#pragma unroll
  for (int e = 0; e < 8; ++e) v[e] = (short)f2bf(uf3(src, 5, c0 + e, m) * sc);
  *(bf8*)(out + (size_t)m * 2304 + c0) = v;
}

// fused unfolds, 8 elems/thread: blocks [0,2304): rsr2 -> U2b [4096][1152]; rest: rsr1 -> U1b [16384][640]
__global__ __launch_bounds__(256) void k_unfold2(const float* __restrict__ rsr2, const float* __restrict__ rsr1,
                                                 unsigned short* __restrict__ U2b, unsigned short* __restrict__ U1b) {
  int bid = blockIdx.x;
  if (bid < 2304) {
    int id8 = bid * 256 + threadIdx.x;              // < 589824
    int n = id8 / 144, c0 = (id8 - n * 144) * 8;
    bf8 v;
#pragma unroll
    for (int e = 0; e < 8; ++e) v[e] = (short)f2bf(uf3(rsr2, 6, c0 + e, n));
    *(bf8*)(U2b + (size_t)n * 1152 + c0) = v;
  } else {
    int id8 = (bid - 2304) * 256 + threadIdx.x;     // < 1310720
    int n = id8 / 80, c0 = (id8 - n * 80) * 8;
    bf8 v;
#pragma unroll
    for (int e = 0; e < 8; ++e) {
      int c = c0 + e;
      v[e] = (short)((c < 576) ? f2bf(uf3(rsr1, 7, c, n)) : (unsigned short)0);
    }
    *(bf8*)(U1b + (size_t)n * 640 + c0) = v;
  }
}

// fused W transposes, LDS-tiled 64x64: blocks x<18 -> W1 (Cw=1152), else W2 (Cw=576)
__global__ __launch_bounds__(256) void k_wtrans2(const float* __restrict__ W1, const float* __restrict__ W2,
                                                 unsigned short* __restrict__ W1t, unsigned short* __restrict__ W2t) {
  __shared__ unsigned short Ls[64][65];
  const float* W; unsigned short* Wt; int Cw, c0;
  if (blockIdx.x < 18) { W = W1; Wt = W1t; Cw = 1152; c0 = blockIdx.x * 64; }
  else                 { W = W2; Wt = W2t; Cw = 576;  c0 = (blockIdx.x - 18) * 64; }
  const int d0 = blockIdx.y * 64;
#pragma unroll
  for (int i = 0; i < 16; ++i) {
    int idx = threadIdx.x + i * 256;
    int r = idx >> 6, c = idx & 63;
    Ls[r][c] = f2bf(W[(size_t)(d0 + r) * Cw + c0 + c]);
  }
  __syncthreads();
#pragma unroll
  for (int i = 0; i < 16; ++i) {
    int idx = threadIdx.x + i * 256;
    int cc = idx >> 6, rr = idx & 63;
    Wt[(size_t)(c0 + cc) * 2304 + d0 + rr] = Ls[rr][cc];
  }
}

// fused bw dots + bb: grid (8,10). y<9: x<5 -> bw2 chunk, x in [5,8) -> bw1 chunk. y==9: x==0 -> bb[0], x==1 -> bb[1].
__global__ __launch_bounds__(256) void k_bwbb(const float* __restrict__ W1, const float* __restrict__ W2,
                                              const float* __restrict__ b1, const float* __restrict__ b2,
                                              float* __restrict__ bw2, float* __restrict__ bw1,
                                              float* __restrict__ bb) {
  if (blockIdx.y == 9) {
    if (blockIdx.x >= 2) return;
    const float* b = blockIdx.x ? b2 : b1;
    float s = 0.f;
    for (int d = threadIdx.x; d < 2304; d += 256) s += b[d] * b[d];
    __shared__ float red[256];
    red[threadIdx.x] = s; __syncthreads();
    for (int o = 128; o > 0; o >>= 1) { if (threadIdx.x < o) red[threadIdx.x] += red[threadIdx.x + o]; __syncthreads(); }
    if (threadIdx.x == 0) bb[blockIdx.x] = red[0];
    return;
  }
  const bool two = blockIdx.x < 5;
  const float* W = two ? W1 : W2;
  const float* b = two ? b1 : b2;
  float* bw = two ? bw2 : bw1;
  const int Cw = two ? 1152 : 576;
  int c = (two ? blockIdx.x : blockIdx.x - 5) * 256 + threadIdx.x;
  if (c >= Cw) return;
  int d0 = blockIdx.y * 256;
  float s = 0.f;
  for (int d = d0; d < d0 + 256; ++d) s += b[d] * W[(size_t)d * Cw + c];
  atomicAdd(&bw[c], s);
}

// ---------------- ninv finalize ----------------
__global__ __launch_bounds__(256) void k_ninv(const float* __restrict__ pnsq2, const float* __restrict__ pbwd2,
                                              const float* __restrict__ pnsq1, const float* __restrict__ pbwd1,
                                              const float* __restrict__ bb,
                                              float* __restrict__ ninv2, float* __restrict__ ninv1) {
  int bid = blockIdx.x;
  if (bid < 16) {
    int i = bid * 256 + threadIdx.x;   // < 4096
    float nsq = 0.f, bwd = 0.f;
#pragma unroll
    for (int p = 0; p < 18; ++p) { nsq += pnsq2[p * 4096 + i]; bwd += pbwd2[p * 4096 + i]; }
    float tq = nsq + 2.f * bwd + bb[0];
    ninv2[i] = 1.f / fmaxf(sqrtf(fmaxf(tq, 0.f)), 1e-12f);
  } else {
    int i = (bid - 16) * 256 + threadIdx.x;  // < 16384
    float nsq = 0.f, bwd = 0.f;
#pragma unroll
    for (int p = 0; p < 10; ++p) { nsq += pnsq1[p * 16384 + i]; bwd += pbwd1[p * 16384 + i]; }
    float tq = nsq + 2.f * bwd + bb[1];
    ninv1[i] = 1.f / fmaxf(sqrtf(fmaxf(tq, 0.f)), 1e-12f);
  }
}

// ---------------- bf16 MFMA GEMM body: 128x128 tile, BK=64, 4 waves, XCD-chunked ----------------
// NBUF==1: m97 structure — single buffer, 32KB LDS (4 blocks/CU), stage -> sync -> MFMA -> sync.
//          Latency hidden by inter-block wave overlap (TLP), not intra-block prefetch (m114).
// NBUF>=2: counted-vmcnt rotating pipeline (for tiny grids with 1 block/CU, e.g. P).
// TN: C[i][j] = sum_k A[i][k]*Bt[j][k].  Two jobs per dispatch (logical id < nb0 -> j0).
// EPI 0: store bf16 C.  EPI 1: per-(colblock,wave-half) partials (unique writer slot = bx*2+wc).
// EPI 2: cmax[by][j] = max_{i in blk} (C[i][j]+bl[j])*ninv[i]  (ninv precomputed).
struct Job {
  const unsigned short* Alo;
  const unsigned short* Ahi;
  const unsigned short* Bt;
  unsigned short* Clo;
  unsigned short* Chi;
  const float* bl;
  const float* bw;
  const float* ninv;
  float* pnsq;
  float* pbwd;
  float* cmax;
  int Msplit, N, K, nbx, Mtot;
};

template <int EPI, int NBUF>
static __device__ __forceinline__ void gemm_body(const Job& j0, const Job& j1, int nb0) {
  __shared__ __align__(16) unsigned short As[NBUF][128 * 64];
  __shared__ __align__(16) unsigned short Bs[NBUF][128 * 64];
  __shared__ unsigned colkey[128];

  // bijective XCD-chunked swizzle (m204)
  const int nwg = (int)gridDim.x;
  const int h = (int)blockIdx.x;
  const int qq = nwg >> 3, rm = nwg & 7;
  const int xcd = h & 7, wth = h >> 3;
  const int bid = (xcd < rm ? xcd * (qq + 1) : rm * (qq + 1) + (xcd - rm) * qq) + wth;

  const bool first = (bid < nb0);
  const Job j = first ? j0 : j1;
  const int local = bid - (first ? 0 : nb0);
  const int by = local / j.nbx;
  const int bx = local - by * j.nbx;
  const int m0 = by * 128, n0 = bx * 128;
  const int K = j.K, N = j.N;

  const unsigned short* Abase = (m0 < j.Msplit)
      ? j.Alo + (size_t)m0 * K
      : j.Ahi + (size_t)(m0 - j.Msplit) * K;

  const int tid = threadIdx.x;
  const int l = tid & 63;
  const int w = tid >> 6;
  const int wr = w >> 1, wc = w & 1;
  if (EPI == 2 && tid < 128) colkey[tid] = 0u;

  f32x4 acc[4][4] = {};

  // staging: wave w stages rows [w*32, w*32+32) in 4 chunks of 8 rows.
  // Pre-swizzle GLOBAL source so LDS slot q of row r holds global slot q^(r&7).
  const int srow = w * 32;
  const int lrow = l >> 3;
  const int gcol = ((l & 7) ^ lrow) * 8;
  const int mr = l & 15;
  const int kg = l >> 4;

  const int nt = K >> 6;
  const int snap_kb = n0 + wc * 64;
  unsigned short snap[4][4][4];

  auto stage = [&](int buf, int kb) {
#pragma unroll
    for (int i = 0; i < 4; ++i) {
      int r = srow + i * 8;
      gload_lds16(Abase + (size_t)(r + lrow) * K + kb + gcol, &As[buf][r * 64]);
      gload_lds16(j.Bt + (size_t)(n0 + r + lrow) * K + kb + gcol, &Bs[buf][r * 64]);
    }
  };
  auto compute_tile = [&](int cur) {
#pragma unroll
    for (int ks = 0; ks < 2; ++ks) {
      bf8 af[4], bv[4];
#pragma unroll
      for (int mi = 0; mi < 4; ++mi) {
        const int row = wr * 64 + mi * 16 + mr;
        af[mi] = *(const bf8*)&As[cur][row * 64 + (((ks * 4 + kg) ^ (row & 7)) * 8)];
      }
#pragma unroll
      for (int ni = 0; ni < 4; ++ni) {
        const int row = wc * 64 + ni * 16 + mr;
        bv[ni] = *(const bf8*)&Bs[cur][row * 64 + (((ks * 4 + kg) ^ (row & 7)) * 8)];
      }
      __builtin_amdgcn_s_setprio(1);
#pragma unroll
      for (int mi = 0; mi < 4; ++mi)
#pragma unroll
        for (int ni = 0; ni < 4; ++ni)
          acc[mi][ni] = __builtin_amdgcn_mfma_f32_16x16x32_bf16(af[mi], bv[ni], acc[mi][ni], 0, 0, 0);
      __builtin_amdgcn_s_setprio(0);
    }
  };
  auto do_snap = [&](int cur) {
#pragma unroll
    for (int mi = 0; mi < 4; ++mi)
#pragma unroll
      for (int e = 0; e < 4; ++e) {
        const int row = wr * 64 + mi * 16 + kg * 4 + e;
#pragma unroll
        for (int ni = 0; ni < 4; ++ni) {
          const int slot = ni * 2 + (mr >> 3);
          snap[mi][ni][e] = As[cur][row * 64 + ((slot ^ (row & 7)) * 8) + (mr & 7)];
        }
      }
  };

  if constexpr (NBUF == 1) {
    // m97 single-buffer loop: TLP across 4 resident blocks hides staging latency.
    for (int t = 0; t < nt; ++t) {
      if (t) __syncthreads();              // all waves done reading LDS before overwrite
      stage(0, t << 6);
      __syncthreads();                     // vmcnt(0)+lgkmcnt(0) drain: tile visible
      compute_tile(0);
      if (EPI == 1 && (t << 6) == snap_kb) do_snap(0);
    }
  } else {
    auto waitv = [&](int Wt) {
      if (Wt >= 2)      asm volatile("s_waitcnt vmcnt(16)\ns_barrier" ::: "memory");
      else if (Wt == 1) asm volatile("s_waitcnt vmcnt(8)\ns_barrier" ::: "memory");
      else              asm volatile("s_waitcnt vmcnt(0)\ns_barrier" ::: "memory");
    };
    // prologue: up to NBUF tiles in flight; ensure tile 0 landed
#pragma unroll
    for (int p = 0; p < NBUF; ++p) if (p < nt) stage(p, p << 6);
    { int inflight = (NBUF < nt ? NBUF : nt); waitv(inflight - 1); }
    int cur = 0;
    for (int t = 0; t < nt; ++t) {
      compute_tile(cur);
      if (EPI == 1 && (t << 6) == snap_kb) do_snap(cur);
      if (t + 1 < nt) {
        asm volatile("s_waitcnt lgkmcnt(0)\ns_barrier" ::: "memory");   // buf[cur] free everywhere
        if (t + NBUF < nt) stage(cur, (t + NBUF) << 6);                 // refill freed buffer
        const int im = (nt - 1 < t + NBUF) ? (nt - 1) : (t + NBUF);     // newest tile issued
        waitv(im - (t + 1));                                            // tile t+1 landed
        cur = (cur + 1 == NBUF) ? 0 : cur + 1;
      }
    }
  }

  // C/D frag layout: col = mr, row = kg*4 + e (within 16x16)
  const int lr0 = wr * 64;
  const int lc0 = wc * 64;
  if (EPI == 0) {
    unsigned short* Cbase = (m0 < j.Msplit)
        ? j.Clo + (size_t)m0 * N
        : j.Chi + (size_t)(m0 - j.Msplit) * N;
#pragma unroll
    for (int mi = 0; mi < 4; ++mi)
#pragma unroll
      for (int ni = 0; ni < 4; ++ni)
#pragma unroll
        for (int e = 0; e < 4; ++e)
          Cbase[(size_t)(lr0 + mi * 16 + kg * 4 + e) * (size_t)N + (n0 + lc0 + ni * 16 + mr)] = f2bf(acc[mi][ni][e]);
  } else if (EPI == 1) {
    float rp[4][4] = {};
    float bp[4][4] = {};
#pragma unroll
    for (int ni = 0; ni < 4; ++ni) {
      const float bwv = j.bw[n0 + lc0 + ni * 16 + mr];
#pragma unroll
      for (int mi = 0; mi < 4; ++mi)
#pragma unroll
        for (int e = 0; e < 4; ++e) {
          const float av = bf2f(snap[mi][ni][e]);
          rp[mi][e] += acc[mi][ni][e] * av;
          bp[mi][e] += bwv * av;
        }
    }
#pragma unroll
    for (int off = 1; off < 16; off <<= 1)
#pragma unroll
      for (int mi = 0; mi < 4; ++mi)
#pragma unroll
        for (int e = 0; e < 4; ++e) {
          rp[mi][e] += __shfl_xor(rp[mi][e], off);
          bp[mi][e] += __shfl_xor(bp[mi][e], off);
        }
    if (mr == 0) {
      // UNIQUE writer per (column-half slot = bx*2+wc, row)
      const size_t slotbase = (size_t)(bx * 2 + wc) * j.Mtot;
#pragma unroll
      for (int mi = 0; mi < 4; ++mi)
#pragma unroll
        for (int e = 0; e < 4; ++e) {
          const int r = m0 + lr0 + mi * 16 + kg * 4 + e;
          j.pnsq[slotbase + r] = rp[mi][e];
          j.pbwd[slotbase + r] = bp[mi][e];
        }
    }
  } else {
    float nv[4][4];
#pragma unroll
    for (int mi = 0; mi < 4; ++mi)
#pragma unroll
      for (int e = 0; e < 4; ++e)
        nv[mi][e] = j.ninv[m0 + lr0 + mi * 16 + kg * 4 + e];
#pragma unroll
    for (int ni = 0; ni < 4; ++ni) {
      float blv = j.bl[n0 + lc0 + ni * 16 + mr];
      float mx = -3.0e38f;
#pragma unroll
      for (int mi = 0; mi < 4; ++mi)
#pragma unroll
        for (int e = 0; e < 4; ++e) mx = fmaxf(mx, (acc[mi][ni][e] + blv) * nv[mi][e]);
      atomicMax(&colkey[lc0 + ni * 16 + mr], fkey(mx));   // LDS atomic only
    }
    __syncthreads();
    if (tid < 128) j.cmax[(size_t)by * 1024 + n0 + tid] = kdec(colkey[tid]);  // unique writer
  }
}

__global__ __launch_bounds__(256) void k_gP (Job a, Job b, int nb0) { gemm_body<0, 3>(a, b, nb0); }
__global__ __launch_bounds__(256) void k_gE1(Job a, Job b, int nb0) { gemm_body<1, 1>(a, b, nb0); }
__global__ __launch_bounds__(256) void k_gE2(Job a, Job b, int nb0) { gemm_body<2, 1>(a, b, nb0); }

// ---------------- fp32 pixel Gram: G2[m][n] = sum_c L[c][m]*R[c][n], 1024x1024, K=256 ----------------
__global__ __launch_bounds__(256) void k_pixgram(const float* __restrict__ L, const float* __restrict__ R,
                                                 float* __restrict__ G2) {
  __shared__ float As[16][32];
  __shared__ float Bs[16][32];
  const int tid = threadIdx.x;
  const int tx = tid & 15, ty = tid >> 4;
  const int m0 = blockIdx.y * 32, n0 = blockIdx.x * 32;
  float acc[2][2] = {};
  for (int kb = 0; kb < 256; kb += 16) {
    __syncthreads();
    {
      int kk = tid >> 5, mm = tid & 31;
      As[kk][mm] = L[(size_t)(kb + kk) * 1024 + m0 + mm];
      Bs[kk][mm] = R[(size_t)(kb + kk) * 1024 + n0 + mm];
      int e2 = tid + 256; int kk2 = e2 >> 5, mm2 = e2 & 31;
      As[kk2][mm2] = L[(size_t)(kb + kk2) * 1024 + m0 + mm2];
      Bs[kk2][mm2] = R[(size_t)(kb + kk2) * 1024 + n0 + mm2];
    }
    __syncthreads();
#pragma unroll
    for (int kk = 0; kk < 16; ++kk) {
      float a0 = As[kk][ty * 2], a1 = As[kk][ty * 2 + 1];
      float b0 = Bs[kk][tx * 2], b1 = Bs[kk][tx * 2 + 1];
      acc[0][0] = fmaf(a0, b0, acc[0][0]); acc[0][1] = fmaf(a0, b1, acc[0][1]);
      acc[1][0] = fmaf(a1, b0, acc[1][0]); acc[1][1] = fmaf(a1, b1, acc[1][1]);
    }
  }
#pragma unroll
  for (int i = 0; i < 2; ++i)
#pragma unroll
    for (int j = 0; j < 2; ++j)
      G2[(size_t)(m0 + ty * 2 + i) * 1024 + (n0 + tx * 2 + j)] = acc[i][j];
}

// ---------------- R3 max/argmax from pixel Gram via masked 9-point diagonal-shift sum ----------------
__global__ __launch_bounds__(256) void k_r3max(const float* __restrict__ G2, const float* __restrict__ scu3,
                                               const float* __restrict__ sclr,
                                               float* __restrict__ s3, int* __restrict__ arg) {
  const int m = blockIdx.x;
  const int mi = m >> 5, mj = m & 31;
  float best = -3.0e38f; int bi = 0;
  for (int n = threadIdx.x; n < 1024; n += 256) {
    const int ni = n >> 5, nj = n & 31;
    float raw = 0.f;
#pragma unroll
    for (int dy = -1; dy <= 1; ++dy) {
#pragma unroll
      for (int dx = -1; dx <= 1; ++dx) {
        bool vm = ((unsigned)(mi + dy) < 32u) && ((unsigned)(mj + dx) < 32u);
        bool vn = ((unsigned)(ni + dy) < 32u) && ((unsigned)(nj + dx) < 32u);
        if (vm && vn) {
          int off = dy * 32 + dx;
          raw += G2[(size_t)(m + off) * 1024 + (n + off)];
        }
      }
    }
    float v = raw * scu3[n];
    if (v > best) { best = v; bi = n; }
  }
  __shared__ float bv[256]; __shared__ int bidx[256];
  bv[threadIdx.x] = best; bidx[threadIdx.x] = bi;
  __syncthreads();
  for (int o = 128; o > 0; o >>= 1) {
    if (threadIdx.x < o) {
      float ov = bv[threadIdx.x + o]; int oi = bidx[threadIdx.x + o];
      if (ov > bv[threadIdx.x] || (ov == bv[threadIdx.x] && oi < bidx[threadIdx.x])) {
        bv[threadIdx.x] = ov; bidx[threadIdx.x] = oi;
      }
    }
    __syncthreads();
  }
  if (threadIdx.x == 0) { s3[m] = bv[0] * sclr[m]; arg[m] = bidx[0]; }
}

// ---------------- fused gather+fold (vectorized) + S1/S2 finalize ----------------
// blocks [0,256): T3 (1 ch/block, plane+arg in LDS); [256,1280): T2 float2; [1280,2304): T1 float4;
// [2304,2312): S1/S2 reduce from cmax
__global__ __launch_bounds__(256) void k_tfold(const float* __restrict__ ref3, const float* __restrict__ ref2,
                                               const float* __restrict__ ref1, const int* __restrict__ arg,
                                               const float* __restrict__ cmax1, const float* __restrict__ cmax2,
                                               float* __restrict__ out) {
  const int bid = blockIdx.x;
  const int tid = threadIdx.x;
  if (bid < 256) {
    __shared__ float plane[1024];
    __shared__ int argL[1024];
    const int c = bid;
#pragma unroll
    for (int k = 0; k < 4; ++k) {
      plane[k * 256 + tid] = ref3[(size_t)c * 1024 + k * 256 + tid];
      argL[k * 256 + tid] = arg[k * 256 + tid];
    }
    __syncthreads();
#pragma unroll
    for (int k = 0; k < 4; ++k) {
      int px = k * 256 + tid;
      int y = px >> 5, x = px & 31;
      float s = 0.f;
#pragma unroll
      for (int di = -1; di <= 1; ++di) {
        int i = y + di;
        if ((unsigned)i >= 32u) continue;
#pragma unroll
        for (int dj = -1; dj <= 1; ++dj) {
          int jw = x + dj;
          if ((unsigned)jw >= 32u) continue;
          int n2 = argL[i * 32 + jw];
          int rr = (n2 >> 5) + y - i, cc = (n2 & 31) + x - jw;
          if ((unsigned)rr < 32u && (unsigned)cc < 32u) s += plane[rr * 32 + cc];
        }
      }
      out[3072 + (size_t)c * 1024 + px] = s * (1.f / 9.f);
    }
  } else if (bid < 1280) {
    __shared__ int argL[1024];
#pragma unroll
    for (int k = 0; k < 4; ++k) argL[k * 256 + tid] = arg[k * 256 + tid];
    __syncthreads();
    int id2 = (bid - 256) * 256 + tid;
    int q = id2 & 31, y = (id2 >> 5) & 63, c = id2 >> 11;
    int iy = y >> 1;
    float s0 = 0.f, s1 = 0.f;
#pragma unroll
    for (int di = -1; di <= 1; ++di) {
      int i = iy + di;
      if ((unsigned)i >= 32u) continue;
      int ry = y - 2 * i;
#pragma unroll
      for (int dj = -1; dj <= 1; ++dj) {
        int jw = q + dj;
        if ((unsigned)jw >= 32u) continue;
        int n2 = argL[i * 32 + jw];
        int rr = (n2 >> 5) * 2 + ry;
        int cb = (n2 & 31) * 2 + 2 * (q - jw);
        if ((unsigned)rr < 64u && (unsigned)cb < 63u) {
          const float* p = ref2 + (size_t)c * 4096 + rr * 64 + cb;
          s0 += p[0]; s1 += p[1];
        }
      }
    }
    float2 o; o.x = s0 * (1.f / 9.f); o.y = s1 * (1.f / 9.f);
    *(float2*)(out + 265216 + (size_t)c * 4096 + y * 64 + 2 * q) = o;
  } else if (bid < 2304) {
    __shared__ int argL[1024];
#pragma unroll
    for (int k = 0; k < 4; ++k) argL[k * 256 + tid] = arg[k * 256 + tid];
    __syncthreads();
    int id1 = (bid - 1280) * 256 + tid;
    int q = id1 & 31, y = (id1 >> 5) & 127, c = id1 >> 12;
    int iy = y >> 2;
    f32x4 s = {0.f, 0.f, 0.f, 0.f};
#pragma unroll
    for (int di = -1; di <= 1; ++di) {
      int i = iy + di;
      if ((unsigned)i >= 32u) continue;
      int ry = y - 4 * i;
#pragma unroll
      for (int dj = -1; dj <= 1; ++dj) {
        int jw = q + dj;
        if ((unsigned)jw >= 32u) continue;
        int n2 = argL[i * 32 + jw];
        int rr = (n2 >> 5) * 4 + ry;
        int cb = (n2 & 31) * 4 + 4 * (q - jw);
        if ((unsigned)rr < 128u && (unsigned)cb < 125u) {
          f32x4 v = *(const f32x4*)(ref1 + (size_t)c * 16384 + rr * 128 + cb);
          s += v;
        }
      }
    }
    s *= (1.f / 9.f);
    *(f32x4*)(out + 789504 + (size_t)c * 16384 + y * 128 + 4 * q) = s;
  } else {
    int t = (bid - 2304) * 256 + tid;  // 0..2047
    if (t < 1024) {
      float mx = -3.0e38f;
      for (int rb = 0; rb < 128; ++rb) mx = fmaxf(mx, cmax1[rb * 1024 + t]);
      out[t] = mx;            // S_1
    } else {
      int tt = t - 1024;
      float mx = -3.0e38f;
      for (int rb = 0; rb < 32; ++rb) mx = fmaxf(mx, cmax2[rb * 1024 + tt]);
      out[1024 + tt] = mx;    // S_2
    }
  }
}

// ---------------- workspace layout (bytes) ----------------
static constexpr size_t OFF_BW2     = 0;                        // 1152 f32
static constexpr size_t OFF_BW1     = 4608;                     // 640 f32
static constexpr size_t ZERO_BYTES  = 7168;
static constexpr size_t OFF_BB      = 7168;                     // 2 f32 (pad to 256)
static constexpr size_t OFF_BL2     = 7424;                     // 1024 f32
static constexpr size_t OFF_BL1     = 11520;                    // 1024 f32
static constexpr size_t OFF_SCLR    = 15616;                    // 1024 f32
static constexpr size_t OFF_SCU3    = 19712;                    // 1024 f32
static constexpr size_t OFF_R3ARG   = 23808;                    // 1024 int
static constexpr size_t OFF_PNSQ2   = 27904;                    // f32 [18][4096]
static constexpr size_t OFF_PBWD2   = OFF_PNSQ2 + 294912;       // f32 [18][4096]
static constexpr size_t OFF_PNSQ1   = OFF_PBWD2 + 294912;       // f32 [10][16384]
static constexpr size_t OFF_PBWD1   = OFF_PNSQ1 + 655360;       // f32 [10][16384]
static constexpr size_t OFF_CMAX2   = OFF_PBWD1 + 655360;       // f32 [32][1024]
static constexpr size_t OFF_CMAX1   = OFF_CMAX2 + 131072;       // f32 [128][1024]
static constexpr size_t OFF_NINV2   = OFF_CMAX1 + 524288;       // f32 [4096]
static constexpr size_t OFF_NINV1   = OFF_NINV2 + 16384;        // f32 [16384]
static constexpr size_t OFF_LR3NBT  = OFF_NINV1 + 65536;        // bf16 [1024][2304]
static constexpr size_t OFF_U2B     = OFF_LR3NBT + 4718592;     // bf16 [4096][1152]
static constexpr size_t OFF_U1B     = OFF_U2B    + 9437184;     // bf16 [16384][640]
static constexpr size_t OFF_W1T     = OFF_U1B    + 20971520;    // bf16 [1152][2304]
static constexpr size_t OFF_W2T     = OFF_W1T    + 5308416;     // bf16 [640][2304] (rows 576+ zero)
static constexpr size_t OFF_A2      = OFF_W2T    + 2949120;     // bf16 [1152][1152]
static constexpr size_t OFF_A1      = OFF_A2     + 2654208;     // bf16 [640][640]
static constexpr size_t OFF_M2T     = OFF_A1     + 819200;      // bf16 [1024][1152]
static constexpr size_t OFF_M1T     = OFF_M2T    + 2359296;     // bf16 [1024][640]
static constexpr size_t OFF_G2      = OFF_M1T    + 1310720;     // f32 [1024][1024]

extern "C" void kernel_launch(void* const* d_in, const int* in_sizes, int n_in,
                              void* d_out, int out_size, void* d_ws, size_t ws_size,
                              hipStream_t stream) {
  (void)in_sizes; (void)n_in; (void)out_size; (void)ws_size;
  const float* lrsr3  = (const float*)d_in[0];
  const float* rsr1   = (const float*)d_in[1];
  const float* rsr2   = (const float*)d_in[2];
  const float* rsr3   = (const float*)d_in[3];
  const float* ref1   = (const float*)d_in[4];
  const float* ref2   = (const float*)d_in[5];
  const float* ref3   = (const float*)d_in[6];
  const float* W1     = (const float*)d_in[7];
  const float* b1     = (const float*)d_in[8];
  const float* W2     = (const float*)d_in[9];
  const float* b2     = (const float*)d_in[10];
  float* out = (float*)d_out;
  char* ws = (char*)d_ws;

  float*          bw2     = (float*)(ws + OFF_BW2);
  float*          bw1     = (float*)(ws + OFF_BW1);
  float*          bb      = (float*)(ws + OFF_BB);
  float*          bl2     = (float*)(ws + OFF_BL2);
  float*          bl1     = (float*)(ws + OFF_BL1);
  float*          sclr    = (float*)(ws + OFF_SCLR);
  float*          scu3    = (float*)(ws + OFF_SCU3);
  int*            R3arg   = (int*)(ws + OFF_R3ARG);
  float*          pnsq2   = (float*)(ws + OFF_PNSQ2);
  float*          pbwd2   = (float*)(ws + OFF_PBWD2);
  float*          pnsq1   = (float*)(ws + OFF_PNSQ1);
  float*          pbwd1   = (float*)(ws + OFF_PBWD1);
  float*          cmax2   = (float*)(ws + OFF_CMAX2);
  float*          cmax1   = (float*)(ws + OFF_CMAX1);
  float*          ninv2   = (float*)(ws + OFF_NINV2);
  float*          ninv1   = (float*)(ws + OFF_NINV1);
  unsigned short* lr3nbT  = (unsigned short*)(ws + OFF_LR3NBT);
  unsigned short* U2b     = (unsigned short*)(ws + OFF_U2B);
  unsigned short* U1b     = (unsigned short*)(ws + OFF_U1B);
  unsigned short* W1t     = (unsigned short*)(ws + OFF_W1T);
  unsigned short* W2t     = (unsigned short*)(ws + OFF_W2T);
  unsigned short* A2b     = (unsigned short*)(ws + OFF_A2);
  unsigned short* A1b     = (unsigned short*)(ws + OFF_A1);
  unsigned short* M2tb    = (unsigned short*)(ws + OFF_M2T);
  unsigned short* M1tb    = (unsigned short*)(ws + OFF_M1T);
  float*          G2      = (float*)(ws + OFF_G2);

  hipMemsetAsync(d_ws, 0, ZERO_BYTES, stream);
  // zero pad rows 576..639 of W2t
  hipMemsetAsync(ws + OFF_W2T + (size_t)576 * 2304 * 2, 0, (size_t)64 * 2304 * 2, stream);

  // norms + bias dots + pixel Gram (R3 path, all fp32)
  k_colnorm2<<<2048, 256, 0, stream>>>(lrsr3, rsr3, b1, b2, sclr, scu3, bl2, bl1);
  k_pixgram<<<dim3(32, 32), 256, 0, stream>>>(lrsr3, rsr3, G2);
  k_r3max<<<1024, 256, 0, stream>>>(G2, scu3, sclr, out + 2048, R3arg);

  // unfolds / transposes for the bf16 score paths (8-wide vectorized)
  k_pass2_md_bf<<<1152, 256, 0, stream>>>(lrsr3, sclr, lr3nbT);
  k_unfold2<<<7424, 256, 0, stream>>>(rsr2, rsr1, U2b, U1b);
  k_wtrans2<<<dim3(27, 36), 256, 0, stream>>>(W1, W2, W1t, W2t);
  k_bwbb<<<dim3(8, 10), 256, 0, stream>>>(W1, W2, b1, b2, bw2, bw1, bb);

  Job jz = {};

  // P: Gram matrices + M^T, fused across row-concat [Wt ; lr3nbT]  (NBUF=3 counted: 1 block/CU regime)
  {
    Job a = jz, b = jz;
    a.Alo = W1t; a.Ahi = lr3nbT; a.Msplit = 1152; a.Bt = W1t;
    a.Clo = A2b; a.Chi = M2tb; a.N = 1152; a.K = 2304; a.nbx = 9;
    b.Alo = W2t; b.Ahi = lr3nbT; b.Msplit = 640; b.Bt = W2t;
    b.Clo = A1b; b.Chi = M1tb; b.N = 640; b.K = 2304; b.nbx = 5;
    k_gP<<<153 + 65, 256, 0, stream>>>(a, b, 153);
  }
  // E1: per-(colblock,half) norm/bw partials (NBUF=1 m97 loop: 4 blocks/CU TLP)
  {
    Job a = jz, b = jz;
    a.Alo = U2b; a.Ahi = U2b; a.Msplit = 4096; a.Bt = A2b;
    a.bw = bw2; a.pnsq = pnsq2; a.pbwd = pbwd2; a.Mtot = 4096;
    a.N = 1152; a.K = 1152; a.nbx = 9;
    b.Alo = U1b; b.Ahi = U1b; b.Msplit = 16384; b.Bt = A1b;
    b.bw = bw1; b.pnsq = pnsq1; b.pbwd = pbwd1; b.Mtot = 16384;
    b.N = 640; b.K = 640; b.nbx = 5;
    k_gE1<<<288 + 640, 256, 0, stream>>>(a, b, 288);
  }
  // ninv finalize: one pass over the partials
  k_ninv<<<80, 256, 0, stream>>>(pnsq2, pbwd2, pnsq1, pbwd1, bb, ninv2, ninv1);
  // E2: score max (NBUF=1 m97 loop)
  {
    Job a = jz, b = jz;
    a.Alo = U2b; a.Ahi = U2b; a.Msplit = 4096; a.Bt = M2tb;
    a.bl = bl2; a.ninv = ninv2; a.cmax = cmax2; a.Mtot = 4096;
    a.N = 1024; a.K = 1152; a.nbx = 8;
    b.Alo = U1b; b.Ahi = U1b; b.Msplit = 16384; b.Bt = M1tb;
    b.bl = bl1; b.ninv = ninv1; b.cmax = cmax1; b.Mtot = 16384;
    b.N = 1024; b.K = 640; b.nbx = 8;
    k_gE2<<<256 + 1024, 256, 0, stream>>>(a, b, 256);
  }

  // transfer + S1/S2 finalize (fused, vectorized gathers)
  k_tfold<<<2312, 256, 0, stream>>>(ref3, ref2, ref1, R3arg, cmax1, cmax2, out);
}

// Round 13
// 276.607 us; speedup vs baseline: 1.2185x; 1.0653x over previous
//
#include <hip/hip_runtime.h>

typedef short bf8 __attribute__((ext_vector_type(8)));
typedef float f32x4 __attribute__((ext_vector_type(4)));

static __device__ __forceinline__ unsigned short f2bf(float f) {
  unsigned u = __float_as_uint(f);
  unsigned r = u + 0x7FFFu + ((u >> 16) & 1u);
  return (unsigned short)(r >> 16);
}
static __device__ __forceinline__ float bf2f(unsigned short h) {
  return __uint_as_float(((unsigned)h) << 16);
}
// order-preserving float<->u32 key (for LDS atomicMax only)
static __device__ __forceinline__ unsigned fkey(float f) {
  unsigned u = __float_as_uint(f);
  return (u & 0x80000000u) ? ~u : (u | 0x80000000u);
}
static __device__ __forceinline__ float kdec(unsigned k) {
  unsigned u = (k & 0x80000000u) ? (k & 0x7FFFFFFFu) : ~k;
  return __uint_as_float(u);
}

// async global->LDS, 16B per lane. lds dest: wave-uniform base + lane*16.
static __device__ __forceinline__ void gload_lds16(const unsigned short* g, unsigned short* l) {
  __builtin_amdgcn_global_load_lds((const __attribute__((address_space(1))) void*)g,
                                   (__attribute__((address_space(3))) void*)l, 16, 0, 0);
}

// unfold(k=3,pad=1,stride=1) value: row d = (cc*3+ki)*3+kj, col m = i*S+j, src [C][S][S]
static __device__ __forceinline__ float uf3(const float* __restrict__ src, int lgS, int d, int m) {
  const int S = 1 << lgS;
  int cc = d / 9;
  int r9 = d - cc * 9;
  int ki = r9 / 3;
  int kj = r9 - ki * 3;
  int i = (m >> lgS) + ki - 1;
  int j = (m & (S - 1)) + kj - 1;
  if ((unsigned)i >= (unsigned)S || (unsigned)j >= (unsigned)S) return 0.f;
  return src[((size_t)cc << (2 * lgS)) + ((size_t)i << lgS) + j];
}

// ---------------- prep dispatch A: colnorms+bias-dots || pixel Gram ----------------
// blocks [0,1024): colnorm+bias-dots of lrsr3 -> sclr, bl2, bl1
// blocks [1024,2048): colnorm of rsr3 -> scu3
// blocks [2048,3072): pixgram 32x32 tiles -> G2
__global__ __launch_bounds__(256) void k_prepA(const float* __restrict__ lrsr3, const float* __restrict__ rsr3,
                                               const float* __restrict__ b1, const float* __restrict__ b2,
                                               float* __restrict__ sclr, float* __restrict__ scu3,
                                               float* __restrict__ bl2, float* __restrict__ bl1,
                                               float* __restrict__ G2) {
  __shared__ float r0[256], r1[256], r2[256];
  __shared__ float As[16][32], Bs[16][32];
  const int blk = blockIdx.x;
  const int tid = threadIdx.x;
  if (blk < 2048) {
    const bool lr = blk < 1024;
    const int m = blk & 1023;
    const float* src = lr ? lrsr3 : rsr3;
    float s = 0.f, d1 = 0.f, d2 = 0.f;
    for (int d = tid; d < 2304; d += 256) {
      float v = uf3(src, 5, d, m);
      s += v * v; d1 += b1[d] * v; d2 += b2[d] * v;
    }
    r0[tid] = s; r1[tid] = d1; r2[tid] = d2;
    __syncthreads();
    for (int o = 128; o > 0; o >>= 1) {
      if (tid < o) { r0[tid] += r0[tid + o]; r1[tid] += r1[tid + o]; r2[tid] += r2[tid + o]; }
      __syncthreads();
    }
    if (tid == 0) {
      float sc = 1.f / fmaxf(sqrtf(r0[0]), 1e-12f);
      if (lr) { sclr[m] = sc; bl2[m] = r1[0] * sc; bl1[m] = r2[0] * sc; }
      else    { scu3[m] = sc; }
    }
  } else {
    const int px = blk - 2048;
    const int m0 = (px >> 5) * 32, n0 = (px & 31) * 32;
    const int tx = tid & 15, ty = tid >> 4;
    float acc[2][2] = {};
    for (int kb = 0; kb < 256; kb += 16) {
      __syncthreads();
      {
        int kk = tid >> 5, mm = tid & 31;
        As[kk][mm] = lrsr3[(size_t)(kb + kk) * 1024 + m0 + mm];
        Bs[kk][mm] = rsr3[(size_t)(kb + kk) * 1024 + n0 + mm];
        int e2 = tid + 256; int kk2 = e2 >> 5, mm2 = e2 & 31;
        As[kk2][mm2] = lrsr3[(size_t)(kb + kk2) * 1024 + m0 + mm2];
        Bs[kk2][mm2] = rsr3[(size_t)(kb + kk2) * 1024 + n0 + mm2];
      }
      __syncthreads();
#pragma unroll
      for (int kk = 0; kk < 16; ++kk) {
        float a0 = As[kk][ty * 2], a1 = As[kk][ty * 2 + 1];
        float b0 = Bs[kk][tx * 2], b1v = Bs[kk][tx * 2 + 1];
        acc[0][0] = fmaf(a0, b0, acc[0][0]); acc[0][1] = fmaf(a0, b1v, acc[0][1]);
        acc[1][0] = fmaf(a1, b0, acc[1][0]); acc[1][1] = fmaf(a1, b1v, acc[1][1]);
      }
    }
#pragma unroll
    for (int i = 0; i < 2; ++i)
#pragma unroll
      for (int jj = 0; jj < 2; ++jj)
        G2[(size_t)(m0 + ty * 2 + i) * 1024 + (n0 + tx * 2 + jj)] = acc[i][jj];
  }
}

// ---------------- prep dispatch B: pass2 || unfolds || W transposes || bw/bb || r3max ----------------
// [0,1152): normalized unfold lrsr3 -> lr3nbT (bf16x8)
// [1152,8576): unfold rsr2 -> U2b, rsr1 -> U1b (bf16x8)
// [8576,9548): W transposes (LDS tiled)
// [9548,9628): bw dots + bb
// [9628,10652): R3 max/argmax from pixel Gram (9-point diagonal-shift sum)
__global__ __launch_bounds__(256) void k_prepB(const float* __restrict__ lrsr3,
                                               const float* __restrict__ rsr2, const float* __restrict__ rsr1,
                                               const float* __restrict__ W1, const float* __restrict__ W2,
                                               const float* __restrict__ b1, const float* __restrict__ b2,
                                               const float* __restrict__ sclr, const float* __restrict__ scu3,
                                               const float* __restrict__ G2,
                                               unsigned short* __restrict__ lr3nbT,
                                               unsigned short* __restrict__ U2b, unsigned short* __restrict__ U1b,
                                               unsigned short* __restrict__ W1t, unsigned short* __restrict__ W2t,
                                               float* __restrict__ bw2, float* __restrict__ bw1,
                                               float* __restrict__ bb,
                                               float* __restrict__ s3, int* __restrict__ arg) {
  __shared__ unsigned short Ls[64][65];
  __shared__ float bv[256]; __shared__ int bidx[256];
  const int blk = blockIdx.x;
  const int tid = threadIdx.x;
  if (blk < 1152) {
    int id8 = blk * 256 + tid;                 // < 294912 = 1024*288
    int m = id8 / 288, c0 = (id8 - m * 288) * 8;
    float sc = sclr[m];
    bf8 v;
#pragma unroll
    for (int e = 0; e < 8; ++e) v[e] = (short)f2bf(uf3(lrsr3, 5, c0 + e, m) * sc);
    *(bf8*)(lr3nbT + (size_t)m * 2304 + c0) = v;
  } else if (blk < 8576) {
    int bid = blk - 1152;
    if (bid < 2304) {
      int id8 = bid * 256 + tid;               // < 589824
      int n = id8 / 144, c0 = (id8 - n * 144) * 8;
      bf8 v;
#pragma unroll
      for (int e = 0; e < 8; ++e) v[e] = (short)f2bf(uf3(rsr2, 6, c0 + e, n));
      *(bf8*)(U2b + (size_t)n * 1152 + c0) = v;
    } else {
      int id8 = (bid - 2304) * 256 + tid;      // < 1310720
      int n = id8 / 80, c0 = (id8 - n * 80) * 8;
      bf8 v;
#pragma unroll
      for (int e = 0; e < 8; ++e) {
        int c = c0 + e;
        v[e] = (short)((c < 576) ? f2bf(uf3(rsr1, 7, c, n)) : (unsigned short)0);
      }
      *(bf8*)(U1b + (size_t)n * 640 + c0) = v;
    }
  } else if (blk < 9548) {
    int idx = blk - 8576;
    int xx = idx % 27, yy = idx / 27;          // yy < 36
    const float* W; unsigned short* Wt; int Cw, c0;
    if (xx < 18) { W = W1; Wt = W1t; Cw = 1152; c0 = xx * 64; }
    else         { W = W2; Wt = W2t; Cw = 576;  c0 = (xx - 18) * 64; }
    const int d0 = yy * 64;
#pragma unroll
    for (int i = 0; i < 16; ++i) {
      int id = tid + i * 256;
      int r = id >> 6, c = id & 63;
      Ls[r][c] = f2bf(W[(size_t)(d0 + r) * Cw + c0 + c]);
    }
    __syncthreads();
#pragma unroll
    for (int i = 0; i < 16; ++i) {
      int id = tid + i * 256;
      int cc = id >> 6, rr = id & 63;
      Wt[(size_t)(c0 + cc) * 2304 + d0 + rr] = Ls[rr][cc];
    }
  } else if (blk < 9628) {
    int idx = blk - 9548;
    int x = idx & 7, y = idx >> 3;             // y < 10
    if (y == 9) {
      if (x >= 2) return;
      const float* b = x ? b2 : b1;
      float s = 0.f;
      for (int d = tid; d < 2304; d += 256) s += b[d] * b[d];
      bv[tid] = s; __syncthreads();
      for (int o = 128; o > 0; o >>= 1) { if (tid < o) bv[tid] += bv[tid + o]; __syncthreads(); }
      if (tid == 0) bb[x] = bv[0];
      return;
    }
    const bool two = x < 5;
    const float* W = two ? W1 : W2;
    const float* b = two ? b1 : b2;
    float* bw = two ? bw2 : bw1;
    const int Cw = two ? 1152 : 576;
    int c = (two ? x : x - 5) * 256 + tid;
    if (c >= Cw) return;
    int d0 = y * 256;
    float s = 0.f;
    for (int d = d0; d < d0 + 256; ++d) s += b[d] * W[(size_t)d * Cw + c];
    atomicAdd(&bw[c], s);
  } else {
    const int m = blk - 9628;
    const int mi = m >> 5, mj = m & 31;
    float best = -3.0e38f; int bi = 0;
    for (int n = tid; n < 1024; n += 256) {
      const int ni = n >> 5, nj = n & 31;
      float raw = 0.f;
#pragma unroll
      for (int dy = -1; dy <= 1; ++dy) {
#pragma unroll
        for (int dx = -1; dx <= 1; ++dx) {
          bool vm = ((unsigned)(mi + dy) < 32u) && ((unsigned)(mj + dx) < 32u);
          bool vn = ((unsigned)(ni + dy) < 32u) && ((unsigned)(nj + dx) < 32u);
          if (vm && vn) {
            int off = dy * 32 + dx;
            raw += G2[(size_t)(m + off) * 1024 + (n + off)];
          }
        }
      }
      float v = raw * scu3[n];
      if (v > best) { best = v; bi = n; }
    }
    bv[tid] = best; bidx[tid] = bi;
    __syncthreads();
    for (int o = 128; o > 0; o >>= 1) {
      if (tid < o) {
        float ov = bv[tid + o]; int oi = bidx[tid + o];
        if (ov > bv[tid] || (ov == bv[tid] && oi < bidx[tid])) { bv[tid] = ov; bidx[tid] = oi; }
      }
      __syncthreads();
    }
    if (tid == 0) { s3[m] = bv[0] * sclr[m]; arg[m] = bidx[0]; }
  }
}

// ---------------- bf16 MFMA GEMM body: 128x128 tile, BK=64, 4 waves, XCD-chunked ----------------
// NBUF==1: m97 structure — single buffer, 32KB LDS (4 blocks/CU), stage -> sync -> MFMA -> sync.
// NBUF>=2: counted-vmcnt rotating pipeline (for 1-block/CU grids, e.g. P).
// TN: C[i][j] = sum_k A[i][k]*Bt[j][k].  Two jobs per dispatch (logical id < nb0 -> j0).
// EPI 0: store bf16 C.  EPI 1: per-(colblock,wave-half) partials (unique writer slot = bx*2+wc).
// EPI 2: per-block ninv from partials (LDS prologue), cmax[by][j] = max_i (C[i][j]+bl[j])*ninv[i].
struct Job {
  const unsigned short* Alo;
  const unsigned short* Ahi;
  const unsigned short* Bt;
  unsigned short* Clo;
  unsigned short* Chi;
  const float* bl;
  const float* bw;
  const float* bbp;
  float* pnsq;
  float* pbwd;
  float* cmax;
  int Msplit, N, K, nbx, Mtot, npart, which;
};

template <int EPI, int NBUF>
static __device__ __forceinline__ void gemm_body(const Job& j0, const Job& j1, int nb0) {
  __shared__ __align__(16) unsigned short As[NBUF][128 * 64];
  __shared__ __align__(16) unsigned short Bs[NBUF][128 * 64];
  __shared__ unsigned colkey[128];
  __shared__ float ninvL[128];

  // bijective XCD-chunked swizzle (m204)
  const int nwg = (int)gridDim.x;
  const int h = (int)blockIdx.x;
  const int qq = nwg >> 3, rm = nwg & 7;
  const int xcd = h & 7, wth = h >> 3;
  const int bid = (xcd < rm ? xcd * (qq + 1) : rm * (qq + 1) + (xcd - rm) * qq) + wth;

  const bool first = (bid < nb0);
  const Job j = first ? j0 : j1;
  const int local = bid - (first ? 0 : nb0);
  const int by = local / j.nbx;
  const int bx = local - by * j.nbx;
  const int m0 = by * 128, n0 = bx * 128;
  const int K = j.K, N = j.N;

  const unsigned short* Abase = (m0 < j.Msplit)
      ? j.Alo + (size_t)m0 * K
      : j.Ahi + (size_t)(m0 - j.Msplit) * K;

  const int tid = threadIdx.x;
  const int l = tid & 63;
  const int w = tid >> 6;
  const int wr = w >> 1, wc = w & 1;
  if (EPI == 2) {
    if (tid < 128) {
      colkey[tid] = 0u;
      // per-block ninv from partials: 1 row/thread, fixed summation order (deterministic)
      const int r = m0 + tid;
      float nsq = 0.f, bwd = 0.f;
      for (int p = 0; p < j.npart; ++p) {
        nsq += j.pnsq[(size_t)p * j.Mtot + r];
        bwd += j.pbwd[(size_t)p * j.Mtot + r];
      }
      float tq = nsq + 2.f * bwd + j.bbp[j.which];
      ninvL[tid] = 1.f / fmaxf(sqrtf(fmaxf(tq, 0.f)), 1e-12f);
    }
  }

  f32x4 acc[4][4] = {};

  // staging: wave w stages rows [w*32, w*32+32) in 4 chunks of 8 rows.
  // Pre-swizzle GLOBAL source so LDS slot q of row r holds global slot q^(r&7).
  const int srow = w * 32;
  const int lrow = l >> 3;
  const int gcol = ((l & 7) ^ lrow) * 8;
  const int mr = l & 15;
  const int kg = l >> 4;

  const int nt = K >> 6;
  const int snap_kb = n0 + wc * 64;
  unsigned short snap[4][4][4];

  auto stage = [&](int buf, int kb) {
#pragma unroll
    for (int i = 0; i < 4; ++i) {
      int r = srow + i * 8;
      gload_lds16(Abase + (size_t)(r + lrow) * K + kb + gcol, &As[buf][r * 64]);
      gload_lds16(j.Bt + (size_t)(n0 + r + lrow) * K + kb + gcol, &Bs[buf][r * 64]);
    }
  };
  auto compute_tile = [&](int cur) {
#pragma unroll
    for (int ks = 0; ks < 2; ++ks) {
      bf8 af[4], bv[4];
#pragma unroll
      for (int mi = 0; mi < 4; ++mi) {
        const int row = wr * 64 + mi * 16 + mr;
        af[mi] = *(const bf8*)&As[cur][row * 64 + (((ks * 4 + kg) ^ (row & 7)) * 8)];
      }
#pragma unroll
      for (int ni = 0; ni < 4; ++ni) {
        const int row = wc * 64 + ni * 16 + mr;
        bv[ni] = *(const bf8*)&Bs[cur][row * 64 + (((ks * 4 + kg) ^ (row & 7)) * 8)];
      }
      __builtin_amdgcn_s_setprio(1);
#pragma unroll
      for (int mi = 0; mi < 4; ++mi)
#pragma unroll
        for (int ni = 0; ni < 4; ++ni)
          acc[mi][ni] = __builtin_amdgcn_mfma_f32_16x16x32_bf16(af[mi], bv[ni], acc[mi][ni], 0, 0, 0);
      __builtin_amdgcn_s_setprio(0);
    }
  };
  auto do_snap = [&](int cur) {
#pragma unroll
    for (int mi = 0; mi < 4; ++mi)
#pragma unroll
      for (int e = 0; e < 4; ++e) {
        const int row = wr * 64 + mi * 16 + kg * 4 + e;
#pragma unroll
        for (int ni = 0; ni < 4; ++ni) {
          const int slot = ni * 2 + (mr >> 3);
          snap[mi][ni][e] = As[cur][row * 64 + ((slot ^ (row & 7)) * 8) + (mr & 7)];
        }
      }
  };

  if constexpr (NBUF == 1) {
    // m97 single-buffer loop: TLP across 4 resident blocks hides staging latency.
    for (int t = 0; t < nt; ++t) {
      if (t) __syncthreads();              // all waves done reading LDS before overwrite
      stage(0, t << 6);
      __syncthreads();                     // vmcnt(0)+lgkmcnt(0) drain: tile visible
      compute_tile(0);
      if (EPI == 1 && (t << 6) == snap_kb) do_snap(0);
    }
  } else {
    auto waitv = [&](int Wt) {
      if (Wt >= 2)      asm volatile("s_waitcnt vmcnt(16)\ns_barrier" ::: "memory");
      else if (Wt == 1) asm volatile("s_waitcnt vmcnt(8)\ns_barrier" ::: "memory");
      else              asm volatile("s_waitcnt vmcnt(0)\ns_barrier" ::: "memory");
    };
#pragma unroll
    for (int p = 0; p < NBUF; ++p) if (p < nt) stage(p, p << 6);
    { int inflight = (NBUF < nt ? NBUF : nt); waitv(inflight - 1); }
    int cur = 0;
    for (int t = 0; t < nt; ++t) {
      compute_tile(cur);
      if (EPI == 1 && (t << 6) == snap_kb) do_snap(cur);
      if (t + 1 < nt) {
        asm volatile("s_waitcnt lgkmcnt(0)\ns_barrier" ::: "memory");   // buf[cur] free everywhere
        if (t + NBUF < nt) stage(cur, (t + NBUF) << 6);                 // refill freed buffer
        const int im = (nt - 1 < t + NBUF) ? (nt - 1) : (t + NBUF);     // newest tile issued
        waitv(im - (t + 1));                                            // tile t+1 landed
        cur = (cur + 1 == NBUF) ? 0 : cur + 1;
      }
    }
  }

  // C/D frag layout: col = mr, row = kg*4 + e (within 16x16)
  const int lr0 = wr * 64;
  const int lc0 = wc * 64;
  if (EPI == 0) {
    unsigned short* Cbase = (m0 < j.Msplit)
        ? j.Clo + (size_t)m0 * N
        : j.Chi + (size_t)(m0 - j.Msplit) * N;
#pragma unroll
    for (int mi = 0; mi < 4; ++mi)
#pragma unroll
      for (int ni = 0; ni < 4; ++ni)
#pragma unroll
        for (int e = 0; e < 4; ++e)
          Cbase[(size_t)(lr0 + mi * 16 + kg * 4 + e) * (size_t)N + (n0 + lc0 + ni * 16 + mr)] = f2bf(acc[mi][ni][e]);
  } else if (EPI == 1) {
    float rp[4][4] = {};
    float bp[4][4] = {};
#pragma unroll
    for (int ni = 0; ni < 4; ++ni) {
      const float bwv = j.bw[n0 + lc0 + ni * 16 + mr];
#pragma unroll
      for (int mi = 0; mi < 4; ++mi)
#pragma unroll
        for (int e = 0; e < 4; ++e) {
          const float av = bf2f(snap[mi][ni][e]);
          rp[mi][e] += acc[mi][ni][e] * av;
          bp[mi][e] += bwv * av;
        }
    }
#pragma unroll
    for (int off = 1; off < 16; off <<= 1)
#pragma unroll
      for (int mi = 0; mi < 4; ++mi)
#pragma unroll
        for (int e = 0; e < 4; ++e) {
          rp[mi][e] += __shfl_xor(rp[mi][e], off);
          bp[mi][e] += __shfl_xor(bp[mi][e], off);
        }
    if (mr == 0) {
      // UNIQUE writer per (column-half slot = bx*2+wc, row)
      const size_t slotbase = (size_t)(bx * 2 + wc) * j.Mtot;
#pragma unroll
      for (int mi = 0; mi < 4; ++mi)
#pragma unroll
        for (int e = 0; e < 4; ++e) {
          const int r = m0 + lr0 + mi * 16 + kg * 4 + e;
          j.pnsq[slotbase + r] = rp[mi][e];
          j.pbwd[slotbase + r] = bp[mi][e];
        }
    }
  } else {
    float nv[4][4];
#pragma unroll
    for (int mi = 0; mi < 4; ++mi)
#pragma unroll
      for (int e = 0; e < 4; ++e)
        nv[mi][e] = ninvL[lr0 + mi * 16 + kg * 4 + e];   // LDS (block prologue)
#pragma unroll
    for (int ni = 0; ni < 4; ++ni) {
      float blv = j.bl[n0 + lc0 + ni * 16 + mr];
      float mx = -3.0e38f;
#pragma unroll
      for (int mi = 0; mi < 4; ++mi)
#pragma unroll
        for (int e = 0; e < 4; ++e) mx = fmaxf(mx, (acc[mi][ni][e] + blv) * nv[mi][e]);
      atomicMax(&colkey[lc0 + ni * 16 + mr], fkey(mx));   // LDS atomic only
    }
    __syncthreads();
    if (tid < 128) j.cmax[(size_t)by * 1024 + n0 + tid] = kdec(colkey[tid]);  // unique writer
  }
}

__global__ __launch_bounds__(256) void k_gP (Job a, Job b, int nb0) { gemm_body<0, 3>(a, b, nb0); }
__global__ __launch_bounds__(256) void k_gE1(Job a, Job b, int nb0) { gemm_body<1, 1>(a, b, nb0); }
__global__ __launch_bounds__(256) void k_gE2(Job a, Job b, int nb0) { gemm_body<2, 1>(a, b, nb0); }

// ---------------- fused gather+fold (vectorized) + S1/S2 finalize ----------------
// blocks [0,256): T3 (1 ch/block, plane+arg in LDS); [256,1280): T2 float2; [1280,2304): T1 float4;
// [2304,2312): S1/S2 reduce from cmax
__global__ __launch_bounds__(256) void k_tfold(const float* __restrict__ ref3, const float* __restrict__ ref2,
                                               const float* __restrict__ ref1, const int* __restrict__ arg,
                                               const float* __restrict__ cmax1, const float* __restrict__ cmax2,
                                               float* __restrict__ out) {
  const int bid = blockIdx.x;
  const int tid = threadIdx.x;
  if (bid < 256) {
    __shared__ float plane[1024];
    __shared__ int argL[1024];
    const int c = bid;
#pragma unroll
    for (int k = 0; k < 4; ++k) {
      plane[k * 256 + tid] = ref3[(size_t)c * 1024 + k * 256 + tid];
      argL[k * 256 + tid] = arg[k * 256 + tid];
    }
    __syncthreads();
#pragma unroll
    for (int k = 0; k < 4; ++k) {
      int px = k * 256 + tid;
      int y = px >> 5, x = px & 31;
      float s = 0.f;
#pragma unroll
      for (int di = -1; di <= 1; ++di) {
        int i = y + di;
        if ((unsigned)i >= 32u) continue;
#pragma unroll
        for (int dj = -1; dj <= 1; ++dj) {
          int jw = x + dj;
          if ((unsigned)jw >= 32u) continue;
          int n2 = argL[i * 32 + jw];
          int rr = (n2 >> 5) + y - i, cc = (n2 & 31) + x - jw;
          if ((unsigned)rr < 32u && (unsigned)cc < 32u) s += plane[rr * 32 + cc];
        }
      }
      out[3072 + (size_t)c * 1024 + px] = s * (1.f / 9.f);
    }
  } else if (bid < 1280) {
    __shared__ int argL[1024];
#pragma unroll
    for (int k = 0; k < 4; ++k) argL[k * 256 + tid] = arg[k * 256 + tid];
    __syncthreads();
    int id2 = (bid - 256) * 256 + tid;
    int q = id2 & 31, y = (id2 >> 5) & 63, c = id2 >> 11;
    int iy = y >> 1;
    float s0 = 0.f, s1 = 0.f;
#pragma unroll
    for (int di = -1; di <= 1; ++di) {
      int i = iy + di;
      if ((unsigned)i >= 32u) continue;
      int ry = y - 2 * i;
#pragma unroll
      for (int dj = -1; dj <= 1; ++dj) {
        int jw = q + dj;
        if ((unsigned)jw >= 32u) continue;
        int n2 = argL[i * 32 + jw];
        int rr = (n2 >> 5) * 2 + ry;
        int cb = (n2 & 31) * 2 + 2 * (q - jw);
        if ((unsigned)rr < 64u && (unsigned)cb < 63u) {
          const float* p = ref2 + (size_t)c * 4096 + rr * 64 + cb;
          s0 += p[0]; s1 += p[1];
        }
      }
    }
    float2 o; o.x = s0 * (1.f / 9.f); o.y = s1 * (1.f / 9.f);
    *(float2*)(out + 265216 + (size_t)c * 4096 + y * 64 + 2 * q) = o;
  } else if (bid < 2304) {
    __shared__ int argL[1024];
#pragma unroll
    for (int k = 0; k < 4; ++k) argL[k * 256 + tid] = arg[k * 256 + tid];
    __syncthreads();
    int id1 = (bid - 1280) * 256 + tid;
    int q = id1 & 31, y = (id1 >> 5) & 127, c = id1 >> 12;
    int iy = y >> 2;
    f32x4 s = {0.f, 0.f, 0.f, 0.f};
#pragma unroll
    for (int di = -1; di <= 1; ++di) {
      int i = iy + di;
      if ((unsigned)i >= 32u) continue;
      int ry = y - 4 * i;
#pragma unroll
      for (int dj = -1; dj <= 1; ++dj) {
        int jw = q + dj;
        if ((unsigned)jw >= 32u) continue;
        int n2 = argL[i * 32 + jw];
        int rr = (n2 >> 5) * 4 + ry;
        int cb = (n2 & 31) * 4 + 4 * (q - jw);
        if ((unsigned)rr < 128u && (unsigned)cb < 125u) {
          f32x4 v = *(const f32x4*)(ref1 + (size_t)c * 16384 + rr * 128 + cb);
          s += v;
        }
      }
    }
    s *= (1.f / 9.f);
    *(f32x4*)(out + 789504 + (size_t)c * 16384 + y * 128 + 4 * q) = s;
  } else {
    int t = (bid - 2304) * 256 + tid;  // 0..2047
    if (t < 1024) {
      float mx = -3.0e38f;
      for (int rb = 0; rb < 128; ++rb) mx = fmaxf(mx, cmax1[rb * 1024 + t]);
      out[t] = mx;            // S_1
    } else {
      int tt = t - 1024;
      float mx = -3.0e38f;
      for (int rb = 0; rb < 32; ++rb) mx = fmaxf(mx, cmax2[rb * 1024 + tt]);
      out[1024 + tt] = mx;    // S_2
    }
  }
}

// ---------------- workspace layout (bytes) ----------------
static constexpr size_t OFF_BW2     = 0;                        // 1152 f32
static constexpr size_t OFF_BW1     = 4608;                     // 640 f32
static constexpr size_t ZERO_BYTES  = 7168;
static constexpr size_t OFF_BB      = 7168;                     // 2 f32 (pad to 256)
static constexpr size_t OFF_BL2     = 7424;                     // 1024 f32
static constexpr size_t OFF_BL1     = 11520;                    // 1024 f32
static constexpr size_t OFF_SCLR    = 15616;                    // 1024 f32
static constexpr size_t OFF_SCU3    = 19712;                    // 1024 f32
static constexpr size_t OFF_R3ARG   = 23808;                    // 1024 int
static constexpr size_t OFF_PNSQ2   = 27904;                    // f32 [18][4096]
static constexpr size_t OFF_PBWD2   = OFF_PNSQ2 + 294912;       // f32 [18][4096]
static constexpr size_t OFF_PNSQ1   = OFF_PBWD2 + 294912;       // f32 [10][16384]
static constexpr size_t OFF_PBWD1   = OFF_PNSQ1 + 655360;       // f32 [10][16384]
static constexpr size_t OFF_CMAX2   = OFF_PBWD1 + 655360;       // f32 [32][1024]
static constexpr size_t OFF_CMAX1   = OFF_CMAX2 + 131072;       // f32 [128][1024]
static constexpr size_t OFF_LR3NBT  = OFF_CMAX1 + 524288;       // bf16 [1024][2304]
static constexpr size_t OFF_U2B     = OFF_LR3NBT + 4718592;     // bf16 [4096][1152]
static constexpr size_t OFF_U1B     = OFF_U2B    + 9437184;     // bf16 [16384][640]
static constexpr size_t OFF_W1T     = OFF_U1B    + 20971520;    // bf16 [1152][2304]
static constexpr size_t OFF_W2T     = OFF_W1T    + 5308416;     // bf16 [640][2304] (rows 576+ zero)
static constexpr size_t OFF_A2      = OFF_W2T    + 2949120;     // bf16 [1152][1152]
static constexpr size_t OFF_A1      = OFF_A2     + 2654208;     // bf16 [640][640]
static constexpr size_t OFF_M2T     = OFF_A1     + 819200;      // bf16 [1024][1152]
static constexpr size_t OFF_M1T     = OFF_M2T    + 2359296;     // bf16 [1024][640]
static constexpr size_t OFF_G2      = OFF_M1T    + 1310720;     // f32 [1024][1024]

extern "C" void kernel_launch(void* const* d_in, const int* in_sizes, int n_in,
                              void* d_out, int out_size, void* d_ws, size_t ws_size,
                              hipStream_t stream) {
  (void)in_sizes; (void)n_in; (void)out_size; (void)ws_size;
  const float* lrsr3  = (const float*)d_in[0];
  const float* rsr1   = (const float*)d_in[1];
  const float* rsr2   = (const float*)d_in[2];
  const float* rsr3   = (const float*)d_in[3];
  const float* ref1   = (const float*)d_in[4];
  const float* ref2   = (const float*)d_in[5];
  const float* ref3   = (const float*)d_in[6];
  const float* W1     = (const float*)d_in[7];
  const float* b1     = (const float*)d_in[8];
  const float* W2     = (const float*)d_in[9];
  const float* b2     = (const float*)d_in[10];
  float* out = (float*)d_out;
  char* ws = (char*)d_ws;

  float*          bw2     = (float*)(ws + OFF_BW2);
  float*          bw1     = (float*)(ws + OFF_BW1);
  float*          bb      = (float*)(ws + OFF_BB);
  float*          bl2     = (float*)(ws + OFF_BL2);
  float*          bl1     = (float*)(ws + OFF_BL1);
  float*          sclr    = (float*)(ws + OFF_SCLR);
  float*          scu3    = (float*)(ws + OFF_SCU3);
  int*            R3arg   = (int*)(ws + OFF_R3ARG);
  float*          pnsq2   = (float*)(ws + OFF_PNSQ2);
  float*          pbwd2   = (float*)(ws + OFF_PBWD2);
  float*          pnsq1   = (float*)(ws + OFF_PNSQ1);
  float*          pbwd1   = (float*)(ws + OFF_PBWD1);
  float*          cmax2   = (float*)(ws + OFF_CMAX2);
  float*          cmax1   = (float*)(ws + OFF_CMAX1);
  unsigned short* lr3nbT  = (unsigned short*)(ws + OFF_LR3NBT);
  unsigned short* U2b     = (unsigned short*)(ws + OFF_U2B);
  unsigned short* U1b     = (unsigned short*)(ws + OFF_U1B);
  unsigned short* W1t     = (unsigned short*)(ws + OFF_W1T);
  unsigned short* W2t     = (unsigned short*)(ws + OFF_W2T);
  unsigned short* A2b     = (unsigned short*)(ws + OFF_A2);
  unsigned short* A1b     = (unsigned short*)(ws + OFF_A1);
  unsigned short* M2tb    = (unsigned short*)(ws + OFF_M2T);
  unsigned short* M1tb    = (unsigned short*)(ws + OFF_M1T);
  float*          G2      = (float*)(ws + OFF_G2);

  hipMemsetAsync(d_ws, 0, ZERO_BYTES, stream);
  // zero pad rows 576..639 of W2t
  hipMemsetAsync(ws + OFF_W2T + (size_t)576 * 2304 * 2, 0, (size_t)64 * 2304 * 2, stream);

  // A: colnorms + bias dots || pixel Gram
  k_prepA<<<3072, 256, 0, stream>>>(lrsr3, rsr3, b1, b2, sclr, scu3, bl2, bl1, G2);
  // B: normalized unfold || unfolds || W transposes || bw/bb || R3 argmax
  k_prepB<<<10652, 256, 0, stream>>>(lrsr3, rsr2, rsr1, W1, W2, b1, b2, sclr, scu3, G2,
                                     lr3nbT, U2b, U1b, W1t, W2t, bw2, bw1, bb, out + 2048, R3arg);

  Job jz = {};

  // P: Gram matrices + M^T, fused across row-concat [Wt ; lr3nbT]  (NBUF=3: 1 block/CU regime)
  {
    Job a = jz, b = jz;
    a.Alo = W1t; a.Ahi = lr3nbT; a.Msplit = 1152; a.Bt = W1t;
    a.Clo = A2b; a.Chi = M2tb; a.N = 1152; a.K = 2304; a.nbx = 9;
    b.Alo = W2t; b.Ahi = lr3nbT; b.Msplit = 640; b.Bt = W2t;
    b.Clo = A1b; b.Chi = M1tb; b.N = 640; b.K = 2304; b.nbx = 5;
    k_gP<<<153 + 65, 256, 0, stream>>>(a, b, 153);
  }
  // E1: per-(colblock,half) norm/bw partials (NBUF=1 m97 loop: 4 blocks/CU TLP)
  {
    Job a = jz, b = jz;
    a.Alo = U2b; a.Ahi = U2b; a.Msplit = 4096; a.Bt = A2b;
    a.bw = bw2; a.pnsq = pnsq2; a.pbwd = pbwd2; a.Mtot = 4096;
    a.N = 1152; a.K = 1152; a.nbx = 9;
    b.Alo = U1b; b.Ahi = U1b; b.Msplit = 16384; b.Bt = A1b;
    b.bw = bw1; b.pnsq = pnsq1; b.pbwd = pbwd1; b.Mtot = 16384;
    b.N = 640; b.K = 640; b.nbx = 5;
    k_gE1<<<288 + 640, 256, 0, stream>>>(a, b, 288);
  }
  // E2: score max (ninv computed per-block in prologue from partials; k_ninv dispatch removed)
  {
    Job a = jz, b = jz;
    a.Alo = U2b; a.Ahi = U2b; a.Msplit = 4096; a.Bt = M2tb;
    a.bl = bl2; a.pnsq = pnsq2; a.pbwd = pbwd2; a.bbp = bb;
    a.npart = 18; a.which = 0; a.cmax = cmax2; a.Mtot = 4096;
    a.N = 1024; a.K = 1152; a.nbx = 8;
    b.Alo = U1b; b.Ahi = U1b; b.Msplit = 16384; b.Bt = M1tb;
    b.bl = bl1; b.pnsq = pnsq1; b.pbwd = pbwd1; b.bbp = bb;
    b.npart = 10; b.which = 1; b.cmax = cmax1; b.Mtot = 16384;
    b.N = 1024; b.K = 640; b.nbx = 8;
    k_gE2<<<256 + 1024, 256, 0, stream>>>(a, b, 256);
  }

  // transfer + S1/S2 finalize (fused, vectorized gathers)
  k_tfold<<<2312, 256, 0, stream>>>(ref3, ref2, ref1, R3arg, cmax1, cmax2, out);
}

// Round 14
// 256.478 us; speedup vs baseline: 1.3141x; 1.0785x over previous
//
#include <hip/hip_runtime.h>

typedef short bf8 __attribute__((ext_vector_type(8)));
typedef float f32x4 __attribute__((ext_vector_type(4)));

static __device__ __forceinline__ unsigned short f2bf(float f) {
  unsigned u = __float_as_uint(f);
  unsigned r = u + 0x7FFFu + ((u >> 16) & 1u);
  return (unsigned short)(r >> 16);
}
static __device__ __forceinline__ float bf2f(unsigned short h) {
  return __uint_as_float(((unsigned)h) << 16);
}
static __device__ __forceinline__ unsigned fkey(float f) {
  unsigned u = __float_as_uint(f);
  return (u & 0x80000000u) ? ~u : (u | 0x80000000u);
}
static __device__ __forceinline__ float kdec(unsigned k) {
  unsigned u = (k & 0x80000000u) ? (k & 0x7FFFFFFFu) : ~k;
  return __uint_as_float(u);
}
// K-permutation: c = cc*9+kk  ->  c' = kk*C + cc  (kernel-position-major)
static __device__ __forceinline__ int permC(int c, int C) { return (c % 9) * C + c / 9; }

// async global->LDS, 16B per lane. lds dest: wave-uniform base + lane*16.
static __device__ __forceinline__ void gload_lds16(const unsigned short* g, unsigned short* l) {
  __builtin_amdgcn_global_load_lds((const __attribute__((address_space(1))) void*)g,
                                   (__attribute__((address_space(3))) void*)l, 16, 0, 0);
}

// unfold(k=3,pad=1,stride=1) value: row d = (cc*3+ki)*3+kj, col m = i*S+j, src [C][S][S]
static __device__ __forceinline__ float uf3(const float* __restrict__ src, int lgS, int d, int m) {
  const int S = 1 << lgS;
  int cc = d / 9;
  int r9 = d - cc * 9;
  int ki = r9 / 3;
  int kj = r9 - ki * 3;
  int i = (m >> lgS) + ki - 1;
  int j = (m & (S - 1)) + kj - 1;
  if ((unsigned)i >= (unsigned)S || (unsigned)j >= (unsigned)S) return 0.f;
  return src[((size_t)cc << (2 * lgS)) + ((size_t)i << lgS) + j];
}

// ---------------- prep dispatch A: colnorms+bias-dots || pixel Gram || channels-last transposes ----------------
// [0,1024): colnorm+bias of lrsr3; [1024,2048): colnorm rsr3; [2048,3072): pixgram;
// [3072,3200): rsr2 [128][4096] -> rsr2t [4096][128]; [3200,3456): rsr1 [64][16384] -> rsr1t [16384][64]
__global__ __launch_bounds__(256) void k_prepA(const float* __restrict__ lrsr3, const float* __restrict__ rsr3,
                                               const float* __restrict__ rsr2, const float* __restrict__ rsr1,
                                               const float* __restrict__ b1, const float* __restrict__ b2,
                                               float* __restrict__ sclr, float* __restrict__ scu3,
                                               float* __restrict__ bl2, float* __restrict__ bl1,
                                               float* __restrict__ G2,
                                               float* __restrict__ rsr2t, float* __restrict__ rsr1t) {
  __shared__ float Tt[64][65];
  const int blk = blockIdx.x;
  const int tid = threadIdx.x;
  if (blk < 2048) {
    __shared__ float r0[256], r1[256], r2[256];
    const bool lr = blk < 1024;
    const int m = blk & 1023;
    const float* src = lr ? lrsr3 : rsr3;
    float s = 0.f, d1 = 0.f, d2 = 0.f;
    for (int d = tid; d < 2304; d += 256) {
      float v = uf3(src, 5, d, m);
      s += v * v; d1 += b1[d] * v; d2 += b2[d] * v;
    }
    r0[tid] = s; r1[tid] = d1; r2[tid] = d2;
    __syncthreads();
    for (int o = 128; o > 0; o >>= 1) {
      if (tid < o) { r0[tid] += r0[tid + o]; r1[tid] += r1[tid + o]; r2[tid] += r2[tid + o]; }
      __syncthreads();
    }
    if (tid == 0) {
      float sc = 1.f / fmaxf(sqrtf(r0[0]), 1e-12f);
      if (lr) { sclr[m] = sc; bl2[m] = r1[0] * sc; bl1[m] = r2[0] * sc; }
      else    { scu3[m] = sc; }
    }
  } else if (blk < 3072) {
    __shared__ float As[16][32], Bs[16][32];
    const int px = blk - 2048;
    const int m0 = (px >> 5) * 32, n0 = (px & 31) * 32;
    const int tx = tid & 15, ty = tid >> 4;
    float acc[2][2] = {};
    for (int kb = 0; kb < 256; kb += 16) {
      __syncthreads();
      {
        int kk = tid >> 5, mm = tid & 31;
        As[kk][mm] = lrsr3[(size_t)(kb + kk) * 1024 + m0 + mm];
        Bs[kk][mm] = rsr3[(size_t)(kb + kk) * 1024 + n0 + mm];
        int e2 = tid + 256; int kk2 = e2 >> 5, mm2 = e2 & 31;
        As[kk2][mm2] = lrsr3[(size_t)(kb + kk2) * 1024 + m0 + mm2];
        Bs[kk2][mm2] = rsr3[(size_t)(kb + kk2) * 1024 + n0 + mm2];
      }
      __syncthreads();
#pragma unroll
      for (int kk = 0; kk < 16; ++kk) {
        float a0 = As[kk][ty * 2], a1 = As[kk][ty * 2 + 1];
        float b0 = Bs[kk][tx * 2], b1v = Bs[kk][tx * 2 + 1];
        acc[0][0] = fmaf(a0, b0, acc[0][0]); acc[0][1] = fmaf(a0, b1v, acc[0][1]);
        acc[1][0] = fmaf(a1, b0, acc[1][0]); acc[1][1] = fmaf(a1, b1v, acc[1][1]);
      }
    }
#pragma unroll
    for (int i = 0; i < 2; ++i)
#pragma unroll
      for (int jj = 0; jj < 2; ++jj)
        G2[(size_t)(m0 + ty * 2 + i) * 1024 + (n0 + tx * 2 + jj)] = acc[i][jj];
  } else if (blk < 3200) {
    // rsr2 transpose: tile (ct,st); in [128][4096], out [4096][128]
    const int idx = blk - 3072;
    const int ct = idx & 1, st = idx >> 1;
#pragma unroll
    for (int i = 0; i < 16; ++i) {
      int id = tid + i * 256;
      int r = id >> 6, c = id & 63;
      Tt[r][c] = rsr2[(size_t)(ct * 64 + r) * 4096 + st * 64 + c];
    }
    __syncthreads();
#pragma unroll
    for (int i = 0; i < 16; ++i) {
      int id = tid + i * 256;
      int cc2 = id >> 6, rr = id & 63;
      rsr2t[(size_t)(st * 64 + cc2) * 128 + ct * 64 + rr] = Tt[rr][cc2];
    }
  } else {
    // rsr1 transpose: in [64][16384], out [16384][64]
    const int st = blk - 3200;
#pragma unroll
    for (int i = 0; i < 16; ++i) {
      int id = tid + i * 256;
      int r = id >> 6, c = id & 63;
      Tt[r][c] = rsr1[(size_t)r * 16384 + st * 64 + c];
    }
    __syncthreads();
#pragma unroll
    for (int i = 0; i < 16; ++i) {
      int id = tid + i * 256;
      int cc2 = id >> 6, rr = id & 63;
      rsr1t[(size_t)(st * 64 + cc2) * 64 + rr] = Tt[rr][cc2];
    }
  }
}

// ---------------- prep dispatch B: pass2 || coalesced unfolds (permuted K) || W transposes || bw/bb || r3max ----------------
// [0,1152): normalized unfold lrsr3 -> lr3nbT (bf16x8)
// [1152,3456): U2b [4096][1152], c' = kk*128+cc, from rsr2t (channels-last, 32B loads)
// [3456,8576): U1b [16384][640], c' = ks*64+cc (ks==9 -> pad zeros), from rsr1t
// [8576,9548): W transposes (LDS tiled, destination row permuted)
// [9548,9628): bw dots (permuted store) + bb
// [9628,10652): R3 max/argmax from pixel Gram
__global__ __launch_bounds__(256) void k_prepB(const float* __restrict__ lrsr3,
                                               const float* __restrict__ rsr2t, const float* __restrict__ rsr1t,
                                               const float* __restrict__ W1, const float* __restrict__ W2,
                                               const float* __restrict__ b1, const float* __restrict__ b2,
                                               const float* __restrict__ sclr, const float* __restrict__ scu3,
                                               const float* __restrict__ G2,
                                               unsigned short* __restrict__ lr3nbT,
                                               unsigned short* __restrict__ U2b, unsigned short* __restrict__ U1b,
                                               unsigned short* __restrict__ W1t, unsigned short* __restrict__ W2t,
                                               float* __restrict__ bw2, float* __restrict__ bw1,
                                               float* __restrict__ bb,
                                               float* __restrict__ s3, int* __restrict__ arg) {
  __shared__ unsigned short Ls[64][65];
  __shared__ float bv[256]; __shared__ int bidx[256];
  const int blk = blockIdx.x;
  const int tid = threadIdx.x;
  if (blk < 1152) {
    int id8 = blk * 256 + tid;                 // < 294912 = 1024*288
    int m = id8 / 288, c0 = (id8 - m * 288) * 8;
    float sc = sclr[m];
    bf8 v;
#pragma unroll
    for (int e = 0; e < 8; ++e) v[e] = (short)f2bf(uf3(lrsr3, 5, c0 + e, m) * sc);
    *(bf8*)(lr3nbT + (size_t)m * 2304 + c0) = v;
  } else if (blk < 3456) {
    // U2b: id = ((n*9)+kk)*16 + t; cc0 = t*8; coalesced 32B loads from rsr2t
    int id = (blk - 1152) * 256 + tid;         // < 589824
    int t = id & 15, rest = id >> 4;
    int kk = rest % 9, n = rest / 9;
    int cc0 = t * 8;
    int ki = kk / 3, kj = kk - ki * 3;
    int sy = (n >> 6) + ki - 1, sx = (n & 63) + kj - 1;
    bf8 v;
    if ((unsigned)sy < 64u && (unsigned)sx < 64u) {
      const float* p = rsr2t + (size_t)(sy * 64 + sx) * 128 + cc0;
      f32x4 a = *(const f32x4*)p;
      f32x4 bq = *(const f32x4*)(p + 4);
#pragma unroll
      for (int e = 0; e < 4; ++e) { v[e] = (short)f2bf(a[e]); v[4 + e] = (short)f2bf(bq[e]); }
    } else {
#pragma unroll
      for (int e = 0; e < 8; ++e) v[e] = 0;
    }
    *(bf8*)(U2b + (size_t)n * 1152 + kk * 128 + cc0) = v;
  } else if (blk < 8576) {
    // U1b: id = (n*10 + ks)*8 + t; cc0 = t*8; ks==9 -> pad zeros
    int id = (blk - 3456) * 256 + tid;         // < 1310720
    int n = id / 80, rem = id - n * 80;
    int ks = rem >> 3, t = rem & 7;
    int cc0 = t * 8;
    bf8 v;
    if (ks == 9) {
#pragma unroll
      for (int e = 0; e < 8; ++e) v[e] = 0;
    } else {
      int ki = ks / 3, kj = ks - ki * 3;
      int sy = (n >> 7) + ki - 1, sx = (n & 127) + kj - 1;
      if ((unsigned)sy < 128u && (unsigned)sx < 128u) {
        const float* p = rsr1t + (size_t)(sy * 128 + sx) * 64 + cc0;
        f32x4 a = *(const f32x4*)p;
        f32x4 bq = *(const f32x4*)(p + 4);
#pragma unroll
        for (int e = 0; e < 4; ++e) { v[e] = (short)f2bf(a[e]); v[4 + e] = (short)f2bf(bq[e]); }
      } else {
#pragma unroll
        for (int e = 0; e < 8; ++e) v[e] = 0;
      }
    }
    *(bf8*)(U1b + (size_t)n * 640 + ks * 64 + cc0) = v;
  } else if (blk < 9548) {
    int idx = blk - 8576;
    int xx = idx % 27, yy = idx / 27;          // yy < 36
    const float* W; unsigned short* Wt; int Cw, c0;
    if (xx < 18) { W = W1; Wt = W1t; Cw = 1152; c0 = xx * 64; }
    else         { W = W2; Wt = W2t; Cw = 576;  c0 = (xx - 18) * 64; }
    const int Cch = Cw / 9;                    // 128 or 64
    const int d0 = yy * 64;
#pragma unroll
    for (int i = 0; i < 16; ++i) {
      int id = tid + i * 256;
      int r = id >> 6, c = id & 63;
      Ls[r][c] = f2bf(W[(size_t)(d0 + r) * Cw + c0 + c]);
    }
    __syncthreads();
#pragma unroll
    for (int i = 0; i < 16; ++i) {
      int id = tid + i * 256;
      int cc = id >> 6, rr = id & 63;
      int c = c0 + cc;
      Wt[(size_t)((c % 9) * Cch + c / 9) * 2304 + d0 + rr] = Ls[rr][cc];
    }
  } else if (blk < 9628) {
    int idx = blk - 9548;
    int x = idx & 7, y = idx >> 3;             // y < 10
    if (y == 9) {
      if (x >= 2) return;
      const float* b = x ? b2 : b1;
      float s = 0.f;
      for (int d = tid; d < 2304; d += 256) s += b[d] * b[d];
      bv[tid] = s; __syncthreads();
      for (int o = 128; o > 0; o >>= 1) { if (tid < o) bv[tid] += bv[tid + o]; __syncthreads(); }
      if (tid == 0) bb[x] = bv[0];
      return;
    }
    const bool two = x < 5;
    const float* W = two ? W1 : W2;
    const float* b = two ? b1 : b2;
    float* bw = two ? bw2 : bw1;
    const int Cw = two ? 1152 : 576;
    int c = (two ? x : x - 5) * 256 + tid;
    if (c >= Cw) return;
    int d0 = y * 256;
    float s = 0.f;
    for (int d = d0; d < d0 + 256; ++d) s += b[d] * W[(size_t)d * Cw + c];
    atomicAdd(&bw[(c % 9) * (Cw / 9) + c / 9], s);   // permuted index
  } else {
    const int m = blk - 9628;
    const int mi = m >> 5, mj = m & 31;
    float best = -3.0e38f; int bi = 0;
    for (int n = tid; n < 1024; n += 256) {
      const int ni = n >> 5, nj = n & 31;
      float raw = 0.f;
#pragma unroll
      for (int dy = -1; dy <= 1; ++dy) {
#pragma unroll
        for (int dx = -1; dx <= 1; ++dx) {
          bool vm = ((unsigned)(mi + dy) < 32u) && ((unsigned)(mj + dx) < 32u);
          bool vn = ((unsigned)(ni + dy) < 32u) && ((unsigned)(nj + dx) < 32u);
          if (vm && vn) {
            int off = dy * 32 + dx;
            raw += G2[(size_t)(m + off) * 1024 + (n + off)];
          }
        }
      }
      float v = raw * scu3[n];
      if (v > best) { best = v; bi = n; }
    }
    bv[tid] = best; bidx[tid] = bi;
    __syncthreads();
    for (int o = 128; o > 0; o >>= 1) {
      if (tid < o) {
        float ov = bv[tid + o]; int oi = bidx[tid + o];
        if (ov > bv[tid] || (ov == bv[tid] && oi < bidx[tid])) { bv[tid] = ov; bidx[tid] = oi; }
      }
      __syncthreads();
    }
    if (tid == 0) { s3[m] = bv[0] * sclr[m]; arg[m] = bidx[0]; }
  }
}

// ---------------- bf16 MFMA GEMM body: 128x128 tile, BK=64, 4 waves, XCD-chunked ----------------
// NBUF==1: m97 structure — single buffer, 32KB LDS (4 blocks/CU), stage -> sync -> MFMA -> sync.
// NBUF>=2: counted-vmcnt rotating pipeline (for 1-block/CU grids, e.g. P).
struct Job {
  const unsigned short* Alo;
  const unsigned short* Ahi;
  const unsigned short* Bt;
  unsigned short* Clo;
  unsigned short* Chi;
  const float* bl;
  const float* bw;
  const float* bbp;
  float* pnsq;
  float* pbwd;
  float* cmax;
  int Msplit, N, K, nbx, Mtot, npart, which;
};

template <int EPI, int NBUF>
static __device__ __forceinline__ void gemm_body(const Job& j0, const Job& j1, int nb0) {
  __shared__ __align__(16) unsigned short As[NBUF][128 * 64];
  __shared__ __align__(16) unsigned short Bs[NBUF][128 * 64];
  __shared__ unsigned colkey[128];
  __shared__ float ninvL[128];

  // bijective XCD-chunked swizzle (m204)
  const int nwg = (int)gridDim.x;
  const int h = (int)blockIdx.x;
  const int qq = nwg >> 3, rm = nwg & 7;
  const int xcd = h & 7, wth = h >> 3;
  const int bid = (xcd < rm ? xcd * (qq + 1) : rm * (qq + 1) + (xcd - rm) * qq) + wth;

  const bool first = (bid < nb0);
  const Job j = first ? j0 : j1;
  const int local = bid - (first ? 0 : nb0);
  const int by = local / j.nbx;
  const int bx = local - by * j.nbx;
  const int m0 = by * 128, n0 = bx * 128;
  const int K = j.K, N = j.N;

  const unsigned short* Abase = (m0 < j.Msplit)
      ? j.Alo + (size_t)m0 * K
      : j.Ahi + (size_t)(m0 - j.Msplit) * K;

  const int tid = threadIdx.x;
  const int l = tid & 63;
  const int w = tid >> 6;
  const int wr = w >> 1, wc = w & 1;
  if (EPI == 2) {
    if (tid < 128) {
      colkey[tid] = 0u;
      const int r = m0 + tid;
      float nsq = 0.f, bwd = 0.f;
      for (int p = 0; p < j.npart; ++p) {
        nsq += j.pnsq[(size_t)p * j.Mtot + r];
        bwd += j.pbwd[(size_t)p * j.Mtot + r];
      }
      float tq = nsq + 2.f * bwd + j.bbp[j.which];
      ninvL[tid] = 1.f / fmaxf(sqrtf(fmaxf(tq, 0.f)), 1e-12f);
    }
  }

  f32x4 acc[4][4] = {};

  const int srow = w * 32;
  const int lrow = l >> 3;
  const int gcol = ((l & 7) ^ lrow) * 8;
  const int mr = l & 15;
  const int kg = l >> 4;

  const int nt = K >> 6;
  const int snap_kb = n0 + wc * 64;
  unsigned short snap[4][4][4];

  auto stage = [&](int buf, int kb) {
#pragma unroll
    for (int i = 0; i < 4; ++i) {
      int r = srow + i * 8;
      gload_lds16(Abase + (size_t)(r + lrow) * K + kb + gcol, &As[buf][r * 64]);
      gload_lds16(j.Bt + (size_t)(n0 + r + lrow) * K + kb + gcol, &Bs[buf][r * 64]);
    }
  };
  auto compute_tile = [&](int cur) {
#pragma unroll
    for (int ks = 0; ks < 2; ++ks) {
      bf8 af[4], bv[4];
#pragma unroll
      for (int mi = 0; mi < 4; ++mi) {
        const int row = wr * 64 + mi * 16 + mr;
        af[mi] = *(const bf8*)&As[cur][row * 64 + (((ks * 4 + kg) ^ (row & 7)) * 8)];
      }
#pragma unroll
      for (int ni = 0; ni < 4; ++ni) {
        const int row = wc * 64 + ni * 16 + mr;
        bv[ni] = *(const bf8*)&Bs[cur][row * 64 + (((ks * 4 + kg) ^ (row & 7)) * 8)];
      }
      __builtin_amdgcn_s_setprio(1);
#pragma unroll
      for (int mi = 0; mi < 4; ++mi)
#pragma unroll
        for (int ni = 0; ni < 4; ++ni)
          acc[mi][ni] = __builtin_amdgcn_mfma_f32_16x16x32_bf16(af[mi], bv[ni], acc[mi][ni], 0, 0, 0);
      __builtin_amdgcn_s_setprio(0);
    }
  };
  auto do_snap = [&](int cur) {
#pragma unroll
    for (int mi = 0; mi < 4; ++mi)
#pragma unroll
      for (int e = 0; e < 4; ++e) {
        const int row = wr * 64 + mi * 16 + kg * 4 + e;
#pragma unroll
        for (int ni = 0; ni < 4; ++ni) {
          const int slot = ni * 2 + (mr >> 3);
          snap[mi][ni][e] = As[cur][row * 64 + ((slot ^ (row & 7)) * 8) + (mr & 7)];
        }
      }
  };

  if constexpr (NBUF == 1) {
    for (int t = 0; t < nt; ++t) {
      if (t) __syncthreads();
      stage(0, t << 6);
      __syncthreads();
      compute_tile(0);
      if (EPI == 1 && (t << 6) == snap_kb) do_snap(0);
    }
  } else {
    auto waitv = [&](int Wt) {
      if (Wt >= 2)      asm volatile("s_waitcnt vmcnt(16)\ns_barrier" ::: "memory");
      else if (Wt == 1) asm volatile("s_waitcnt vmcnt(8)\ns_barrier" ::: "memory");
      else              asm volatile("s_waitcnt vmcnt(0)\ns_barrier" ::: "memory");
    };
#pragma unroll
    for (int p = 0; p < NBUF; ++p) if (p < nt) stage(p, p << 6);
    { int inflight = (NBUF < nt ? NBUF : nt); waitv(inflight - 1); }
    int cur = 0;
    for (int t = 0; t < nt; ++t) {
      compute_tile(cur);
      if (EPI == 1 && (t << 6) == snap_kb) do_snap(cur);
      if (t + 1 < nt) {
        asm volatile("s_waitcnt lgkmcnt(0)\ns_barrier" ::: "memory");
        if (t + NBUF < nt) stage(cur, (t + NBUF) << 6);
        const int im = (nt - 1 < t + NBUF) ? (nt - 1) : (t + NBUF);
        waitv(im - (t + 1));
        cur = (cur + 1 == NBUF) ? 0 : cur + 1;
      }
    }
  }

  // C/D frag layout: col = mr, row = kg*4 + e (within 16x16)
  const int lr0 = wr * 64;
  const int lc0 = wc * 64;
  if (EPI == 0) {
    unsigned short* Cbase = (m0 < j.Msplit)
        ? j.Clo + (size_t)m0 * N
        : j.Chi + (size_t)(m0 - j.Msplit) * N;
#pragma unroll
    for (int mi = 0; mi < 4; ++mi)
#pragma unroll
      for (int ni = 0; ni < 4; ++ni)
#pragma unroll
        for (int e = 0; e < 4; ++e)
          Cbase[(size_t)(lr0 + mi * 16 + kg * 4 + e) * (size_t)N + (n0 + lc0 + ni * 16 + mr)] = f2bf(acc[mi][ni][e]);
  } else if (EPI == 1) {
    float rp[4][4] = {};
    float bp[4][4] = {};
#pragma unroll
    for (int ni = 0; ni < 4; ++ni) {
      const float bwv = j.bw[n0 + lc0 + ni * 16 + mr];
#pragma unroll
      for (int mi = 0; mi < 4; ++mi)
#pragma unroll
        for (int e = 0; e < 4; ++e) {
          const float av = bf2f(snap[mi][ni][e]);
          rp[mi][e] += acc[mi][ni][e] * av;
          bp[mi][e] += bwv * av;
        }
    }
#pragma unroll
    for (int off = 1; off < 16; off <<= 1)
#pragma unroll
      for (int mi = 0; mi < 4; ++mi)
#pragma unroll
        for (int e = 0; e < 4; ++e) {
          rp[mi][e] += __shfl_xor(rp[mi][e], off);
          bp[mi][e] += __shfl_xor(bp[mi][e], off);
        }
    if (mr == 0) {
      const size_t slotbase = (size_t)(bx * 2 + wc) * j.Mtot;
#pragma unroll
      for (int mi = 0; mi < 4; ++mi)
#pragma unroll
        for (int e = 0; e < 4; ++e) {
          const int r = m0 + lr0 + mi * 16 + kg * 4 + e;
          j.pnsq[slotbase + r] = rp[mi][e];
          j.pbwd[slotbase + r] = bp[mi][e];
        }
    }
  } else {
    float nv[4][4];
#pragma unroll
    for (int mi = 0; mi < 4; ++mi)
#pragma unroll
      for (int e = 0; e < 4; ++e)
        nv[mi][e] = ninvL[lr0 + mi * 16 + kg * 4 + e];
#pragma unroll
    for (int ni = 0; ni < 4; ++ni) {
      float blv = j.bl[n0 + lc0 + ni * 16 + mr];
      float mx = -3.0e38f;
#pragma unroll
      for (int mi = 0; mi < 4; ++mi)
#pragma unroll
        for (int e = 0; e < 4; ++e) mx = fmaxf(mx, (acc[mi][ni][e] + blv) * nv[mi][e]);
      atomicMax(&colkey[lc0 + ni * 16 + mr], fkey(mx));
    }
    __syncthreads();
    if (tid < 128) j.cmax[(size_t)by * 1024 + n0 + tid] = kdec(colkey[tid]);
  }
}

__global__ __launch_bounds__(256) void k_gP (Job a, Job b, int nb0) { gemm_body<0, 3>(a, b, nb0); }
__global__ __launch_bounds__(256) void k_gE1(Job a, Job b, int nb0) { gemm_body<1, 1>(a, b, nb0); }
__global__ __launch_bounds__(256) void k_gE2(Job a, Job b, int nb0) { gemm_body<2, 1>(a, b, nb0); }

// ---------------- fused gather+fold (vectorized) + S1/S2 finalize ----------------
__global__ __launch_bounds__(256) void k_tfold(const float* __restrict__ ref3, const float* __restrict__ ref2,
                                               const float* __restrict__ ref1, const int* __restrict__ arg,
                                               const float* __restrict__ cmax1, const float* __restrict__ cmax2,
                                               float* __restrict__ out) {
  const int bid = blockIdx.x;
  const int tid = threadIdx.x;
  if (bid < 256) {
    __shared__ float plane[1024];
    __shared__ int argL[1024];
    const int c = bid;
#pragma unroll
    for (int k = 0; k < 4; ++k) {
      plane[k * 256 + tid] = ref3[(size_t)c * 1024 + k * 256 + tid];
      argL[k * 256 + tid] = arg[k * 256 + tid];
    }
    __syncthreads();
#pragma unroll
    for (int k = 0; k < 4; ++k) {
      int px = k * 256 + tid;
      int y = px >> 5, x = px & 31;
      float s = 0.f;
#pragma unroll
      for (int di = -1; di <= 1; ++di) {
        int i = y + di;
        if ((unsigned)i >= 32u) continue;
#pragma unroll
        for (int dj = -1; dj <= 1; ++dj) {
          int jw = x + dj;
          if ((unsigned)jw >= 32u) continue;
          int n2 = argL[i * 32 + jw];
          int rr = (n2 >> 5) + y - i, cc = (n2 & 31) + x - jw;
          if ((unsigned)rr < 32u && (unsigned)cc < 32u) s += plane[rr * 32 + cc];
        }
      }
      out[3072 + (size_t)c * 1024 + px] = s * (1.f / 9.f);
    }
  } else if (bid < 1280) {
    __shared__ int argL[1024];
#pragma unroll
    for (int k = 0; k < 4; ++k) argL[k * 256 + tid] = arg[k * 256 + tid];
    __syncthreads();
    int id2 = (bid - 256) * 256 + tid;
    int q = id2 & 31, y = (id2 >> 5) & 63, c = id2 >> 11;
    int iy = y >> 1;
    float s0 = 0.f, s1 = 0.f;
#pragma unroll
    for (int di = -1; di <= 1; ++di) {
      int i = iy + di;
      if ((unsigned)i >= 32u) continue;
      int ry = y - 2 * i;
#pragma unroll
      for (int dj = -1; dj <= 1; ++dj) {
        int jw = q + dj;
        if ((unsigned)jw >= 32u) continue;
        int n2 = argL[i * 32 + jw];
        int rr = (n2 >> 5) * 2 + ry;
        int cb = (n2 & 31) * 2 + 2 * (q - jw);
        if ((unsigned)rr < 64u && (unsigned)cb < 63u) {
          const float* p = ref2 + (size_t)c * 4096 + rr * 64 + cb;
          s0 += p[0]; s1 += p[1];
        }
      }
    }
    float2 o; o.x = s0 * (1.f / 9.f); o.y = s1 * (1.f / 9.f);
    *(float2*)(out + 265216 + (size_t)c * 4096 + y * 64 + 2 * q) = o;
  } else if (bid < 2304) {
    __shared__ int argL[1024];
#pragma unroll
    for (int k = 0; k < 4; ++k) argL[k * 256 + tid] = arg[k * 256 + tid];
    __syncthreads();
    int id1 = (bid - 1280) * 256 + tid;
    int q = id1 & 31, y = (id1 >> 5) & 127, c = id1 >> 12;
    int iy = y >> 2;
    f32x4 s = {0.f, 0.f, 0.f, 0.f};
#pragma unroll
    for (int di = -1; di <= 1; ++di) {
      int i = iy + di;
      if ((unsigned)i >= 32u) continue;
      int ry = y - 4 * i;
#pragma unroll
      for (int dj = -1; dj <= 1; ++dj) {
        int jw = q + dj;
        if ((unsigned)jw >= 32u) continue;
        int n2 = argL[i * 32 + jw];
        int rr = (n2 >> 5) * 4 + ry;
        int cb = (n2 & 31) * 4 + 4 * (q - jw);
        if ((unsigned)rr < 128u && (unsigned)cb < 125u) {
          f32x4 v = *(const f32x4*)(ref1 + (size_t)c * 16384 + rr * 128 + cb);
          s += v;
        }
      }
    }
    s *= (1.f / 9.f);
    *(f32x4*)(out + 789504 + (size_t)c * 16384 + y * 128 + 4 * q) = s;
  } else {
    int t = (bid - 2304) * 256 + tid;  // 0..2047
    if (t < 1024) {
      float mx = -3.0e38f;
      for (int rb = 0; rb < 128; ++rb) mx = fmaxf(mx, cmax1[rb * 1024 + t]);
      out[t] = mx;            // S_1
    } else {
      int tt = t - 1024;
      float mx = -3.0e38f;
      for (int rb = 0; rb < 32; ++rb) mx = fmaxf(mx, cmax2[rb * 1024 + tt]);
      out[1024 + tt] = mx;    // S_2
    }
  }
}

// ---------------- workspace layout (bytes) ----------------
static constexpr size_t OFF_BW2     = 0;                        // 1152 f32
static constexpr size_t OFF_BW1     = 4608;                     // 640 f32
static constexpr size_t ZERO_BYTES  = 7168;
static constexpr size_t OFF_BB      = 7168;                     // 2 f32 (pad to 256)
static constexpr size_t OFF_BL2     = 7424;                     // 1024 f32
static constexpr size_t OFF_BL1     = 11520;                    // 1024 f32
static constexpr size_t OFF_SCLR    = 15616;                    // 1024 f32
static constexpr size_t OFF_SCU3    = 19712;                    // 1024 f32
static constexpr size_t OFF_R3ARG   = 23808;                    // 1024 int
static constexpr size_t OFF_PNSQ2   = 27904;                    // f32 [18][4096]
static constexpr size_t OFF_PBWD2   = OFF_PNSQ2 + 294912;       // f32 [18][4096]
static constexpr size_t OFF_PNSQ1   = OFF_PBWD2 + 294912;       // f32 [10][16384]
static constexpr size_t OFF_PBWD1   = OFF_PNSQ1 + 655360;       // f32 [10][16384]
static constexpr size_t OFF_CMAX2   = OFF_PBWD1 + 655360;       // f32 [32][1024]
static constexpr size_t OFF_CMAX1   = OFF_CMAX2 + 131072;       // f32 [128][1024]
static constexpr size_t OFF_LR3NBT  = OFF_CMAX1 + 524288;       // bf16 [1024][2304]
static constexpr size_t OFF_U2B     = OFF_LR3NBT + 4718592;     // bf16 [4096][1152] (perm K)
static constexpr size_t OFF_U1B     = OFF_U2B    + 9437184;     // bf16 [16384][640] (perm K)
static constexpr size_t OFF_W1T     = OFF_U1B    + 20971520;    // bf16 [1152][2304] (perm rows)
static constexpr size_t OFF_W2T     = OFF_W1T    + 5308416;     // bf16 [640][2304] (perm rows; 576+ zero)
static constexpr size_t OFF_A2      = OFF_W2T    + 2949120;     // bf16 [1152][1152]
static constexpr size_t OFF_A1      = OFF_A2     + 2654208;     // bf16 [640][640]
static constexpr size_t OFF_M2T     = OFF_A1     + 819200;      // bf16 [1024][1152]
static constexpr size_t OFF_M1T     = OFF_M2T    + 2359296;     // bf16 [1024][640]
static constexpr size_t OFF_G2      = OFF_M1T    + 1310720;     // f32 [1024][1024]
static constexpr size_t OFF_R2T     = OFF_G2     + 4194304;     // f32 [4096][128]
static constexpr size_t OFF_R1T     = OFF_R2T    + 2097152;     // f32 [16384][64]

extern "C" void kernel_launch(void* const* d_in, const int* in_sizes, int n_in,
                              void* d_out, int out_size, void* d_ws, size_t ws_size,
                              hipStream_t stream) {
  (void)in_sizes; (void)n_in; (void)out_size; (void)ws_size;
  const float* lrsr3  = (const float*)d_in[0];
  const float* rsr1   = (const float*)d_in[1];
  const float* rsr2   = (const float*)d_in[2];
  const float* rsr3   = (const float*)d_in[3];
  const float* ref1   = (const float*)d_in[4];
  const float* ref2   = (const float*)d_in[5];
  const float* ref3   = (const float*)d_in[6];
  const float* W1     = (const float*)d_in[7];
  const float* b1     = (const float*)d_in[8];
  const float* W2     = (const float*)d_in[9];
  const float* b2     = (const float*)d_in[10];
  float* out = (float*)d_out;
  char* ws = (char*)d_ws;

  float*          bw2     = (float*)(ws + OFF_BW2);
  float*          bw1     = (float*)(ws + OFF_BW1);
  float*          bb      = (float*)(ws + OFF_BB);
  float*          bl2     = (float*)(ws + OFF_BL2);
  float*          bl1     = (float*)(ws + OFF_BL1);
  float*          sclr    = (float*)(ws + OFF_SCLR);
  float*          scu3    = (float*)(ws + OFF_SCU3);
  int*            R3arg   = (int*)(ws + OFF_R3ARG);
  float*          pnsq2   = (float*)(ws + OFF_PNSQ2);
  float*          pbwd2   = (float*)(ws + OFF_PBWD2);
  float*          pnsq1   = (float*)(ws + OFF_PNSQ1);
  float*          pbwd1   = (float*)(ws + OFF_PBWD1);
  float*          cmax2   = (float*)(ws + OFF_CMAX2);
  float*          cmax1   = (float*)(ws + OFF_CMAX1);
  unsigned short* lr3nbT  = (unsigned short*)(ws + OFF_LR3NBT);
  unsigned short* U2b     = (unsigned short*)(ws + OFF_U2B);
  unsigned short* U1b     = (unsigned short*)(ws + OFF_U1B);
  unsigned short* W1t     = (unsigned short*)(ws + OFF_W1T);
  unsigned short* W2t     = (unsigned short*)(ws + OFF_W2T);
  unsigned short* A2b     = (unsigned short*)(ws + OFF_A2);
  unsigned short* A1b     = (unsigned short*)(ws + OFF_A1);
  unsigned short* M2tb    = (unsigned short*)(ws + OFF_M2T);
  unsigned short* M1tb    = (unsigned short*)(ws + OFF_M1T);
  float*          G2      = (float*)(ws + OFF_G2);
  float*          rsr2t   = (float*)(ws + OFF_R2T);
  float*          rsr1t   = (float*)(ws + OFF_R1T);

  hipMemsetAsync(d_ws, 0, ZERO_BYTES, stream);
  // zero pad rows 576..639 of W2t
  hipMemsetAsync(ws + OFF_W2T + (size_t)576 * 2304 * 2, 0, (size_t)64 * 2304 * 2, stream);

  // A: colnorms + bias dots || pixel Gram || channels-last transposes
  k_prepA<<<3456, 256, 0, stream>>>(lrsr3, rsr3, rsr2, rsr1, b1, b2, sclr, scu3, bl2, bl1, G2, rsr2t, rsr1t);
  // B: normalized unfold || coalesced permuted unfolds || W transposes || bw/bb || R3 argmax
  k_prepB<<<10652, 256, 0, stream>>>(lrsr3, rsr2t, rsr1t, W1, W2, b1, b2, sclr, scu3, G2,
                                     lr3nbT, U2b, U1b, W1t, W2t, bw2, bw1, bb, out + 2048, R3arg);

  Job jz = {};

  // P: Gram matrices + M^T, fused across row-concat [Wt ; lr3nbT]  (NBUF=3: 1 block/CU regime)
  {
    Job a = jz, b = jz;
    a.Alo = W1t; a.Ahi = lr3nbT; a.Msplit = 1152; a.Bt = W1t;
    a.Clo = A2b; a.Chi = M2tb; a.N = 1152; a.K = 2304; a.nbx = 9;
    b.Alo = W2t; b.Ahi = lr3nbT; b.Msplit = 640; b.Bt = W2t;
    b.Clo = A1b; b.Chi = M1tb; b.N = 640; b.K = 2304; b.nbx = 5;
    k_gP<<<153 + 65, 256, 0, stream>>>(a, b, 153);
  }
  // E1: per-(colblock,half) norm/bw partials (NBUF=1 m97 loop: 4 blocks/CU TLP)
  {
    Job a = jz, b = jz;
    a.Alo = U2b; a.Ahi = U2b; a.Msplit = 4096; a.Bt = A2b;
    a.bw = bw2; a.pnsq = pnsq2; a.pbwd = pbwd2; a.Mtot = 4096;
    a.N = 1152; a.K = 1152; a.nbx = 9;
    b.Alo = U1b; b.Ahi = U1b; b.Msplit = 16384; b.Bt = A1b;
    b.bw = bw1; b.pnsq = pnsq1; b.pbwd = pbwd1; b.Mtot = 16384;
    b.N = 640; b.K = 640; b.nbx = 5;
    k_gE1<<<288 + 640, 256, 0, stream>>>(a, b, 288);
  }
  // E2: score max (ninv computed per-block in prologue from partials)
  {
    Job a = jz, b = jz;
    a.Alo = U2b; a.Ahi = U2b; a.Msplit = 4096; a.Bt = M2tb;
    a.bl = bl2; a.pnsq = pnsq2; a.pbwd = pbwd2; a.bbp = bb;
    a.npart = 18; a.which = 0; a.cmax = cmax2; a.Mtot = 4096;
    a.N = 1024; a.K = 1152; a.nbx = 8;
    b.Alo = U1b; b.Ahi = U1b; b.Msplit = 16384; b.Bt = M1tb;
    b.bl = bl1; b.pnsq = pnsq1; b.pbwd = pbwd1; b.bbp = bb;
    b.npart = 10; b.which = 1; b.cmax = cmax1; b.Mtot = 16384;
    b.N = 1024; b.K = 640; b.nbx = 8;
    k_gE2<<<256 + 1024, 256, 0, stream>>>(a, b, 256);
  }

  // transfer + S1/S2 finalize (fused, vectorized gathers)
  k_tfold<<<2312, 256, 0, stream>>>(ref3, ref2, ref1, R3arg, cmax1, cmax2, out);
}

// Round 15
// 231.567 us; speedup vs baseline: 1.4555x; 1.1076x over previous
//
#include <hip/hip_runtime.h>

typedef short bf8 __attribute__((ext_vector_type(8)));
typedef float f32x4 __attribute__((ext_vector_type(4)));

static __device__ __forceinline__ unsigned short f2bf(float f) {
  unsigned u = __float_as_uint(f);
  unsigned r = u + 0x7FFFu + ((u >> 16) & 1u);
  return (unsigned short)(r >> 16);
}
static __device__ __forceinline__ float bf2f(unsigned short h) {
  return __uint_as_float(((unsigned)h) << 16);
}
static __device__ __forceinline__ unsigned fkey(float f) {
  unsigned u = __float_as_uint(f);
  return (u & 0x80000000u) ? ~u : (u | 0x80000000u);
}
static __device__ __forceinline__ float kdec(unsigned k) {
  unsigned u = (k & 0x80000000u) ? (k & 0x7FFFFFFFu) : ~k;
  return __uint_as_float(u);
}
// bijective XCD-chunked swizzle (m204)
static __device__ __forceinline__ int xcdswz(int h, int nwg) {
  int q = nwg >> 3, r = nwg & 7;
  int xcd = h & 7, w = h >> 3;
  return (xcd < r ? xcd * (q + 1) : r * (q + 1) + (xcd - r) * q) + w;
}

// async global->LDS, 16B per lane. lds dest: wave-uniform base + lane*16.
static __device__ __forceinline__ void gload_lds16(const unsigned short* g, unsigned short* l) {
  __builtin_amdgcn_global_load_lds((const __attribute__((address_space(1))) void*)g,
                                   (__attribute__((address_space(3))) void*)l, 16, 0, 0);
}

// unfold(k=3,pad=1,stride=1) value: row d = (cc*3+ki)*3+kj, col m = i*S+j, src [C][S][S]
static __device__ __forceinline__ float uf3(const float* __restrict__ src, int lgS, int d, int m) {
  const int S = 1 << lgS;
  int cc = d / 9;
  int r9 = d - cc * 9;
  int ki = r9 / 3;
  int kj = r9 - ki * 3;
  int i = (m >> lgS) + ki - 1;
  int j = (m & (S - 1)) + kj - 1;
  if ((unsigned)i >= (unsigned)S || (unsigned)j >= (unsigned)S) return 0.f;
  return src[((size_t)cc << (2 * lgS)) + ((size_t)i << lgS) + j];
}

// ---------------- prep dispatch A ----------------
// [0,2048): colnorms (+bias dots for lrsr3); [2048,3072): pixgram; [3072,3200): rsr2t; [3200,3456): rsr1t;
// [3456,4608): RAW lr3nb unfold -> lr3nbT bf16 (scale deferred to P epilogue); [4608,5580): W transposes
__global__ __launch_bounds__(256) void k_prepA(const float* __restrict__ lrsr3, const float* __restrict__ rsr3,
                                               const float* __restrict__ rsr2, const float* __restrict__ rsr1,
                                               const float* __restrict__ W1, const float* __restrict__ W2,
                                               const float* __restrict__ b1, const float* __restrict__ b2,
                                               float* __restrict__ sclr, float* __restrict__ scu3,
                                               float* __restrict__ bl2, float* __restrict__ bl1,
                                               float* __restrict__ G2,
                                               float* __restrict__ rsr2t, float* __restrict__ rsr1t,
                                               unsigned short* __restrict__ lr3nbT,
                                               unsigned short* __restrict__ W1t, unsigned short* __restrict__ W2t) {
  const int blk = blockIdx.x;
  const int tid = threadIdx.x;
  if (blk < 2048) {
    __shared__ float r0[256], r1[256], r2[256];
    const bool lr = blk < 1024;
    const int m = blk & 1023;
    const float* src = lr ? lrsr3 : rsr3;
    float s = 0.f, d1 = 0.f, d2 = 0.f;
    for (int d = tid; d < 2304; d += 256) {
      float v = uf3(src, 5, d, m);
      s += v * v; d1 += b1[d] * v; d2 += b2[d] * v;
    }
    r0[tid] = s; r1[tid] = d1; r2[tid] = d2;
    __syncthreads();
    for (int o = 128; o > 0; o >>= 1) {
      if (tid < o) { r0[tid] += r0[tid + o]; r1[tid] += r1[tid + o]; r2[tid] += r2[tid + o]; }
      __syncthreads();
    }
    if (tid == 0) {
      float sc = 1.f / fmaxf(sqrtf(r0[0]), 1e-12f);
      if (lr) { sclr[m] = sc; bl2[m] = r1[0] * sc; bl1[m] = r2[0] * sc; }
      else    { scu3[m] = sc; }
    }
  } else if (blk < 3072) {
    __shared__ float As[16][32], Bs[16][32];
    const int px = blk - 2048;
    const int m0 = (px >> 5) * 32, n0 = (px & 31) * 32;
    const int tx = tid & 15, ty = tid >> 4;
    float acc[2][2] = {};
    for (int kb = 0; kb < 256; kb += 16) {
      __syncthreads();
      {
        int kk = tid >> 5, mm = tid & 31;
        As[kk][mm] = lrsr3[(size_t)(kb + kk) * 1024 + m0 + mm];
        Bs[kk][mm] = rsr3[(size_t)(kb + kk) * 1024 + n0 + mm];
        int e2 = tid + 256; int kk2 = e2 >> 5, mm2 = e2 & 31;
        As[kk2][mm2] = lrsr3[(size_t)(kb + kk2) * 1024 + m0 + mm2];
        Bs[kk2][mm2] = rsr3[(size_t)(kb + kk2) * 1024 + n0 + mm2];
      }
      __syncthreads();
#pragma unroll
      for (int kk = 0; kk < 16; ++kk) {
        float a0 = As[kk][ty * 2], a1 = As[kk][ty * 2 + 1];
        float b0 = Bs[kk][tx * 2], b1v = Bs[kk][tx * 2 + 1];
        acc[0][0] = fmaf(a0, b0, acc[0][0]); acc[0][1] = fmaf(a0, b1v, acc[0][1]);
        acc[1][0] = fmaf(a1, b0, acc[1][0]); acc[1][1] = fmaf(a1, b1v, acc[1][1]);
      }
    }
#pragma unroll
    for (int i = 0; i < 2; ++i)
#pragma unroll
      for (int jj = 0; jj < 2; ++jj)
        G2[(size_t)(m0 + ty * 2 + i) * 1024 + (n0 + tx * 2 + jj)] = acc[i][jj];
  } else if (blk < 3200) {
    __shared__ float Tt[64][65];
    const int idx = blk - 3072;
    const int ct = idx & 1, st = idx >> 1;
#pragma unroll
    for (int i = 0; i < 16; ++i) {
      int id = tid + i * 256;
      int r = id >> 6, c = id & 63;
      Tt[r][c] = rsr2[(size_t)(ct * 64 + r) * 4096 + st * 64 + c];
    }
    __syncthreads();
#pragma unroll
    for (int i = 0; i < 16; ++i) {
      int id = tid + i * 256;
      int cc2 = id >> 6, rr = id & 63;
      rsr2t[(size_t)(st * 64 + cc2) * 128 + ct * 64 + rr] = Tt[rr][cc2];
    }
  } else if (blk < 3456) {
    __shared__ float Tt[64][65];
    const int st = blk - 3200;
#pragma unroll
    for (int i = 0; i < 16; ++i) {
      int id = tid + i * 256;
      int r = id >> 6, c = id & 63;
      Tt[r][c] = rsr1[(size_t)r * 16384 + st * 64 + c];
    }
    __syncthreads();
#pragma unroll
    for (int i = 0; i < 16; ++i) {
      int id = tid + i * 256;
      int cc2 = id >> 6, rr = id & 63;
      rsr1t[(size_t)(st * 64 + cc2) * 64 + rr] = Tt[rr][cc2];
    }
  } else if (blk < 4608) {
    // RAW lr3nb unfold (normalization deferred to P's M-row epilogue)
    int id8 = (blk - 3456) * 256 + tid;        // < 294912
    int m = id8 / 288, c0 = (id8 - m * 288) * 8;
    bf8 v;
#pragma unroll
    for (int e = 0; e < 8; ++e) v[e] = (short)f2bf(uf3(lrsr3, 5, c0 + e, m));
    *(bf8*)(lr3nbT + (size_t)m * 2304 + c0) = v;
  } else {
    __shared__ unsigned short Ls[64][65];
    int idx = blk - 4608;
    int xx = idx % 27, yy = idx / 27;          // yy < 36
    const float* W; unsigned short* Wt; int Cw, c0;
    if (xx < 18) { W = W1; Wt = W1t; Cw = 1152; c0 = xx * 64; }
    else         { W = W2; Wt = W2t; Cw = 576;  c0 = (xx - 18) * 64; }
    const int Cch = Cw / 9;
    const int d0 = yy * 64;
#pragma unroll
    for (int i = 0; i < 16; ++i) {
      int id = tid + i * 256;
      int r = id >> 6, c = id & 63;
      Ls[r][c] = f2bf(W[(size_t)(d0 + r) * Cw + c0 + c]);
    }
    __syncthreads();
#pragma unroll
    for (int i = 0; i < 16; ++i) {
      int id = tid + i * 256;
      int cc = id >> 6, rr = id & 63;
      int c = c0 + cc;
      Wt[(size_t)((c % 9) * Cch + c / 9) * 2304 + d0 + rr] = Ls[rr][cc];
    }
  }
}

// ---------------- bf16 MFMA GEMM body: 128x128 tile, BK=64, 4 waves ----------------
// NBUF==1: m97 single-buffer loop. NBUF>=2: counted-vmcnt rotating pipeline.
// EPI 0: store bf16 C (rows >= Msplit scaled by rowscale[row-Msplit]).
// EPI 1: per-(colblock,wave-half) partials (unique writer slot = bx*2+wc).
// EPI 2: per-block ninv from partials (LDS prologue), cmax stores.
struct Job {
  const unsigned short* Alo;
  const unsigned short* Ahi;
  const unsigned short* Bt;
  unsigned short* Clo;
  unsigned short* Chi;
  const float* bl;
  const float* bw;
  const float* bbp;
  const float* rowscale;
  float* pnsq;
  float* pbwd;
  float* cmax;
  int Msplit, N, K, nbx, Mtot, npart, which;
};

template <int EPI, int NBUF>
static __device__ __forceinline__ void gemm_body(const Job& j0, const Job& j1, int nb0, int bid) {
  __shared__ __align__(16) unsigned short As[NBUF][128 * 64];
  __shared__ __align__(16) unsigned short Bs[NBUF][128 * 64];
  __shared__ unsigned colkey[128];
  __shared__ float ninvL[128];

  const bool first = (bid < nb0);
  const Job j = first ? j0 : j1;
  const int local = bid - (first ? 0 : nb0);
  const int by = local / j.nbx;
  const int bx = local - by * j.nbx;
  const int m0 = by * 128, n0 = bx * 128;
  const int K = j.K, N = j.N;

  const unsigned short* Abase = (m0 < j.Msplit)
      ? j.Alo + (size_t)m0 * K
      : j.Ahi + (size_t)(m0 - j.Msplit) * K;

  const int tid = threadIdx.x;
  const int l = tid & 63;
  const int w = tid >> 6;
  const int wr = w >> 1, wc = w & 1;
  if (EPI == 2) {
    if (tid < 128) {
      colkey[tid] = 0u;
      const int r = m0 + tid;
      float nsq = 0.f, bwd = 0.f;
      for (int p = 0; p < j.npart; ++p) {
        nsq += j.pnsq[(size_t)p * j.Mtot + r];
        bwd += j.pbwd[(size_t)p * j.Mtot + r];
      }
      float tq = nsq + 2.f * bwd + j.bbp[j.which];
      ninvL[tid] = 1.f / fmaxf(sqrtf(fmaxf(tq, 0.f)), 1e-12f);
    }
  }

  f32x4 acc[4][4] = {};

  const int srow = w * 32;
  const int lrow = l >> 3;
  const int gcol = ((l & 7) ^ lrow) * 8;
  const int mr = l & 15;
  const int kg = l >> 4;

  const int nt = K >> 6;
  const int snap_kb = n0 + wc * 64;
  unsigned short snap[4][4][4];

  auto stage = [&](int buf, int kb) {
#pragma unroll
    for (int i = 0; i < 4; ++i) {
      int r = srow + i * 8;
      gload_lds16(Abase + (size_t)(r + lrow) * K + kb + gcol, &As[buf][r * 64]);
      gload_lds16(j.Bt + (size_t)(n0 + r + lrow) * K + kb + gcol, &Bs[buf][r * 64]);
    }
  };
  auto compute_tile = [&](int cur) {
#pragma unroll
    for (int ks = 0; ks < 2; ++ks) {
      bf8 af[4], bv[4];
#pragma unroll
      for (int mi = 0; mi < 4; ++mi) {
        const int row = wr * 64 + mi * 16 + mr;
        af[mi] = *(const bf8*)&As[cur][row * 64 + (((ks * 4 + kg) ^ (row & 7)) * 8)];
      }
#pragma unroll
      for (int ni = 0; ni < 4; ++ni) {
        const int row = wc * 64 + ni * 16 + mr;
        bv[ni] = *(const bf8*)&Bs[cur][row * 64 + (((ks * 4 + kg) ^ (row & 7)) * 8)];
      }
      __builtin_amdgcn_s_setprio(1);
#pragma unroll
      for (int mi = 0; mi < 4; ++mi)
#pragma unroll
        for (int ni = 0; ni < 4; ++ni)
          acc[mi][ni] = __builtin_amdgcn_mfma_f32_16x16x32_bf16(af[mi], bv[ni], acc[mi][ni], 0, 0, 0);
      __builtin_amdgcn_s_setprio(0);
    }
  };
  auto do_snap = [&](int cur) {
#pragma unroll
    for (int mi = 0; mi < 4; ++mi)
#pragma unroll
      for (int e = 0; e < 4; ++e) {
        const int row = wr * 64 + mi * 16 + kg * 4 + e;
#pragma unroll
        for (int ni = 0; ni < 4; ++ni) {
          const int slot = ni * 2 + (mr >> 3);
          snap[mi][ni][e] = As[cur][row * 64 + ((slot ^ (row & 7)) * 8) + (mr & 7)];
        }
      }
  };

  if constexpr (NBUF == 1) {
    for (int t = 0; t < nt; ++t) {
      if (t) __syncthreads();
      stage(0, t << 6);
      __syncthreads();
      compute_tile(0);
      if (EPI == 1 && (t << 6) == snap_kb) do_snap(0);
    }
  } else {
    auto waitv = [&](int Wt) {
      if (Wt >= 2)      asm volatile("s_waitcnt vmcnt(16)\ns_barrier" ::: "memory");
      else if (Wt == 1) asm volatile("s_waitcnt vmcnt(8)\ns_barrier" ::: "memory");
      else              asm volatile("s_waitcnt vmcnt(0)\ns_barrier" ::: "memory");
    };
#pragma unroll
    for (int p = 0; p < NBUF; ++p) if (p < nt) stage(p, p << 6);
    { int inflight = (NBUF < nt ? NBUF : nt); waitv(inflight - 1); }
    int cur = 0;
    for (int t = 0; t < nt; ++t) {
      compute_tile(cur);
      if (EPI == 1 && (t << 6) == snap_kb) do_snap(cur);
      if (t + 1 < nt) {
        asm volatile("s_waitcnt lgkmcnt(0)\ns_barrier" ::: "memory");
        if (t + NBUF < nt) stage(cur, (t + NBUF) << 6);
        const int im = (nt - 1 < t + NBUF) ? (nt - 1) : (t + NBUF);
        waitv(im - (t + 1));
        cur = (cur + 1 == NBUF) ? 0 : cur + 1;
      }
    }
  }

  // C/D frag layout: col = mr, row = kg*4 + e (within 16x16)
  const int lr0 = wr * 64;
  const int lc0 = wc * 64;
  if (EPI == 0) {
    const bool hi = (m0 >= j.Msplit);
    unsigned short* Cbase = hi ? j.Chi + (size_t)(m0 - j.Msplit) * N
                               : j.Clo + (size_t)m0 * N;
    float rs[4][4];
#pragma unroll
    for (int mi = 0; mi < 4; ++mi)
#pragma unroll
      for (int e = 0; e < 4; ++e)
        rs[mi][e] = hi ? j.rowscale[m0 - j.Msplit + lr0 + mi * 16 + kg * 4 + e] : 1.f;
#pragma unroll
    for (int mi = 0; mi < 4; ++mi)
#pragma unroll
      for (int ni = 0; ni < 4; ++ni)
#pragma unroll
        for (int e = 0; e < 4; ++e)
          Cbase[(size_t)(lr0 + mi * 16 + kg * 4 + e) * (size_t)N + (n0 + lc0 + ni * 16 + mr)] =
              f2bf(acc[mi][ni][e] * rs[mi][e]);
  } else if (EPI == 1) {
    float rp[4][4] = {};
    float bp[4][4] = {};
#pragma unroll
    for (int ni = 0; ni < 4; ++ni) {
      const float bwv = j.bw[n0 + lc0 + ni * 16 + mr];
#pragma unroll
      for (int mi = 0; mi < 4; ++mi)
#pragma unroll
        for (int e = 0; e < 4; ++e) {
          const float av = bf2f(snap[mi][ni][e]);
          rp[mi][e] += acc[mi][ni][e] * av;
          bp[mi][e] += bwv * av;
        }
    }
#pragma unroll
    for (int off = 1; off < 16; off <<= 1)
#pragma unroll
      for (int mi = 0; mi < 4; ++mi)
#pragma unroll
        for (int e = 0; e < 4; ++e) {
          rp[mi][e] += __shfl_xor(rp[mi][e], off);
          bp[mi][e] += __shfl_xor(bp[mi][e], off);
        }
    if (mr == 0) {
      const size_t slotbase = (size_t)(bx * 2 + wc) * j.Mtot;
#pragma unroll
      for (int mi = 0; mi < 4; ++mi)
#pragma unroll
        for (int e = 0; e < 4; ++e) {
          const int r = m0 + lr0 + mi * 16 + kg * 4 + e;
          j.pnsq[slotbase + r] = rp[mi][e];
          j.pbwd[slotbase + r] = bp[mi][e];
        }
    }
  } else {
    float nv[4][4];
#pragma unroll
    for (int mi = 0; mi < 4; ++mi)
#pragma unroll
      for (int e = 0; e < 4; ++e)
        nv[mi][e] = ninvL[lr0 + mi * 16 + kg * 4 + e];
#pragma unroll
    for (int ni = 0; ni < 4; ++ni) {
      float blv = j.bl[n0 + lc0 + ni * 16 + mr];
      float mx = -3.0e38f;
#pragma unroll
      for (int mi = 0; mi < 4; ++mi)
#pragma unroll
        for (int e = 0; e < 4; ++e) mx = fmaxf(mx, (acc[mi][ni][e] + blv) * nv[mi][e]);
      atomicMax(&colkey[lc0 + ni * 16 + mr], fkey(mx));
    }
    __syncthreads();
    if (tid < 128) j.cmax[(size_t)by * 1024 + n0 + tid] = kdec(colkey[tid]);
  }
}

// ---------------- prep dispatch B (merged with P): P-GEMM || unfolds || bw/bb || r3max ----------------
// [0,218): P GEMM blocks (EPI0, NBUF=1, M-rows scaled by sclr);
// [218,2522): U2b unfold; [2522,7642): U1b unfold; [7642,7722): bw/bb; [7722,8746): r3max
__global__ __launch_bounds__(256) void k_prepBP(Job pa, Job pb, int nbP0,
                                                const float* __restrict__ rsr2t, const float* __restrict__ rsr1t,
                                                const float* __restrict__ W1, const float* __restrict__ W2,
                                                const float* __restrict__ b1, const float* __restrict__ b2,
                                                const float* __restrict__ sclr, const float* __restrict__ scu3,
                                                const float* __restrict__ G2,
                                                unsigned short* __restrict__ U2b, unsigned short* __restrict__ U1b,
                                                float* __restrict__ bw2, float* __restrict__ bw1,
                                                float* __restrict__ bb,
                                                float* __restrict__ s3, int* __restrict__ arg) {
  const int blk = blockIdx.x;
  const int tid = threadIdx.x;
  if (blk < 218) {
    gemm_body<0, 1>(pa, pb, nbP0, xcdswz(blk, 218));
  } else if (blk < 2522) {
    int id = (blk - 218) * 256 + tid;          // < 589824
    int t = id & 15, rest = id >> 4;
    int kk = rest % 9, n = rest / 9;
    int cc0 = t * 8;
    int ki = kk / 3, kj = kk - ki * 3;
    int sy = (n >> 6) + ki - 1, sx = (n & 63) + kj - 1;
    bf8 v;
    if ((unsigned)sy < 64u && (unsigned)sx < 64u) {
      const float* p = rsr2t + (size_t)(sy * 64 + sx) * 128 + cc0;
      f32x4 a = *(const f32x4*)p;
      f32x4 bq = *(const f32x4*)(p + 4);
#pragma unroll
      for (int e = 0; e < 4; ++e) { v[e] = (short)f2bf(a[e]); v[4 + e] = (short)f2bf(bq[e]); }
    } else {
#pragma unroll
      for (int e = 0; e < 8; ++e) v[e] = 0;
    }
    *(bf8*)(U2b + (size_t)n * 1152 + kk * 128 + cc0) = v;
  } else if (blk < 7642) {
    int id = (blk - 2522) * 256 + tid;         // < 1310720
    int n = id / 80, rem = id - n * 80;
    int ks = rem >> 3, t = rem & 7;
    int cc0 = t * 8;
    bf8 v;
    if (ks == 9) {
#pragma unroll
      for (int e = 0; e < 8; ++e) v[e] = 0;
    } else {
      int ki = ks / 3, kj = ks - ki * 3;
      int sy = (n >> 7) + ki - 1, sx = (n & 127) + kj - 1;
      if ((unsigned)sy < 128u && (unsigned)sx < 128u) {
        const float* p = rsr1t + (size_t)(sy * 128 + sx) * 64 + cc0;
        f32x4 a = *(const f32x4*)p;
        f32x4 bq = *(const f32x4*)(p + 4);
#pragma unroll
        for (int e = 0; e < 4; ++e) { v[e] = (short)f2bf(a[e]); v[4 + e] = (short)f2bf(bq[e]); }
      } else {
#pragma unroll
        for (int e = 0; e < 8; ++e) v[e] = 0;
      }
    }
    *(bf8*)(U1b + (size_t)n * 640 + ks * 64 + cc0) = v;
  } else if (blk < 7722) {
    __shared__ float red[256];
    int idx = blk - 7642;
    int x = idx & 7, y = idx >> 3;             // y < 10
    if (y == 9) {
      if (x >= 2) return;
      const float* b = x ? b2 : b1;
      float s = 0.f;
      for (int d = tid; d < 2304; d += 256) s += b[d] * b[d];
      red[tid] = s; __syncthreads();
      for (int o = 128; o > 0; o >>= 1) { if (tid < o) red[tid] += red[tid + o]; __syncthreads(); }
      if (tid == 0) bb[x] = red[0];
      return;
    }
    const bool two = x < 5;
    const float* W = two ? W1 : W2;
    const float* b = two ? b1 : b2;
    float* bw = two ? bw2 : bw1;
    const int Cw = two ? 1152 : 576;
    int c = (two ? x : x - 5) * 256 + tid;
    if (c >= Cw) return;
    int d0 = y * 256;
    float s = 0.f;
    for (int d = d0; d < d0 + 256; ++d) s += b[d] * W[(size_t)d * Cw + c];
    atomicAdd(&bw[(c % 9) * (Cw / 9) + c / 9], s);   // permuted index
  } else {
    __shared__ float bv[256]; __shared__ int bidx[256];
    const int m = blk - 7722;
    const int mi = m >> 5, mj = m & 31;
    float best = -3.0e38f; int bi = 0;
    for (int n = tid; n < 1024; n += 256) {
      const int ni = n >> 5, nj = n & 31;
      float raw = 0.f;
#pragma unroll
      for (int dy = -1; dy <= 1; ++dy) {
#pragma unroll
        for (int dx = -1; dx <= 1; ++dx) {
          bool vm = ((unsigned)(mi + dy) < 32u) && ((unsigned)(mj + dx) < 32u);
          bool vn = ((unsigned)(ni + dy) < 32u) && ((unsigned)(nj + dx) < 32u);
          if (vm && vn) {
            int off = dy * 32 + dx;
            raw += G2[(size_t)(m + off) * 1024 + (n + off)];
          }
        }
      }
      float v = raw * scu3[n];
      if (v > best) { best = v; bi = n; }
    }
    bv[tid] = best; bidx[tid] = bi;
    __syncthreads();
    for (int o = 128; o > 0; o >>= 1) {
      if (tid < o) {
        float ov = bv[tid + o]; int oi = bidx[tid + o];
        if (ov > bv[tid] || (ov == bv[tid] && oi < bidx[tid])) { bv[tid] = ov; bidx[tid] = oi; }
      }
      __syncthreads();
    }
    if (tid == 0) { s3[m] = bv[0] * sclr[m]; arg[m] = bidx[0]; }
  }
}

__global__ __launch_bounds__(256) void k_gE1(Job a, Job b, int nb0) {
  gemm_body<1, 1>(a, b, nb0, xcdswz((int)blockIdx.x, (int)gridDim.x));
}
__global__ __launch_bounds__(256) void k_gE2(Job a, Job b, int nb0) {
  gemm_body<2, 1>(a, b, nb0, xcdswz((int)blockIdx.x, (int)gridDim.x));
}

// ---------------- fused gather+fold (vectorized) + S1/S2 finalize ----------------
__global__ __launch_bounds__(256) void k_tfold(const float* __restrict__ ref3, const float* __restrict__ ref2,
                                               const float* __restrict__ ref1, const int* __restrict__ arg,
                                               const float* __restrict__ cmax1, const float* __restrict__ cmax2,
                                               float* __restrict__ out) {
  const int bid = blockIdx.x;
  const int tid = threadIdx.x;
  if (bid < 256) {
    __shared__ float plane[1024];
    __shared__ int argL[1024];
    const int c = bid;
#pragma unroll
    for (int k = 0; k < 4; ++k) {
      plane[k * 256 + tid] = ref3[(size_t)c * 1024 + k * 256 + tid];
      argL[k * 256 + tid] = arg[k * 256 + tid];
    }
    __syncthreads();
#pragma unroll
    for (int k = 0; k < 4; ++k) {
      int px = k * 256 + tid;
      int y = px >> 5, x = px & 31;
      float s = 0.f;
#pragma unroll
      for (int di = -1; di <= 1; ++di) {
        int i = y + di;
        if ((unsigned)i >= 32u) continue;
#pragma unroll
        for (int dj = -1; dj <= 1; ++dj) {
          int jw = x + dj;
          if ((unsigned)jw >= 32u) continue;
          int n2 = argL[i * 32 + jw];
          int rr = (n2 >> 5) + y - i, cc = (n2 & 31) + x - jw;
          if ((unsigned)rr < 32u && (unsigned)cc < 32u) s += plane[rr * 32 + cc];
        }
      }
      out[3072 + (size_t)c * 1024 + px] = s * (1.f / 9.f);
    }
  } else if (bid < 1280) {
    __shared__ int argL[1024];
#pragma unroll
    for (int k = 0; k < 4; ++k) argL[k * 256 + tid] = arg[k * 256 + tid];
    __syncthreads();
    int id2 = (bid - 256) * 256 + tid;
    int q = id2 & 31, y = (id2 >> 5) & 63, c = id2 >> 11;
    int iy = y >> 1;
    float s0 = 0.f, s1 = 0.f;
#pragma unroll
    for (int di = -1; di <= 1; ++di) {
      int i = iy + di;
      if ((unsigned)i >= 32u) continue;
      int ry = y - 2 * i;
#pragma unroll
      for (int dj = -1; dj <= 1; ++dj) {
        int jw = q + dj;
        if ((unsigned)jw >= 32u) continue;
        int n2 = argL[i * 32 + jw];
        int rr = (n2 >> 5) * 2 + ry;
        int cb = (n2 & 31) * 2 + 2 * (q - jw);
        if ((unsigned)rr < 64u && (unsigned)cb < 63u) {
          const float* p = ref2 + (size_t)c * 4096 + rr * 64 + cb;
          s0 += p[0]; s1 += p[1];
        }
      }
    }
    float2 o; o.x = s0 * (1.f / 9.f); o.y = s1 * (1.f / 9.f);
    *(float2*)(out + 265216 + (size_t)c * 4096 + y * 64 + 2 * q) = o;
  } else if (bid < 2304) {
    __shared__ int argL[1024];
#pragma unroll
    for (int k = 0; k < 4; ++k) argL[k * 256 + tid] = arg[k * 256 + tid];
    __syncthreads();
    int id1 = (bid - 1280) * 256 + tid;
    int q = id1 & 31, y = (id1 >> 5) & 127, c = id1 >> 12;
    int iy = y >> 2;
    f32x4 s = {0.f, 0.f, 0.f, 0.f};
#pragma unroll
    for (int di = -1; di <= 1; ++di) {
      int i = iy + di;
      if ((unsigned)i >= 32u) continue;
      int ry = y - 4 * i;
#pragma unroll
      for (int dj = -1; dj <= 1; ++dj) {
        int jw = q + dj;
        if ((unsigned)jw >= 32u) continue;
        int n2 = argL[i * 32 + jw];
        int rr = (n2 >> 5) * 4 + ry;
        int cb = (n2 & 31) * 4 + 4 * (q - jw);
        if ((unsigned)rr < 128u && (unsigned)cb < 125u) {
          f32x4 v = *(const f32x4*)(ref1 + (size_t)c * 16384 + rr * 128 + cb);
          s += v;
        }
      }
    }
    s *= (1.f / 9.f);
    *(f32x4*)(out + 789504 + (size_t)c * 16384 + y * 128 + 4 * q) = s;
  } else {
    int t = (bid - 2304) * 256 + tid;  // 0..2047
    if (t < 1024) {
      float mx = -3.0e38f;
      for (int rb = 0; rb < 128; ++rb) mx = fmaxf(mx, cmax1[rb * 1024 + t]);
      out[t] = mx;            // S_1
    } else {
      int tt = t - 1024;
      float mx = -3.0e38f;
      for (int rb = 0; rb < 32; ++rb) mx = fmaxf(mx, cmax2[rb * 1024 + tt]);
      out[1024 + tt] = mx;    // S_2
    }
  }
}

// ---------------- workspace layout (bytes) ----------------
static constexpr size_t OFF_BW2     = 0;                        // 1152 f32
static constexpr size_t OFF_BW1     = 4608;                     // 640 f32
static constexpr size_t ZERO_BYTES  = 7168;
static constexpr size_t OFF_BB      = 7168;                     // 2 f32 (pad to 256)
static constexpr size_t OFF_BL2     = 7424;                     // 1024 f32
static constexpr size_t OFF_BL1     = 11520;                    // 1024 f32
static constexpr size_t OFF_SCLR    = 15616;                    // 1024 f32
static constexpr size_t OFF_SCU3    = 19712;                    // 1024 f32
static constexpr size_t OFF_R3ARG   = 23808;                    // 1024 int
static constexpr size_t OFF_PNSQ2   = 27904;                    // f32 [18][4096]
static constexpr size_t OFF_PBWD2   = OFF_PNSQ2 + 294912;       // f32 [18][4096]
static constexpr size_t OFF_PNSQ1   = OFF_PBWD2 + 294912;       // f32 [10][16384]
static constexpr size_t OFF_PBWD1   = OFF_PNSQ1 + 655360;       // f32 [10][16384]
static constexpr size_t OFF_CMAX2   = OFF_PBWD1 + 655360;       // f32 [32][1024]
static constexpr size_t OFF_CMAX1   = OFF_CMAX2 + 131072;       // f32 [128][1024]
static constexpr size_t OFF_LR3NBT  = OFF_CMAX1 + 524288;       // bf16 [1024][2304] (RAW)
static constexpr size_t OFF_U2B     = OFF_LR3NBT + 4718592;     // bf16 [4096][1152] (perm K)
static constexpr size_t OFF_U1B     = OFF_U2B    + 9437184;     // bf16 [16384][640] (perm K)
static constexpr size_t OFF_W1T     = OFF_U1B    + 20971520;    // bf16 [1152][2304] (perm rows)
static constexpr size_t OFF_W2T     = OFF_W1T    + 5308416;     // bf16 [640][2304] (perm rows; 576+ zero)
static constexpr size_t OFF_A2      = OFF_W2T    + 2949120;     // bf16 [1152][1152]
static constexpr size_t OFF_A1      = OFF_A2     + 2654208;     // bf16 [640][640]
static constexpr size_t OFF_M2T     = OFF_A1     + 819200;      // bf16 [1024][1152]
static constexpr size_t OFF_M1T     = OFF_M2T    + 2359296;     // bf16 [1024][640]
static constexpr size_t OFF_G2      = OFF_M1T    + 1310720;     // f32 [1024][1024]
static constexpr size_t OFF_R2T     = OFF_G2     + 4194304;     // f32 [4096][128]
static constexpr size_t OFF_R1T     = OFF_R2T    + 2097152;     // f32 [16384][64]

extern "C" void kernel_launch(void* const* d_in, const int* in_sizes, int n_in,
                              void* d_out, int out_size, void* d_ws, size_t ws_size,
                              hipStream_t stream) {
  (void)in_sizes; (void)n_in; (void)out_size; (void)ws_size;
  const float* lrsr3  = (const float*)d_in[0];
  const float* rsr1   = (const float*)d_in[1];
  const float* rsr2   = (const float*)d_in[2];
  const float* rsr3   = (const float*)d_in[3];
  const float* ref1   = (const float*)d_in[4];
  const float* ref2   = (const float*)d_in[5];
  const float* ref3   = (const float*)d_in[6];
  const float* W1     = (const float*)d_in[7];
  const float* b1     = (const float*)d_in[8];
  const float* W2     = (const float*)d_in[9];
  const float* b2     = (const float*)d_in[10];
  float* out = (float*)d_out;
  char* ws = (char*)d_ws;

  float*          bw2     = (float*)(ws + OFF_BW2);
  float*          bw1     = (float*)(ws + OFF_BW1);
  float*          bb      = (float*)(ws + OFF_BB);
  float*          bl2     = (float*)(ws + OFF_BL2);
  float*          bl1     = (float*)(ws + OFF_BL1);
  float*          sclr    = (float*)(ws + OFF_SCLR);
  float*          scu3    = (float*)(ws + OFF_SCU3);
  int*            R3arg   = (int*)(ws + OFF_R3ARG);
  float*          pnsq2   = (float*)(ws + OFF_PNSQ2);
  float*          pbwd2   = (float*)(ws + OFF_PBWD2);
  float*          pnsq1   = (float*)(ws + OFF_PNSQ1);
  float*          pbwd1   = (float*)(ws + OFF_PBWD1);
  float*          cmax2   = (float*)(ws + OFF_CMAX2);
  float*          cmax1   = (float*)(ws + OFF_CMAX1);
  unsigned short* lr3nbT  = (unsigned short*)(ws + OFF_LR3NBT);
  unsigned short* U2b     = (unsigned short*)(ws + OFF_U2B);
  unsigned short* U1b     = (unsigned short*)(ws + OFF_U1B);
  unsigned short* W1t     = (unsigned short*)(ws + OFF_W1T);
  unsigned short* W2t     = (unsigned short*)(ws + OFF_W2T);
  unsigned short* A2b     = (unsigned short*)(ws + OFF_A2);
  unsigned short* A1b     = (unsigned short*)(ws + OFF_A1);
  unsigned short* M2tb    = (unsigned short*)(ws + OFF_M2T);
  unsigned short* M1tb    = (unsigned short*)(ws + OFF_M1T);
  float*          G2      = (float*)(ws + OFF_G2);
  float*          rsr2t   = (float*)(ws + OFF_R2T);
  float*          rsr1t   = (float*)(ws + OFF_R1T);

  hipMemsetAsync(d_ws, 0, ZERO_BYTES, stream);
  // zero pad rows 576..639 of W2t
  hipMemsetAsync(ws + OFF_W2T + (size_t)576 * 2304 * 2, 0, (size_t)64 * 2304 * 2, stream);

  // A: colnorms || pixel Gram || channels-last transposes || RAW lr3nb unfold || W transposes
  k_prepA<<<5580, 256, 0, stream>>>(lrsr3, rsr3, rsr2, rsr1, W1, W2, b1, b2,
                                    sclr, scu3, bl2, bl1, G2, rsr2t, rsr1t, lr3nbT, W1t, W2t);

  Job jz = {};
  // B+P: P-GEMM (Gram + M^T with deferred sclr scaling) || U unfolds || bw/bb || r3max
  {
    Job a = jz, b = jz;
    a.Alo = W1t; a.Ahi = lr3nbT; a.Msplit = 1152; a.Bt = W1t;
    a.Clo = A2b; a.Chi = M2tb; a.rowscale = sclr; a.N = 1152; a.K = 2304; a.nbx = 9;
    b.Alo = W2t; b.Ahi = lr3nbT; b.Msplit = 640; b.Bt = W2t;
    b.Clo = A1b; b.Chi = M1tb; b.rowscale = sclr; b.N = 640; b.K = 2304; b.nbx = 5;
    k_prepBP<<<8746, 256, 0, stream>>>(a, b, 153, rsr2t, rsr1t, W1, W2, b1, b2, sclr, scu3, G2,
                                       U2b, U1b, bw2, bw1, bb, out + 2048, R3arg);
  }
  // E1: per-(colblock,half) norm/bw partials
  {
    Job a = jz, b = jz;
    a.Alo = U2b; a.Ahi = U2b; a.Msplit = 4096; a.Bt = A2b;
    a.bw = bw2; a.pnsq = pnsq2; a.pbwd = pbwd2; a.Mtot = 4096;
    a.N = 1152; a.K = 1152; a.nbx = 9;
    b.Alo = U1b; b.Ahi = U1b; b.Msplit = 16384; b.Bt = A1b;
    b.bw = bw1; b.pnsq = pnsq1; b.pbwd = pbwd1; b.Mtot = 16384;
    b.N = 640; b.K = 640; b.nbx = 5;
    k_gE1<<<288 + 640, 256, 0, stream>>>(a, b, 288);
  }
  // E2: score max (per-block ninv from partials)
  {
    Job a = jz, b = jz;
    a.Alo = U2b; a.Ahi = U2b; a.Msplit = 4096; a.Bt = M2tb;
    a.bl = bl2; a.pnsq = pnsq2; a.pbwd = pbwd2; a.bbp = bb;
    a.npart = 18; a.which = 0; a.cmax = cmax2; a.Mtot = 4096;
    a.N = 1024; a.K = 1152; a.nbx = 8;
    b.Alo = U1b; b.Ahi = U1b; b.Msplit = 16384; b.Bt = M1tb;
    b.bl = bl1; b.pnsq = pnsq1; b.pbwd = pbwd1; b.bbp = bb;
    b.npart = 10; b.which = 1; b.cmax = cmax1; b.Mtot = 16384;
    b.N = 1024; b.K = 640; b.nbx = 8;
    k_gE2<<<256 + 1024, 256, 0, stream>>>(a, b, 256);
  }

  // transfer + S1/S2 finalize (fused, vectorized gathers)
  k_tfold<<<2312, 256, 0, stream>>>(ref3, ref2, ref1, R3arg, cmax1, cmax2, out);
}

// Round 16
// 207.936 us; speedup vs baseline: 1.6209x; 1.1136x over previous
//
#include <hip/hip_runtime.h>

typedef short bf8 __attribute__((ext_vector_type(8)));
typedef float f32x4 __attribute__((ext_vector_type(4)));

static __device__ __forceinline__ unsigned short f2bf(float f) {
  unsigned u = __float_as_uint(f);
  unsigned r = u + 0x7FFFu + ((u >> 16) & 1u);
  return (unsigned short)(r >> 16);
}
static __device__ __forceinline__ float bf2f(unsigned short h) {
  return __uint_as_float(((unsigned)h) << 16);
}
static __device__ __forceinline__ unsigned fkey(float f) {
  unsigned u = __float_as_uint(f);
  return (u & 0x80000000u) ? ~u : (u | 0x80000000u);
}
static __device__ __forceinline__ float kdec(unsigned k) {
  unsigned u = (k & 0x80000000u) ? (k & 0x7FFFFFFFu) : ~k;
  return __uint_as_float(u);
}
// bijective XCD-chunked swizzle (m204)
static __device__ __forceinline__ int xcdswz(int h, int nwg) {
  int q = nwg >> 3, r = nwg & 7;
  int xcd = h & 7, w = h >> 3;
  return (xcd < r ? xcd * (q + 1) : r * (q + 1) + (xcd - r) * q) + w;
}
// balanced dual-job XCD chunking: each XCD gets contiguous chunks of BOTH jobs
// (requires nb0 % 8 == 0 and (nwg-nb0) % 8 == 0). Fixes inter-job XCD imbalance
// while keeping per-XCD panel contiguity (round-15 lesson).
static __device__ __forceinline__ int xcdbal(int h, int nwg, int nb0) {
  int xcd = h & 7, w = h >> 3;
  int qa = nb0 >> 3, qb = (nwg - nb0) >> 3;
  return (w < qa) ? (xcd * qa + w) : (nb0 + xcd * qb + (w - qa));
}

// async global->LDS, 16B per lane. lds dest: wave-uniform base + lane*16.
static __device__ __forceinline__ void gload_lds16(const unsigned short* g, unsigned short* l) {
  __builtin_amdgcn_global_load_lds((const __attribute__((address_space(1))) void*)g,
                                   (__attribute__((address_space(3))) void*)l, 16, 0, 0);
}

// unfold(k=3,pad=1,stride=1) value: row d = (cc*3+ki)*3+kj, col m = i*S+j, src [C][S][S]
static __device__ __forceinline__ float uf3(const float* __restrict__ src, int lgS, int d, int m) {
  const int S = 1 << lgS;
  int cc = d / 9;
  int r9 = d - cc * 9;
  int ki = r9 / 3;
  int kj = r9 - ki * 3;
  int i = (m >> lgS) + ki - 1;
  int j = (m & (S - 1)) + kj - 1;
  if ((unsigned)i >= (unsigned)S || (unsigned)j >= (unsigned)S) return 0.f;
  return src[((size_t)cc << (2 * lgS)) + ((size_t)i << lgS) + j];
}

// ---------------- prep dispatch A ----------------
// [0,2048): colnorms (+bias dots for lrsr3); [2048,3072): pixgram; [3072,3200): rsr2t; [3200,3456): rsr1t;
// [3456,4608): RAW lr3nb unfold -> lr3nbT bf16 (scale deferred to P epilogue); [4608,5580): W transposes
__global__ __launch_bounds__(256) void k_prepA(const float* __restrict__ lrsr3, const float* __restrict__ rsr3,
                                               const float* __restrict__ rsr2, const float* __restrict__ rsr1,
                                               const float* __restrict__ W1, const float* __restrict__ W2,
                                               const float* __restrict__ b1, const float* __restrict__ b2,
                                               float* __restrict__ sclr, float* __restrict__ scu3,
                                               float* __restrict__ bl2, float* __restrict__ bl1,
                                               float* __restrict__ G2,
                                               float* __restrict__ rsr2t, float* __restrict__ rsr1t,
                                               unsigned short* __restrict__ lr3nbT,
                                               unsigned short* __restrict__ W1t, unsigned short* __restrict__ W2t) {
  const int blk = blockIdx.x;
  const int tid = threadIdx.x;
  if (blk < 2048) {
    __shared__ float r0[256], r1[256], r2[256];
    const bool lr = blk < 1024;
    const int m = blk & 1023;
    const float* src = lr ? lrsr3 : rsr3;
    float s = 0.f, d1 = 0.f, d2 = 0.f;
    for (int d = tid; d < 2304; d += 256) {
      float v = uf3(src, 5, d, m);
      s += v * v; d1 += b1[d] * v; d2 += b2[d] * v;
    }
    r0[tid] = s; r1[tid] = d1; r2[tid] = d2;
    __syncthreads();
    for (int o = 128; o > 0; o >>= 1) {
      if (tid < o) { r0[tid] += r0[tid + o]; r1[tid] += r1[tid + o]; r2[tid] += r2[tid + o]; }
      __syncthreads();
    }
    if (tid == 0) {
      float sc = 1.f / fmaxf(sqrtf(r0[0]), 1e-12f);
      if (lr) { sclr[m] = sc; bl2[m] = r1[0] * sc; bl1[m] = r2[0] * sc; }
      else    { scu3[m] = sc; }
    }
  } else if (blk < 3072) {
    __shared__ float As[16][32], Bs[16][32];
    const int px = blk - 2048;
    const int m0 = (px >> 5) * 32, n0 = (px & 31) * 32;
    const int tx = tid & 15, ty = tid >> 4;
    float acc[2][2] = {};
    for (int kb = 0; kb < 256; kb += 16) {
      __syncthreads();
      {
        int kk = tid >> 5, mm = tid & 31;
        As[kk][mm] = lrsr3[(size_t)(kb + kk) * 1024 + m0 + mm];
        Bs[kk][mm] = rsr3[(size_t)(kb + kk) * 1024 + n0 + mm];
        int e2 = tid + 256; int kk2 = e2 >> 5, mm2 = e2 & 31;
        As[kk2][mm2] = lrsr3[(size_t)(kb + kk2) * 1024 + m0 + mm2];
        Bs[kk2][mm2] = rsr3[(size_t)(kb + kk2) * 1024 + n0 + mm2];
      }
      __syncthreads();
#pragma unroll
      for (int kk = 0; kk < 16; ++kk) {
        float a0 = As[kk][ty * 2], a1 = As[kk][ty * 2 + 1];
        float b0 = Bs[kk][tx * 2], b1v = Bs[kk][tx * 2 + 1];
        acc[0][0] = fmaf(a0, b0, acc[0][0]); acc[0][1] = fmaf(a0, b1v, acc[0][1]);
        acc[1][0] = fmaf(a1, b0, acc[1][0]); acc[1][1] = fmaf(a1, b1v, acc[1][1]);
      }
    }
#pragma unroll
    for (int i = 0; i < 2; ++i)
#pragma unroll
      for (int jj = 0; jj < 2; ++jj)
        G2[(size_t)(m0 + ty * 2 + i) * 1024 + (n0 + tx * 2 + jj)] = acc[i][jj];
  } else if (blk < 3200) {
    __shared__ float Tt[64][65];
    const int idx = blk - 3072;
    const int ct = idx & 1, st = idx >> 1;
#pragma unroll
    for (int i = 0; i < 16; ++i) {
      int id = tid + i * 256;
      int r = id >> 6, c = id & 63;
      Tt[r][c] = rsr2[(size_t)(ct * 64 + r) * 4096 + st * 64 + c];
    }
    __syncthreads();
#pragma unroll
    for (int i = 0; i < 16; ++i) {
      int id = tid + i * 256;
      int cc2 = id >> 6, rr = id & 63;
      rsr2t[(size_t)(st * 64 + cc2) * 128 + ct * 64 + rr] = Tt[rr][cc2];
    }
  } else if (blk < 3456) {
    __shared__ float Tt[64][65];
    const int st = blk - 3200;
#pragma unroll
    for (int i = 0; i < 16; ++i) {
      int id = tid + i * 256;
      int r = id >> 6, c = id & 63;
      Tt[r][c] = rsr1[(size_t)r * 16384 + st * 64 + c];
    }
    __syncthreads();
#pragma unroll
    for (int i = 0; i < 16; ++i) {
      int id = tid + i * 256;
      int cc2 = id >> 6, rr = id & 63;
      rsr1t[(size_t)(st * 64 + cc2) * 64 + rr] = Tt[rr][cc2];
    }
  } else if (blk < 4608) {
    // RAW lr3nb unfold (normalization deferred to P's M-row epilogue)
    int id8 = (blk - 3456) * 256 + tid;        // < 294912
    int m = id8 / 288, c0 = (id8 - m * 288) * 8;
    bf8 v;
#pragma unroll
    for (int e = 0; e < 8; ++e) v[e] = (short)f2bf(uf3(lrsr3, 5, c0 + e, m));
    *(bf8*)(lr3nbT + (size_t)m * 2304 + c0) = v;
  } else {
    __shared__ unsigned short Ls[64][65];
    int idx = blk - 4608;
    int xx = idx % 27, yy = idx / 27;          // yy < 36
    const float* W; unsigned short* Wt; int Cw, c0;
    if (xx < 18) { W = W1; Wt = W1t; Cw = 1152; c0 = xx * 64; }
    else         { W = W2; Wt = W2t; Cw = 576;  c0 = (xx - 18) * 64; }
    const int Cch = Cw / 9;
    const int d0 = yy * 64;
#pragma unroll
    for (int i = 0; i < 16; ++i) {
      int id = tid + i * 256;
      int r = id >> 6, c = id & 63;
      Ls[r][c] = f2bf(W[(size_t)(d0 + r) * Cw + c0 + c]);
    }
    __syncthreads();
#pragma unroll
    for (int i = 0; i < 16; ++i) {
      int id = tid + i * 256;
      int cc = id >> 6, rr = id & 63;
      int c = c0 + cc;
      Wt[(size_t)((c % 9) * Cch + c / 9) * 2304 + d0 + rr] = Ls[rr][cc];
    }
  }
}

// ---------------- bf16 MFMA GEMM body: 128x128 tile, BK=64, 4 waves ----------------
// NBUF==1: m97 single-buffer loop. NBUF>=2: counted-vmcnt rotating pipeline.
// EPI 0: store bf16 C (rows >= Msplit scaled by rowscale[row-Msplit]).
// EPI 1: per-(colblock,wave-half) partials (unique writer slot = bx*2+wc).
// EPI 2: per-block ninv from partials (LDS prologue), cmax stores.
struct Job {
  const unsigned short* Alo;
  const unsigned short* Ahi;
  const unsigned short* Bt;
  unsigned short* Clo;
  unsigned short* Chi;
  const float* bl;
  const float* bw;
  const float* bbp;
  const float* rowscale;
  float* pnsq;
  float* pbwd;
  float* cmax;
  int Msplit, N, K, nbx, Mtot, npart, which;
};

template <int EPI, int NBUF>
static __device__ __forceinline__ void gemm_body(const Job& j0, const Job& j1, int nb0, int bid) {
  __shared__ __align__(16) unsigned short As[NBUF][128 * 64];
  __shared__ __align__(16) unsigned short Bs[NBUF][128 * 64];
  __shared__ unsigned colkey[128];
  __shared__ float ninvL[128];

  const bool first = (bid < nb0);
  const Job j = first ? j0 : j1;
  const int local = bid - (first ? 0 : nb0);
  const int by = local / j.nbx;
  const int bx = local - by * j.nbx;
  const int m0 = by * 128, n0 = bx * 128;
  const int K = j.K, N = j.N;

  const unsigned short* Abase = (m0 < j.Msplit)
      ? j.Alo + (size_t)m0 * K
      : j.Ahi + (size_t)(m0 - j.Msplit) * K;

  const int tid = threadIdx.x;
  const int l = tid & 63;
  const int w = tid >> 6;
  const int wr = w >> 1, wc = w & 1;
  if (EPI == 2) {
    if (tid < 128) {
      colkey[tid] = 0u;
      const int r = m0 + tid;
      float nsq = 0.f, bwd = 0.f;
      for (int p = 0; p < j.npart; ++p) {
        nsq += j.pnsq[(size_t)p * j.Mtot + r];
        bwd += j.pbwd[(size_t)p * j.Mtot + r];
      }
      float tq = nsq + 2.f * bwd + j.bbp[j.which];
      ninvL[tid] = 1.f / fmaxf(sqrtf(fmaxf(tq, 0.f)), 1e-12f);
    }
  }

  f32x4 acc[4][4] = {};

  const int srow = w * 32;
  const int lrow = l >> 3;
  const int gcol = ((l & 7) ^ lrow) * 8;
  const int mr = l & 15;
  const int kg = l >> 4;

  const int nt = K >> 6;
  const int snap_kb = n0 + wc * 64;
  unsigned short snap[4][4][4];

  auto stage = [&](int buf, int kb) {
#pragma unroll
    for (int i = 0; i < 4; ++i) {
      int r = srow + i * 8;
      gload_lds16(Abase + (size_t)(r + lrow) * K + kb + gcol, &As[buf][r * 64]);
      gload_lds16(j.Bt + (size_t)(n0 + r + lrow) * K + kb + gcol, &Bs[buf][r * 64]);
    }
  };
  auto compute_tile = [&](int cur) {
#pragma unroll
    for (int ks = 0; ks < 2; ++ks) {
      bf8 af[4], bv[4];
#pragma unroll
      for (int mi = 0; mi < 4; ++mi) {
        const int row = wr * 64 + mi * 16 + mr;
        af[mi] = *(const bf8*)&As[cur][row * 64 + (((ks * 4 + kg) ^ (row & 7)) * 8)];
      }
#pragma unroll
      for (int ni = 0; ni < 4; ++ni) {
        const int row = wc * 64 + ni * 16 + mr;
        bv[ni] = *(const bf8*)&Bs[cur][row * 64 + (((ks * 4 + kg) ^ (row & 7)) * 8)];
      }
      __builtin_amdgcn_s_setprio(1);
#pragma unroll
      for (int mi = 0; mi < 4; ++mi)
#pragma unroll
        for (int ni = 0; ni < 4; ++ni)
          acc[mi][ni] = __builtin_amdgcn_mfma_f32_16x16x32_bf16(af[mi], bv[ni], acc[mi][ni], 0, 0, 0);
      __builtin_amdgcn_s_setprio(0);
    }
  };
  auto do_snap = [&](int cur) {
#pragma unroll
    for (int mi = 0; mi < 4; ++mi)
#pragma unroll
      for (int e = 0; e < 4; ++e) {
        const int row = wr * 64 + mi * 16 + kg * 4 + e;
#pragma unroll
        for (int ni = 0; ni < 4; ++ni) {
          const int slot = ni * 2 + (mr >> 3);
          snap[mi][ni][e] = As[cur][row * 64 + ((slot ^ (row & 7)) * 8) + (mr & 7)];
        }
      }
  };

  if constexpr (NBUF == 1) {
    for (int t = 0; t < nt; ++t) {
      if (t) __syncthreads();
      stage(0, t << 6);
      __syncthreads();
      compute_tile(0);
      if (EPI == 1 && (t << 6) == snap_kb) do_snap(0);
    }
  } else {
    auto waitv = [&](int Wt) {
      if (Wt >= 2)      asm volatile("s_waitcnt vmcnt(16)\ns_barrier" ::: "memory");
      else if (Wt == 1) asm volatile("s_waitcnt vmcnt(8)\ns_barrier" ::: "memory");
      else              asm volatile("s_waitcnt vmcnt(0)\ns_barrier" ::: "memory");
    };
#pragma unroll
    for (int p = 0; p < NBUF; ++p) if (p < nt) stage(p, p << 6);
    { int inflight = (NBUF < nt ? NBUF : nt); waitv(inflight - 1); }
    int cur = 0;
    for (int t = 0; t < nt; ++t) {
      compute_tile(cur);
      if (EPI == 1 && (t << 6) == snap_kb) do_snap(cur);
      if (t + 1 < nt) {
        asm volatile("s_waitcnt lgkmcnt(0)\ns_barrier" ::: "memory");
        if (t + NBUF < nt) stage(cur, (t + NBUF) << 6);
        const int im = (nt - 1 < t + NBUF) ? (nt - 1) : (t + NBUF);
        waitv(im - (t + 1));
        cur = (cur + 1 == NBUF) ? 0 : cur + 1;
      }
    }
  }

  // C/D frag layout: col = mr, row = kg*4 + e (within 16x16)
  const int lr0 = wr * 64;
  const int lc0 = wc * 64;
  if (EPI == 0) {
    const bool hi = (m0 >= j.Msplit);
    unsigned short* Cbase = hi ? j.Chi + (size_t)(m0 - j.Msplit) * N
                               : j.Clo + (size_t)m0 * N;
    float rs[4][4];
#pragma unroll
    for (int mi = 0; mi < 4; ++mi)
#pragma unroll
      for (int e = 0; e < 4; ++e)
        rs[mi][e] = hi ? j.rowscale[m0 - j.Msplit + lr0 + mi * 16 + kg * 4 + e] : 1.f;
#pragma unroll
    for (int mi = 0; mi < 4; ++mi)
#pragma unroll
      for (int ni = 0; ni < 4; ++ni)
#pragma unroll
        for (int e = 0; e < 4; ++e)
          Cbase[(size_t)(lr0 + mi * 16 + kg * 4 + e) * (size_t)N + (n0 + lc0 + ni * 16 + mr)] =
              f2bf(acc[mi][ni][e] * rs[mi][e]);
  } else if (EPI == 1) {
    float rp[4][4] = {};
    float bp[4][4] = {};
#pragma unroll
    for (int ni = 0; ni < 4; ++ni) {
      const float bwv = j.bw[n0 + lc0 + ni * 16 + mr];
#pragma unroll
      for (int mi = 0; mi < 4; ++mi)
#pragma unroll
        for (int e = 0; e < 4; ++e) {
          const float av = bf2f(snap[mi][ni][e]);
          rp[mi][e] += acc[mi][ni][e] * av;
          bp[mi][e] += bwv * av;
        }
    }
#pragma unroll
    for (int off = 1; off < 16; off <<= 1)
#pragma unroll
      for (int mi = 0; mi < 4; ++mi)
#pragma unroll
        for (int e = 0; e < 4; ++e) {
          rp[mi][e] += __shfl_xor(rp[mi][e], off);
          bp[mi][e] += __shfl_xor(bp[mi][e], off);
        }
    if (mr == 0) {
      const size_t slotbase = (size_t)(bx * 2 + wc) * j.Mtot;
#pragma unroll
      for (int mi = 0; mi < 4; ++mi)
#pragma unroll
        for (int e = 0; e < 4; ++e) {
          const int r = m0 + lr0 + mi * 16 + kg * 4 + e;
          j.pnsq[slotbase + r] = rp[mi][e];
          j.pbwd[slotbase + r] = bp[mi][e];
        }
    }
  } else {
    float nv[4][4];
#pragma unroll
    for (int mi = 0; mi < 4; ++mi)
#pragma unroll
      for (int e = 0; e < 4; ++e)
        nv[mi][e] = ninvL[lr0 + mi * 16 + kg * 4 + e];
#pragma unroll
    for (int ni = 0; ni < 4; ++ni) {
      float blv = j.bl[n0 + lc0 + ni * 16 + mr];
      float mx = -3.0e38f;
#pragma unroll
      for (int mi = 0; mi < 4; ++mi)
#pragma unroll
        for (int e = 0; e < 4; ++e) mx = fmaxf(mx, (acc[mi][ni][e] + blv) * nv[mi][e]);
      atomicMax(&colkey[lc0 + ni * 16 + mr], fkey(mx));
    }
    __syncthreads();
    if (tid < 128) j.cmax[(size_t)by * 1024 + n0 + tid] = kdec(colkey[tid]);
  }
}

// ---------------- prep dispatch B (merged with P): P-GEMM || unfolds || bw/bb || r3max ----------------
// [0,218): P GEMM blocks (EPI0, NBUF=1, M-rows scaled by sclr);
// [218,2522): U2b unfold; [2522,7642): U1b unfold; [7642,7722): bw/bb; [7722,8746): r3max
__global__ __launch_bounds__(256) void k_prepBP(Job pa, Job pb, int nbP0,
                                                const float* __restrict__ rsr2t, const float* __restrict__ rsr1t,
                                                const float* __restrict__ W1, const float* __restrict__ W2,
                                                const float* __restrict__ b1, const float* __restrict__ b2,
                                                const float* __restrict__ sclr, const float* __restrict__ scu3,
                                                const float* __restrict__ G2,
                                                unsigned short* __restrict__ U2b, unsigned short* __restrict__ U1b,
                                                float* __restrict__ bw2, float* __restrict__ bw1,
                                                float* __restrict__ bb,
                                                float* __restrict__ s3, int* __restrict__ arg) {
  const int blk = blockIdx.x;
  const int tid = threadIdx.x;
  if (blk < 218) {
    gemm_body<0, 1>(pa, pb, nbP0, xcdswz(blk, 218));
  } else if (blk < 2522) {
    int id = (blk - 218) * 256 + tid;          // < 589824
    int t = id & 15, rest = id >> 4;
    int kk = rest % 9, n = rest / 9;
    int cc0 = t * 8;
    int ki = kk / 3, kj = kk - ki * 3;
    int sy = (n >> 6) + ki - 1, sx = (n & 63) + kj - 1;
    bf8 v;
    if ((unsigned)sy < 64u && (unsigned)sx < 64u) {
      const float* p = rsr2t + (size_t)(sy * 64 + sx) * 128 + cc0;
      f32x4 a = *(const f32x4*)p;
      f32x4 bq = *(const f32x4*)(p + 4);
#pragma unroll
      for (int e = 0; e < 4; ++e) { v[e] = (short)f2bf(a[e]); v[4 + e] = (short)f2bf(bq[e]); }
    } else {
#pragma unroll
      for (int e = 0; e < 8; ++e) v[e] = 0;
    }
    *(bf8*)(U2b + (size_t)n * 1152 + kk * 128 + cc0) = v;
  } else if (blk < 7642) {
    int id = (blk - 2522) * 256 + tid;         // < 1310720
    int n = id / 80, rem = id - n * 80;
    int ks = rem >> 3, t = rem & 7;
    int cc0 = t * 8;
    bf8 v;
    if (ks == 9) {
#pragma unroll
      for (int e = 0; e < 8; ++e) v[e] = 0;
    } else {
      int ki = ks / 3, kj = ks - ki * 3;
      int sy = (n >> 7) + ki - 1, sx = (n & 127) + kj - 1;
      if ((unsigned)sy < 128u && (unsigned)sx < 128u) {
        const float* p = rsr1t + (size_t)(sy * 128 + sx) * 64 + cc0;
        f32x4 a = *(const f32x4*)p;
        f32x4 bq = *(const f32x4*)(p + 4);
#pragma unroll
        for (int e = 0; e < 4; ++e) { v[e] = (short)f2bf(a[e]); v[4 + e] = (short)f2bf(bq[e]); }
      } else {
#pragma unroll
        for (int e = 0; e < 8; ++e) v[e] = 0;
      }
    }
    *(bf8*)(U1b + (size_t)n * 640 + ks * 64 + cc0) = v;
  } else if (blk < 7722) {
    __shared__ float red[256];
    int idx = blk - 7642;
    int x = idx & 7, y = idx >> 3;             // y < 10
    if (y == 9) {
      if (x >= 2) return;
      const float* b = x ? b2 : b1;
      float s = 0.f;
      for (int d = tid; d < 2304; d += 256) s += b[d] * b[d];
      red[tid] = s; __syncthreads();
      for (int o = 128; o > 0; o >>= 1) { if (tid < o) red[tid] += red[tid + o]; __syncthreads(); }
      if (tid == 0) bb[x] = red[0];
      return;
    }
    const bool two = x < 5;
    const float* W = two ? W1 : W2;
    const float* b = two ? b1 : b2;
    float* bw = two ? bw2 : bw1;
    const int Cw = two ? 1152 : 576;
    int c = (two ? x : x - 5) * 256 + tid;
    if (c >= Cw) return;
    int d0 = y * 256;
    float s = 0.f;
    for (int d = d0; d < d0 + 256; ++d) s += b[d] * W[(size_t)d * Cw + c];
    atomicAdd(&bw[(c % 9) * (Cw / 9) + c / 9], s);   // permuted index
  } else {
    __shared__ float bv[256]; __shared__ int bidx[256];
    const int m = blk - 7722;
    const int mi = m >> 5, mj = m & 31;
    float best = -3.0e38f; int bi = 0;
    for (int n = tid; n < 1024; n += 256) {
      const int ni = n >> 5, nj = n & 31;
      float raw = 0.f;
#pragma unroll
      for (int dy = -1; dy <= 1; ++dy) {
#pragma unroll
        for (int dx = -1; dx <= 1; ++dx) {
          bool vm = ((unsigned)(mi + dy) < 32u) && ((unsigned)(mj + dx) < 32u);
          bool vn = ((unsigned)(ni + dy) < 32u) && ((unsigned)(nj + dx) < 32u);
          if (vm && vn) {
            int off = dy * 32 + dx;
            raw += G2[(size_t)(m + off) * 1024 + (n + off)];
          }
        }
      }
      float v = raw * scu3[n];
      if (v > best) { best = v; bi = n; }
    }
    bv[tid] = best; bidx[tid] = bi;
    __syncthreads();
    for (int o = 128; o > 0; o >>= 1) {
      if (tid < o) {
        float ov = bv[tid + o]; int oi = bidx[tid + o];
        if (ov > bv[tid] || (ov == bv[tid] && oi < bidx[tid])) { bv[tid] = ov; bidx[tid] = oi; }
      }
      __syncthreads();
    }
    if (tid == 0) { s3[m] = bv[0] * sclr[m]; arg[m] = bidx[0]; }
  }
}

__global__ __launch_bounds__(256) void k_gE1(Job a, Job b, int nb0) {
  gemm_body<1, 1>(a, b, nb0, xcdbal((int)blockIdx.x, (int)gridDim.x, nb0));
}
__global__ __launch_bounds__(256) void k_gE2(Job a, Job b, int nb0) {
  gemm_body<2, 1>(a, b, nb0, xcdbal((int)blockIdx.x, (int)gridDim.x, nb0));
}

// ---------------- fused gather+fold (vectorized) + S1/S2 finalize ----------------
__global__ __launch_bounds__(256) void k_tfold(const float* __restrict__ ref3, const float* __restrict__ ref2,
                                               const float* __restrict__ ref1, const int* __restrict__ arg,
                                               const float* __restrict__ cmax1, const float* __restrict__ cmax2,
                                               float* __restrict__ out) {
  const int bid = blockIdx.x;
  const int tid = threadIdx.x;
  if (bid < 256) {
    __shared__ float plane[1024];
    __shared__ int argL[1024];
    const int c = bid;
#pragma unroll
    for (int k = 0; k < 4; ++k) {
      plane[k * 256 + tid] = ref3[(size_t)c * 1024 + k * 256 + tid];
      argL[k * 256 + tid] = arg[k * 256 + tid];
    }
    __syncthreads();
#pragma unroll
    for (int k = 0; k < 4; ++k) {
      int px = k * 256 + tid;
      int y = px >> 5, x = px & 31;
      float s = 0.f;
#pragma unroll
      for (int di = -1; di <= 1; ++di) {
        int i = y + di;
        if ((unsigned)i >= 32u) continue;
#pragma unroll
        for (int dj = -1; dj <= 1; ++dj) {
          int jw = x + dj;
          if ((unsigned)jw >= 32u) continue;
          int n2 = argL[i * 32 + jw];
          int rr = (n2 >> 5) + y - i, cc = (n2 & 31) + x - jw;
          if ((unsigned)rr < 32u && (unsigned)cc < 32u) s += plane[rr * 32 + cc];
        }
      }
      out[3072 + (size_t)c * 1024 + px] = s * (1.f / 9.f);
    }
  } else if (bid < 1280) {
    __shared__ int argL[1024];
#pragma unroll
    for (int k = 0; k < 4; ++k) argL[k * 256 + tid] = arg[k * 256 + tid];
    __syncthreads();
    int id2 = (bid - 256) * 256 + tid;
    int q = id2 & 31, y = (id2 >> 5) & 63, c = id2 >> 11;
    int iy = y >> 1;
    float s0 = 0.f, s1 = 0.f;
#pragma unroll
    for (int di = -1; di <= 1; ++di) {
      int i = iy + di;
      if ((unsigned)i >= 32u) continue;
      int ry = y - 2 * i;
#pragma unroll
      for (int dj = -1; dj <= 1; ++dj) {
        int jw = q + dj;
        if ((unsigned)jw >= 32u) continue;
        int n2 = argL[i * 32 + jw];
        int rr = (n2 >> 5) * 2 + ry;
        int cb = (n2 & 31) * 2 + 2 * (q - jw);
        if ((unsigned)rr < 64u && (unsigned)cb < 63u) {
          const float* p = ref2 + (size_t)c * 4096 + rr * 64 + cb;
          s0 += p[0]; s1 += p[1];
        }
      }
    }
    float2 o; o.x = s0 * (1.f / 9.f); o.y = s1 * (1.f / 9.f);
    *(float2*)(out + 265216 + (size_t)c * 4096 + y * 64 + 2 * q) = o;
  } else if (bid < 2304) {
    __shared__ int argL[1024];
#pragma unroll
    for (int k = 0; k < 4; ++k) argL[k * 256 + tid] = arg[k * 256 + tid];
    __syncthreads();
    int id1 = (bid - 1280) * 256 + tid;
    int q = id1 & 31, y = (id1 >> 5) & 127, c = id1 >> 12;
    int iy = y >> 2;
    f32x4 s = {0.f, 0.f, 0.f, 0.f};
#pragma unroll
    for (int di = -1; di <= 1; ++di) {
      int i = iy + di;
      if ((unsigned)i >= 32u) continue;
      int ry = y - 4 * i;
#pragma unroll
      for (int dj = -1; dj <= 1; ++dj) {
        int jw = q + dj;
        if ((unsigned)jw >= 32u) continue;
        int n2 = argL[i * 32 + jw];
        int rr = (n2 >> 5) * 4 + ry;
        int cb = (n2 & 31) * 4 + 4 * (q - jw);
        if ((unsigned)rr < 128u && (unsigned)cb < 125u) {
          f32x4 v = *(const f32x4*)(ref1 + (size_t)c * 16384 + rr * 128 + cb);
          s += v;
        }
      }
    }
    s *= (1.f / 9.f);
    *(f32x4*)(out + 789504 + (size_t)c * 16384 + y * 128 + 4 * q) = s;
  } else {
    int t = (bid - 2304) * 256 + tid;  // 0..2047
    if (t < 1024) {
      float mx = -3.0e38f;
      for (int rb = 0; rb < 128; ++rb) mx = fmaxf(mx, cmax1[rb * 1024 + t]);
      out[t] = mx;            // S_1
    } else {
      int tt = t - 1024;
      float mx = -3.0e38f;
      for (int rb = 0; rb < 32; ++rb) mx = fmaxf(mx, cmax2[rb * 1024 + tt]);
      out[1024 + tt] = mx;    // S_2
    }
  }
}

// ---------------- workspace layout (bytes) ----------------
static constexpr size_t OFF_BW2     = 0;                        // 1152 f32
static constexpr size_t OFF_BW1     = 4608;                     // 640 f32
static constexpr size_t ZERO_BYTES  = 7168;
static constexpr size_t OFF_BB      = 7168;                     // 2 f32 (pad to 256)
static constexpr size_t OFF_BL2     = 7424;                     // 1024 f32
static constexpr size_t OFF_BL1     = 11520;                    // 1024 f32
static constexpr size_t OFF_SCLR    = 15616;                    // 1024 f32
static constexpr size_t OFF_SCU3    = 19712;                    // 1024 f32
static constexpr size_t OFF_R3ARG   = 23808;                    // 1024 int
static constexpr size_t OFF_PNSQ2   = 27904;                    // f32 [18][4096]
static constexpr size_t OFF_PBWD2   = OFF_PNSQ2 + 294912;       // f32 [18][4096]
static constexpr size_t OFF_PNSQ1   = OFF_PBWD2 + 294912;       // f32 [10][16384]
static constexpr size_t OFF_PBWD1   = OFF_PNSQ1 + 655360;       // f32 [10][16384]
static constexpr size_t OFF_CMAX2   = OFF_PBWD1 + 655360;       // f32 [32][1024]
static constexpr size_t OFF_CMAX1   = OFF_CMAX2 + 131072;       // f32 [128][1024]
static constexpr size_t OFF_LR3NBT  = OFF_CMAX1 + 524288;       // bf16 [1024][2304] (RAW)
static constexpr size_t OFF_U2B     = OFF_LR3NBT + 4718592;     // bf16 [4096][1152] (perm K)
static constexpr size_t OFF_U1B     = OFF_U2B    + 9437184;     // bf16 [16384][640] (perm K)
static constexpr size_t OFF_W1T     = OFF_U1B    + 20971520;    // bf16 [1152][2304] (perm rows)
static constexpr size_t OFF_W2T     = OFF_W1T    + 5308416;     // bf16 [640][2304] (perm rows; 576+ zero)
static constexpr size_t OFF_A2      = OFF_W2T    + 2949120;     // bf16 [1152][1152]
static constexpr size_t OFF_A1      = OFF_A2     + 2654208;     // bf16 [640][640]
static constexpr size_t OFF_M2T     = OFF_A1     + 819200;      // bf16 [1024][1152]
static constexpr size_t OFF_M1T     = OFF_M2T    + 2359296;     // bf16 [1024][640]
static constexpr size_t OFF_G2      = OFF_M1T    + 1310720;     // f32 [1024][1024]
static constexpr size_t OFF_R2T     = OFF_G2     + 4194304;     // f32 [4096][128]
static constexpr size_t OFF_R1T     = OFF_R2T    + 2097152;     // f32 [16384][64]

extern "C" void kernel_launch(void* const* d_in, const int* in_sizes, int n_in,
                              void* d_out, int out_size, void* d_ws, size_t ws_size,
                              hipStream_t stream) {
  (void)in_sizes; (void)n_in; (void)out_size; (void)ws_size;
  const float* lrsr3  = (const float*)d_in[0];
  const float* rsr1   = (const float*)d_in[1];
  const float* rsr2   = (const float*)d_in[2];
  const float* rsr3   = (const float*)d_in[3];
  const float* ref1   = (const float*)d_in[4];
  const float* ref2   = (const float*)d_in[5];
  const float* ref3   = (const float*)d_in[6];
  const float* W1     = (const float*)d_in[7];
  const float* b1     = (const float*)d_in[8];
  const float* W2     = (const float*)d_in[9];
  const float* b2     = (const float*)d_in[10];
  float* out = (float*)d_out;
  char* ws = (char*)d_ws;

  float*          bw2     = (float*)(ws + OFF_BW2);
  float*          bw1     = (float*)(ws + OFF_BW1);
  float*          bb      = (float*)(ws + OFF_BB);
  float*          bl2     = (float*)(ws + OFF_BL2);
  float*          bl1     = (float*)(ws + OFF_BL1);
  float*          sclr    = (float*)(ws + OFF_SCLR);
  float*          scu3    = (float*)(ws + OFF_SCU3);
  int*            R3arg   = (int*)(ws + OFF_R3ARG);
  float*          pnsq2   = (float*)(ws + OFF_PNSQ2);
  float*          pbwd2   = (float*)(ws + OFF_PBWD2);
  float*          pnsq1   = (float*)(ws + OFF_PNSQ1);
  float*          pbwd1   = (float*)(ws + OFF_PBWD1);
  float*          cmax2   = (float*)(ws + OFF_CMAX2);
  float*          cmax1   = (float*)(ws + OFF_CMAX1);
  unsigned short* lr3nbT  = (unsigned short*)(ws + OFF_LR3NBT);
  unsigned short* U2b     = (unsigned short*)(ws + OFF_U2B);
  unsigned short* U1b     = (unsigned short*)(ws + OFF_U1B);
  unsigned short* W1t     = (unsigned short*)(ws + OFF_W1T);
  unsigned short* W2t     = (unsigned short*)(ws + OFF_W2T);
  unsigned short* A2b     = (unsigned short*)(ws + OFF_A2);
  unsigned short* A1b     = (unsigned short*)(ws + OFF_A1);
  unsigned short* M2tb    = (unsigned short*)(ws + OFF_M2T);
  unsigned short* M1tb    = (unsigned short*)(ws + OFF_M1T);
  float*          G2      = (float*)(ws + OFF_G2);
  float*          rsr2t   = (float*)(ws + OFF_R2T);
  float*          rsr1t   = (float*)(ws + OFF_R1T);

  hipMemsetAsync(d_ws, 0, ZERO_BYTES, stream);
  // zero pad rows 576..639 of W2t
  hipMemsetAsync(ws + OFF_W2T + (size_t)576 * 2304 * 2, 0, (size_t)64 * 2304 * 2, stream);

  // A: colnorms || pixel Gram || channels-last transposes || RAW lr3nb unfold || W transposes
  k_prepA<<<5580, 256, 0, stream>>>(lrsr3, rsr3, rsr2, rsr1, W1, W2, b1, b2,
                                    sclr, scu3, bl2, bl1, G2, rsr2t, rsr1t, lr3nbT, W1t, W2t);

  Job jz = {};
  // B+P: P-GEMM (Gram + M^T with deferred sclr scaling) || U unfolds || bw/bb || r3max
  {
    Job a = jz, b = jz;
    a.Alo = W1t; a.Ahi = lr3nbT; a.Msplit = 1152; a.Bt = W1t;
    a.Clo = A2b; a.Chi = M2tb; a.rowscale = sclr; a.N = 1152; a.K = 2304; a.nbx = 9;
    b.Alo = W2t; b.Ahi = lr3nbT; b.Msplit = 640; b.Bt = W2t;
    b.Clo = A1b; b.Chi = M1tb; b.rowscale = sclr; b.N = 640; b.K = 2304; b.nbx = 5;
    k_prepBP<<<8746, 256, 0, stream>>>(a, b, 153, rsr2t, rsr1t, W1, W2, b1, b2, sclr, scu3, G2,
                                       U2b, U1b, bw2, bw1, bb, out + 2048, R3arg);
  }
  // E1: per-(colblock,half) norm/bw partials (balanced per-XCD dual-job chunking)
  {
    Job a = jz, b = jz;
    a.Alo = U2b; a.Ahi = U2b; a.Msplit = 4096; a.Bt = A2b;
    a.bw = bw2; a.pnsq = pnsq2; a.pbwd = pbwd2; a.Mtot = 4096;
    a.N = 1152; a.K = 1152; a.nbx = 9;
    b.Alo = U1b; b.Ahi = U1b; b.Msplit = 16384; b.Bt = A1b;
    b.bw = bw1; b.pnsq = pnsq1; b.pbwd = pbwd1; b.Mtot = 16384;
    b.N = 640; b.K = 640; b.nbx = 5;
    k_gE1<<<288 + 640, 256, 0, stream>>>(a, b, 288);
  }
  // E2: score max (per-block ninv from partials; balanced per-XCD dual-job chunking)
  {
    Job a = jz, b = jz;
    a.Alo = U2b; a.Ahi = U2b; a.Msplit = 4096; a.Bt = M2tb;
    a.bl = bl2; a.pnsq = pnsq2; a.pbwd = pbwd2; a.bbp = bb;
    a.npart = 18; a.which = 0; a.cmax = cmax2; a.Mtot = 4096;
    a.N = 1024; a.K = 1152; a.nbx = 8;
    b.Alo = U1b; b.Ahi = U1b; b.Msplit = 16384; b.Bt = M1tb;
    b.bl = bl1; b.pnsq = pnsq1; b.pbwd = pbwd1; b.bbp = bb;
    b.npart = 10; b.which = 1; b.cmax = cmax1; b.Mtot = 16384;
    b.N = 1024; b.K = 640; b.nbx = 8;
    k_gE2<<<256 + 1024, 256, 0, stream>>>(a, b, 256);
  }

  // transfer + S1/S2 finalize (fused, vectorized gathers)
  k_tfold<<<2312, 256, 0, stream>>>(ref3, ref2, ref1, R3arg, cmax1, cmax2, out);
}